// Round 2
// baseline (4353.633 us; speedup 1.0000x reference)
//
#include <hip/hip_runtime.h>
#include <hip/hip_bf16.h>
#include <math.h>

typedef __hip_bfloat16 bf16;

__device__ __forceinline__ float bff(const bf16 x){ return __bfloat162float(x); }
__device__ __forceinline__ float gelu_f(float v){
    return 0.5f * v * (1.f + erff(v * 0.70710678118654752f));
}
__device__ __forceinline__ float silu_f(float v){
    return v / (1.f + expf(-v));
}
// dtype-agnostic input read: f32 ? fp32 : bf16
__device__ __forceinline__ float rdf(const void* p, size_t i, bool f32){
    return f32 ? ((const float*)p)[i] : __bfloat162float(((const bf16*)p)[i]);
}

// Geometry
// B=256, C=64, H=W=34 (padded), modes: ky in {0..11, 22..33} (24), kx in 0..11 (12)
// h layout (ws, ALWAYS bf16): [b][c][y][x], stride c = 1156, stride b = 73984
// hft layout: [m][b*64+c] complex bf16, m = kyi*12+kx (kyi 0..23)
// mixed layout: [(b*64+o)*288 + m] complex bf16

// ---------------- dtype probe ----------------
__global__ __launch_bounds__(256) void k_probe(const void* x, float* flag){
    __shared__ int wild;
    int t = threadIdx.x;
    if (t == 0) wild = 0;
    __syncthreads();
    const bf16* xb = (const bf16*)x;
    for (int i = t; i < 1024; i += 256){
        float v = bff(xb[i]);
        if (!(fabsf(v) < 1e10f)) wild = 1;   // catches huge and NaN
    }
    __syncthreads();
    if (t == 0) flag[0] = wild ? 1.f : 0.f;
}

// ---------------- tables ----------------
__global__ __launch_bounds__(256) void k_tables(float* tabs){
    int t = threadIdx.x;
    float* Wfy = tabs;          // 24*34*2
    float* Wfx = tabs + 1632;   // 12*34*2
    float* Wix = tabs + 2448;   // 12*34*2
    float* Wiy = tabs + 3264;   // 24*34*2
    const float TWO_PI = 6.283185307179586f;
    for (int e = t; e < 24*34; e += 256){
        int kyi = e / 34, y = e % 34;
        int ky = (kyi < 12) ? kyi : kyi + 10;
        int ph = (ky * y) % 34;
        float ang = TWO_PI * (float)ph / 34.0f;
        float s, c;
        sincosf(ang, &s, &c);
        Wfy[e*2]   = c;   Wfy[e*2+1] = -s;           // e^{-i ang}
        Wiy[e*2]   = c * (1.0f/1156.0f);
        Wiy[e*2+1] = s * (1.0f/1156.0f);             // (1/HW) e^{+i ang}
    }
    for (int e = t; e < 12*34; e += 256){
        int kx = e / 34, x = e % 34;
        int ph = (kx * x) % 34;
        float ang = TWO_PI * (float)ph / 34.0f;
        float s, c;
        sincosf(ang, &s, &c);
        Wfx[e*2] = c; Wfx[e*2+1] = -s;               // e^{-i ang}
        float ck = (kx == 0) ? 1.0f : 2.0f;
        Wix[e*2] = ck * c; Wix[e*2+1] = ck * s;      // c_kx e^{+i ang}
    }
}

// ---------------- fc0: concat(x,grid) @ fc0_w + b, NCHW, zero-pad to 34x34 ----
__global__ __launch_bounds__(256) void k_fc0(const void* __restrict__ xin,
                                             const void* __restrict__ grd,
                                             const void* __restrict__ w,
                                             const void* __restrict__ bias,
                                             bf16* __restrict__ h,
                                             const float* __restrict__ flg){
    __shared__ float sin_[32*42];
    __shared__ float sw[42*64];
    __shared__ float sb[64];
    const bool f32 = (flg[0] > 0.5f);
    int bid = blockIdx.x;          // b*34 + y
    int b = bid / 34, y = bid - b*34;
    int t = threadIdx.x;
    bf16* hb = h + (size_t)b*73984 + y*34;
    if (y >= 32){
        for (int e = t; e < 2176; e += 256){
            int c = e / 34, x = e - c*34;
            hb[(size_t)c*1156 + x] = __float2bfloat16(0.f);
        }
        return;
    }
    for (int idx = t; idx < 2688; idx += 256) sw[idx] = rdf(w, idx, f32);
    if (t < 64) sb[t] = rdf(bias, t, f32);
    size_t xbase = (size_t)(b*32 + y)*32*40;
    for (int idx = t; idx < 1280; idx += 256){
        int x = idx / 40, k = idx - x*40;
        sin_[x*42 + k] = rdf(xin, xbase + idx, f32);
    }
    size_t gbase = (size_t)(b*32 + y)*32*2;
    if (t < 64){
        int x = t >> 1, k2 = t & 1;
        sin_[x*42 + 40 + k2] = rdf(grd, gbase + x*2 + k2, f32);
    }
    __syncthreads();
    for (int e = t; e < 2048; e += 256){
        int x = e & 31, c = e >> 5;
        float acc = sb[c];
        #pragma unroll
        for (int k = 0; k < 42; ++k)
            acc += sin_[x*42 + k] * sw[k*64 + c];
        hb[(size_t)c*1156 + x] = __float2bfloat16(acc);
    }
    for (int e = t; e < 128; e += 256){
        int c = e >> 1, x = 32 + (e & 1);
        hb[(size_t)c*1156 + x] = __float2bfloat16(0.f);
    }
}

// ---------------- forward truncated DFT per (b,c) ----------------
__global__ __launch_bounds__(256) void k_fwd(const bf16* __restrict__ h,
                                             bf16* __restrict__ hft,
                                             const float* __restrict__ tabs){
    __shared__ float sh[1156];
    __shared__ float st[24*34*2];
    int bc = blockIdx.x;           // b*64 + c
    int t = threadIdx.x;
    const float* Wfy = tabs;
    const float* Wfx = tabs + 1632;
    const bf16* src = h + (size_t)bc * 1156;
    for (int e = t; e < 1156; e += 256) sh[e] = bff(src[e]);
    __syncthreads();
    for (int e = t; e < 816; e += 256){
        int kyi = e / 34, x = e - kyi*34;
        float ar = 0.f, ai = 0.f;
        const float* wy = Wfy + kyi*68;
        #pragma unroll 2
        for (int y = 0; y < 34; ++y){
            float hv = sh[y*34 + x];
            ar += hv * wy[y*2];
            ai += hv * wy[y*2 + 1];
        }
        st[e*2] = ar; st[e*2+1] = ai;
    }
    __syncthreads();
    for (int e = t; e < 288; e += 256){
        int kyi = e / 12, kx = e - kyi*12;
        float ar = 0.f, ai = 0.f;
        const float* wx = Wfx + kx*68;
        const float* tr = st + kyi*68;
        #pragma unroll 2
        for (int x = 0; x < 34; ++x){
            float cr = wx[x*2], ci = wx[x*2+1];
            float gr = tr[x*2], gi = tr[x*2+1];
            ar += gr*cr - gi*ci;
            ai += gr*ci + gi*cr;
        }
        size_t o = ((size_t)e * 16384 + (size_t)bc) * 2;
        hft[o]   = __float2bfloat16(ar);
        hft[o+1] = __float2bfloat16(ai);
    }
}

// ---------------- per-mode complex channel mix ----------------
// grid: 288 modes x 8 batch-tiles of 32; LDS = 32KB (w) + 16KB (h) = 48KB
__global__ __launch_bounds__(256) void k_mix(const bf16* __restrict__ hft,
                                             const void* __restrict__ sc_w1,
                                             const void* __restrict__ sc_w2,
                                             bf16* __restrict__ mixed, int layer,
                                             const float* __restrict__ flg){
    __shared__ float sw[4096*2];
    __shared__ float shh[2048*2];
    const bool f32 = (flg[0] > 0.5f);
    int m  = blockIdx.x >> 3;
    int bt = blockIdx.x & 7;
    int b0 = bt * 32;
    int t = threadIdx.x;
    int kyi = m / 12, kx = m - kyi*12;
    const void* w = (kyi < 12) ? sc_w1 : sc_w2;
    int r = (kyi < 12) ? kyi : kyi - 12;
    size_t wbase = (size_t)layer * 64*64*144*2;
    for (int idx = t; idx < 4096; idx += 256){
        int i = idx >> 6, o = idx & 63;
        size_t off = wbase + ((((size_t)(i*64 + o))*12 + r)*12 + kx)*2;
        sw[idx*2]   = rdf(w, off, f32);
        sw[idx*2+1] = rdf(w, off+1, f32);
    }
    const bf16* hsrc = hft + ((size_t)m * 16384 + (size_t)b0*64) * 2;
    for (int idx = t; idx < 2048; idx += 256){
        shh[idx*2]   = bff(hsrc[idx*2]);
        shh[idx*2+1] = bff(hsrc[idx*2+1]);
    }
    __syncthreads();
    int o = t & 63;
    int br0 = t >> 6;
    for (int bb = br0; bb < 32; bb += 4){
        float ar = 0.f, ai = 0.f;
        const float* hrow = shh + bb*128;
        #pragma unroll 4
        for (int i = 0; i < 64; ++i){
            float hr = hrow[i*2], hi = hrow[i*2+1];
            float wr = sw[(i*64+o)*2], wi = sw[(i*64+o)*2+1];
            ar += hr*wr - hi*wi;
            ai += hr*wi + hi*wr;
        }
        size_t oo = (((size_t)(b0+bb)*64 + o)*288 + m)*2;
        mixed[oo]   = __float2bfloat16(ar);
        mixed[oo+1] = __float2bfloat16(ai);
    }
}

// ---------------- pointwise 64x64 channel GEMM (wc path), IN PLACE -----------
// block (b,y) exclusively owns row y of batch b: load all c to LDS, sync, write
__global__ __launch_bounds__(256) void k_wc(bf16* __restrict__ h,
                                            const void* __restrict__ wc_w,
                                            const void* __restrict__ wc_b,
                                            int layer,
                                            const float* __restrict__ flg){
    __shared__ float sw[64*65];
    __shared__ float sh[64*34];
    __shared__ float sb[64];
    const bool f32 = (flg[0] > 0.5f);
    int bid = blockIdx.x;          // b*34 + y
    int b = bid / 34, y = bid - b*34;
    int t = threadIdx.x;
    size_t wbase = (size_t)layer*4096;
    for (int idx = t; idx < 4096; idx += 256){
        int o = idx >> 6, c = idx & 63;
        sw[c*65 + o] = rdf(wc_w, wbase + idx, f32);
    }
    if (t < 64) sb[t] = rdf(wc_b, layer*64 + t, f32);
    bf16* hb = h + (size_t)b*73984 + y*34;
    for (int idx = t; idx < 2176; idx += 256){
        int c = idx / 34, x = idx - c*34;
        sh[c*34 + x] = bff(hb[(size_t)c*1156 + x]);
    }
    __syncthreads();
    for (int e = t; e < 2176; e += 256){
        int o = e / 34, x = e - o*34;
        float acc = sb[o];
        #pragma unroll 4
        for (int c = 0; c < 64; ++c)
            acc += sh[c*34 + x] * sw[c*65 + o];
        hb[(size_t)o*1156 + x] = __float2bfloat16(acc);
    }
}

// ---------------- inverse truncated DFT per (b,o); adds into h in place ------
__global__ __launch_bounds__(256) void k_inv(const bf16* __restrict__ mixed,
                                             const float* __restrict__ tabs,
                                             bf16* __restrict__ hio, int layer){
    __shared__ float sm[576];
    __shared__ float sg[24*34*2];
    int bo = blockIdx.x;           // b*64 + o
    int t = threadIdx.x;
    const float* Wix = tabs + 2448;
    const float* Wiy = tabs + 3264;
    const bf16* msrc = mixed + (size_t)bo * 576;
    for (int e = t; e < 576; e += 256) sm[e] = bff(msrc[e]);
    __syncthreads();
    for (int e = t; e < 816; e += 256){
        int kyi = e / 34, x = e - kyi*34;
        float gr = 0.f, gi = 0.f;
        const float* mr = sm + kyi*24;
        #pragma unroll
        for (int kx = 0; kx < 12; ++kx){
            float fr = mr[kx*2], fi = mr[kx*2+1];
            float c = Wix[(kx*34+x)*2], s = Wix[(kx*34+x)*2+1];
            gr += fr*c - fi*s;
            gi += fr*s + fi*c;
        }
        sg[e*2] = gr; sg[e*2+1] = gi;
    }
    __syncthreads();
    bf16* io = hio + (size_t)bo * 1156;
    for (int e = t; e < 1156; e += 256){
        int y = e / 34, x = e - y*34;
        float acc = 0.f;
        #pragma unroll 4
        for (int kyi = 0; kyi < 24; ++kyi){
            float gr = sg[(kyi*34+x)*2], gi = sg[(kyi*34+x)*2+1];
            float c = Wiy[(kyi*34+y)*2], s = Wiy[(kyi*34+y)*2+1];
            acc += gr*c - gi*s;
        }
        float v = acc + bff(io[e]);
        if (layer < 3) v = gelu_f(v);
        io[e] = __float2bfloat16(v);
    }
}

// ---------------- 8x8/stride4 VALID conv -> gelu -> pe2 scale ----------------
__global__ __launch_bounds__(256) void k_pe(const bf16* __restrict__ h,
                                            const void* __restrict__ pw,
                                            const void* __restrict__ pb,
                                            const void* __restrict__ p2w,
                                            const void* __restrict__ p2b,
                                            float* __restrict__ p49,
                                            const float* __restrict__ flg){
    __shared__ float red[256];
    const bool f32 = (flg[0] > 0.5f);
    int bid = blockIdx.x;          // b*49 + py*7 + px
    int b = bid / 49, r = bid - b*49;
    int py = r / 7, px = r - py*7;
    int t = threadIdx.x;
    const bf16* hb = h + (size_t)b*73984 + (py*4)*34 + px*4;
    float partial = 0.f;
    for (int tt = t; tt < 4096; tt += 256){
        int c = tt >> 6, k = tt & 63, ky = k >> 3, kx = k & 7;
        partial += bff(hb[(size_t)c*1156 + ky*34 + kx]) * rdf(pw, tt, f32);
    }
    red[t] = partial;
    __syncthreads();
    for (int s = 128; s > 0; s >>= 1){
        if (t < s) red[t] += red[t + s];
        __syncthreads();
    }
    if (t == 0){
        float v = red[0] + rdf(pb, 0, f32);
        v = gelu_f(v);
        p49[bid] = v * rdf(p2w, 0, f32) + rdf(p2b, 0, f32);
    }
}

// ---------------- sentence MLP 384->32->32->16 (relu,relu,lin) ---------------
__global__ __launch_bounds__(64) void k_sent(const void* __restrict__ se,
                                             const void* __restrict__ w1, const void* __restrict__ b1,
                                             const void* __restrict__ w2, const void* __restrict__ b2,
                                             const void* __restrict__ w3, const void* __restrict__ b3,
                                             float* __restrict__ outv,
                                             const float* __restrict__ flg){
    __shared__ float s1[32], s2[32];
    const bool f32 = (flg[0] > 0.5f);
    int b = blockIdx.x, t = threadIdx.x;
    if (t < 32){
        float acc = rdf(b1, t, f32);
        size_t rbase = (size_t)b*384;
        for (int k = 0; k < 384; ++k) acc += rdf(se, rbase + k, f32) * rdf(w1, k*32 + t, f32);
        s1[t] = fmaxf(acc, 0.f);
    }
    __syncthreads();
    if (t < 32){
        float acc = rdf(b2, t, f32);
        for (int k = 0; k < 32; ++k) acc += s1[k] * rdf(w2, k*32 + t, f32);
        s2[t] = fmaxf(acc, 0.f);
    }
    __syncthreads();
    if (t < 16){
        float acc = rdf(b3, t, f32);
        for (int k = 0; k < 32; ++k) acc += s2[k] * rdf(w3, k*16 + t, f32);
        outv[b*16 + t] = acc;
    }
}

// ---------------- xp MLP 49->32->32->16 (silu,silu,lin) ----------------------
__global__ __launch_bounds__(64) void k_xp(const float* __restrict__ p49,
                                           const void* __restrict__ w1, const void* __restrict__ b1,
                                           const void* __restrict__ w2, const void* __restrict__ b2,
                                           const void* __restrict__ w3, const void* __restrict__ b3,
                                           float* __restrict__ outv,
                                           const float* __restrict__ flg){
    __shared__ float s1[32], s2[32];
    const bool f32 = (flg[0] > 0.5f);
    int b = blockIdx.x, t = threadIdx.x;
    if (t < 32){
        float acc = rdf(b1, t, f32);
        const float* row = p49 + b*49;
        for (int k = 0; k < 49; ++k) acc += row[k] * rdf(w1, k*32 + t, f32);
        s1[t] = silu_f(acc);
    }
    __syncthreads();
    if (t < 32){
        float acc = rdf(b2, t, f32);
        for (int k = 0; k < 32; ++k) acc += s1[k] * rdf(w2, k*32 + t, f32);
        s2[t] = silu_f(acc);
    }
    __syncthreads();
    if (t < 16){
        float acc = rdf(b3, t, f32);
        for (int k = 0; k < 32; ++k) acc += s2[k] * rdf(w3, k*16 + t, f32);
        outv[b*16 + t] = acc;
    }
}

// ---------------- pu MLP 32->128->256->1156 (silu,silu,lin) ------------------
__global__ __launch_bounds__(256) void k_pu(const float* __restrict__ xemb,
                                            const float* __restrict__ semb,
                                            const void* __restrict__ w1, const void* __restrict__ b1,
                                            const void* __restrict__ w2, const void* __restrict__ b2,
                                            const void* __restrict__ w3, const void* __restrict__ b3,
                                            float* __restrict__ emb,
                                            const float* __restrict__ flg){
    __shared__ float ein[32];
    __shared__ float h1[128];
    __shared__ float h2[256];
    const bool f32 = (flg[0] > 0.5f);
    int b = blockIdx.x, t = threadIdx.x;
    if (t < 16) ein[t] = xemb[b*16 + t];
    else if (t < 32) ein[t] = semb[b*16 + (t - 16)];
    __syncthreads();
    if (t < 128){
        float acc = rdf(b1, t, f32);
        for (int k = 0; k < 32; ++k) acc += ein[k] * rdf(w1, k*128 + t, f32);
        h1[t] = silu_f(acc);
    }
    __syncthreads();
    {
        float acc = rdf(b2, t, f32);
        for (int k = 0; k < 128; ++k) acc += h1[k] * rdf(w2, k*256 + t, f32);
        h2[t] = silu_f(acc);
    }
    __syncthreads();
    for (int e = t; e < 1156; e += 256){
        float acc = rdf(b3, e, f32);
        for (int k = 0; k < 256; ++k) acc += h2[k] * rdf(w3, k*1156 + e, f32);
        emb[(size_t)b*1156 + e] = acc;
    }
}

// ---------------- final: crop, concat emb, fc1+gelu, fc2 ---------------------
__global__ __launch_bounds__(256) void k_final(const bf16* __restrict__ h,
                                               const float* __restrict__ emb,
                                               const void* __restrict__ w1, const void* __restrict__ b1,
                                               const void* __restrict__ w2, const void* __restrict__ b2,
                                               void* __restrict__ out,
                                               const float* __restrict__ flg){
    __shared__ float sw1[65*128];
    __shared__ float sb1[128];
    __shared__ float sw2[512];
    __shared__ float sb2[4];
    __shared__ float sinp[65*32];
    __shared__ float shid[32*128];
    const bool f32 = (flg[0] > 0.5f);
    int bid = blockIdx.x;          // b*32 + y
    int b = bid >> 5, y = bid & 31;
    int t = threadIdx.x;
    for (int idx = t; idx < 8320; idx += 256) sw1[idx] = rdf(w1, idx, f32);
    if (t < 128) sb1[t] = rdf(b1, t, f32);
    for (int idx = t; idx < 512; idx += 256) sw2[idx] = rdf(w2, idx, f32);
    if (t < 4) sb2[t] = rdf(b2, t, f32);
    const bf16* hb = h + (size_t)b*73984 + y*34;
    for (int idx = t; idx < 2048; idx += 256){
        int c = idx >> 5, x = idx & 31;
        sinp[c*32 + x] = bff(hb[(size_t)c*1156 + x]);
    }
    if (t < 32) sinp[64*32 + t] = emb[(size_t)b*1156 + y*34 + t];
    __syncthreads();
    for (int e = t; e < 4096; e += 256){
        int x = e >> 7, j = e & 127;
        float acc = sb1[j];
        #pragma unroll 4
        for (int c = 0; c < 65; ++c)
            acc += sinp[c*32 + x] * sw1[c*128 + j];
        shid[x*128 + j] = gelu_f(acc);
    }
    __syncthreads();
    if (t < 128){
        int x = t >> 2, k = t & 3;
        float acc = sb2[k];
        #pragma unroll 4
        for (int j = 0; j < 128; ++j)
            acc += shid[x*128 + j] * sw2[j*4 + k];
        size_t o = ((size_t)(b*32 + y)*32 + x)*4 + k;
        if (f32) ((float*)out)[o] = acc;
        else     ((bf16*)out)[o] = __float2bfloat16(acc);
    }
}

extern "C" void kernel_launch(void* const* d_in, const int* in_sizes, int n_in,
                              void* d_out, int out_size, void* d_ws, size_t ws_size,
                              hipStream_t stream) {
    (void)in_sizes; (void)n_in; (void)out_size; (void)ws_size;
    const void* x     = d_in[0];
    const void* grd   = d_in[1];
    const void* se    = d_in[2];
    const void* fc0_w = d_in[3];
    const void* fc0_b = d_in[4];
    const void* sc_w1 = d_in[5];
    const void* sc_w2 = d_in[6];
    const void* wc_w  = d_in[7];
    const void* wc_b  = d_in[8];
    const void* pe1_w = d_in[9];
    const void* pe1_b = d_in[10];
    const void* pe2_w = d_in[11];
    const void* pe2_b = d_in[12];
    const void* sp_w1 = d_in[13];
    const void* sp_b1 = d_in[14];
    const void* sp_w2 = d_in[15];
    const void* sp_b2 = d_in[16];
    const void* sp_w3 = d_in[17];
    const void* sp_b3 = d_in[18];
    const void* xp_w1 = d_in[19];
    const void* xp_b1 = d_in[20];
    const void* xp_w2 = d_in[21];
    const void* xp_b2 = d_in[22];
    const void* xp_w3 = d_in[23];
    const void* xp_b3 = d_in[24];
    const void* pu_w1 = d_in[25];
    const void* pu_b1 = d_in[26];
    const void* pu_w2 = d_in[27];
    const void* pu_b2 = d_in[28];
    const void* pu_w3 = d_in[29];
    const void* pu_b3 = d_in[30];
    const void* fc1_w = d_in[31];
    const void* fc1_b = d_in[32];
    const void* fc2_w = d_in[33];
    const void* fc2_b = d_in[34];

    // workspace layout (float-unit offsets); total ~77 MB
    float* ws    = (float*)d_ws;
    bf16*  hA    = (bf16*)ws;                         // 18,939,904 bf16 (9,469,952 f)
    bf16*  hft   = (bf16*)(ws + 9469952);             // 9,437,184 bf16 (4,718,592 f)
    bf16*  mixed = (bf16*)(ws + 14188544);            // 9,437,184 bf16 (4,718,592 f)
    float* tabs  = ws + 18907136;                     // 4,896
    float* p49   = ws + 18912032;                     // 12,544
    float* semb  = ws + 18924576;                     // 4,096
    float* xemb  = ws + 18928672;                     // 4,096
    float* emb   = ws + 18932768;                     // 295,936
    float* flag  = ws + 19228704;                     // 1

    k_probe<<<1, 256, 0, stream>>>(x, flag);
    k_tables<<<1, 256, 0, stream>>>(tabs);
    k_fc0<<<256*34, 256, 0, stream>>>(x, grd, fc0_w, fc0_b, hA, flag);

    for (int l = 0; l < 4; ++l){
        k_fwd<<<16384, 256, 0, stream>>>(hA, hft, tabs);
        k_mix<<<288*8, 256, 0, stream>>>(hft, sc_w1, sc_w2, mixed, l, flag);
        k_wc <<<256*34, 256, 0, stream>>>(hA, wc_w, wc_b, l, flag);
        k_inv<<<16384, 256, 0, stream>>>(mixed, tabs, hA, l);
    }

    k_pe  <<<256*49, 256, 0, stream>>>(hA, pe1_w, pe1_b, pe2_w, pe2_b, p49, flag);
    k_sent<<<256, 64, 0, stream>>>(se, sp_w1, sp_b1, sp_w2, sp_b2, sp_w3, sp_b3, semb, flag);
    k_xp  <<<256, 64, 0, stream>>>(p49, xp_w1, xp_b1, xp_w2, xp_b2, xp_w3, xp_b3, xemb, flag);
    k_pu  <<<256, 256, 0, stream>>>(xemb, semb, pu_w1, pu_b1, pu_w2, pu_b2, pu_w3, pu_b3, emb, flag);
    k_final<<<256*32, 256, 0, stream>>>(hA, emb, fc1_w, fc1_b, fc2_w, fc2_b, d_out, flag);
}

// Round 3
// 2509.372 us; speedup vs baseline: 1.7349x; 1.7349x over previous
//
#include <hip/hip_runtime.h>
#include <hip/hip_bf16.h>
#include <math.h>

typedef __hip_bfloat16 bf16;

__device__ __forceinline__ float bff(const bf16 x){ return __bfloat162float(x); }
__device__ __forceinline__ float gelu_f(float v){
    return 0.5f * v * (1.f + erff(v * 0.70710678118654752f));
}
__device__ __forceinline__ float silu_f(float v){
    return v / (1.f + expf(-v));
}
// dtype-agnostic input read: f32 ? fp32 : bf16
__device__ __forceinline__ float rdf(const void* p, size_t i, bool f32){
    return f32 ? ((const float*)p)[i] : __bfloat162float(((const bf16*)p)[i]);
}
__device__ __forceinline__ unsigned int packbf2(float a, float b){
    __hip_bfloat162 v;
    v.x = __float2bfloat16(a);
    v.y = __float2bfloat16(b);
    return *reinterpret_cast<unsigned int*>(&v);
}
__device__ __forceinline__ float2 unpackbf2(unsigned int u){
    __hip_bfloat162 v = *reinterpret_cast<__hip_bfloat162*>(&u);
    return make_float2(__bfloat162float(v.x), __bfloat162float(v.y));
}
__device__ __forceinline__ float us2f(unsigned short u){
    unsigned int x = ((unsigned int)u) << 16;
    return __uint_as_float(x);
}
__device__ __forceinline__ unsigned short f2us(float f){
    bf16 v = __float2bfloat16(f);
    return *reinterpret_cast<unsigned short*>(&v);
}

// Geometry
// B=256, C=64, H=W=34 (padded), modes: ky in {0..11, 22..33} (24), kx in 0..11 (12)
// h layout (ws, bf16): [b][c][y][x], stride c = 1156, stride b = 73984
// hft layout: [m][b*64+c] packed bf16x2 (r,i) dwords, m = kyi*12+kx
// mixed layout: [(b*64+o)*288 + m] packed bf16x2 dwords

// ---------------- dtype probe ----------------
__global__ __launch_bounds__(256) void k_probe(const void* x, float* flag){
    __shared__ int wild;
    int t = threadIdx.x;
    if (t == 0) wild = 0;
    __syncthreads();
    const bf16* xb = (const bf16*)x;
    for (int i = t; i < 1024; i += 256){
        float v = bff(xb[i]);
        if (!(fabsf(v) < 1e10f)) wild = 1;
    }
    __syncthreads();
    if (t == 0) flag[0] = wild ? 1.f : 0.f;
}

// ---------------- tables ----------------
__global__ __launch_bounds__(256) void k_tables(float* tabs){
    int t = threadIdx.x;
    float* Wfy = tabs;          // 24*34*2
    float* Wfx = tabs + 1632;   // 12*34*2
    float* Wix = tabs + 2448;   // 12*34*2
    float* Wiy = tabs + 3264;   // 24*34*2
    const float TWO_PI = 6.283185307179586f;
    for (int e = t; e < 24*34; e += 256){
        int kyi = e / 34, y = e % 34;
        int ky = (kyi < 12) ? kyi : kyi + 10;
        int ph = (ky * y) % 34;
        float ang = TWO_PI * (float)ph / 34.0f;
        float s, c;
        sincosf(ang, &s, &c);
        Wfy[e*2]   = c;   Wfy[e*2+1] = -s;           // e^{-i ang}
        Wiy[e*2]   = c * (1.0f/1156.0f);
        Wiy[e*2+1] = s * (1.0f/1156.0f);             // (1/HW) e^{+i ang}
    }
    for (int e = t; e < 12*34; e += 256){
        int kx = e / 34, x = e % 34;
        int ph = (kx * x) % 34;
        float ang = TWO_PI * (float)ph / 34.0f;
        float s, c;
        sincosf(ang, &s, &c);
        Wfx[e*2] = c; Wfx[e*2+1] = -s;               // e^{-i ang}
        float ck = (kx == 0) ? 1.0f : 2.0f;
        Wix[e*2] = ck * c; Wix[e*2+1] = ck * s;      // c_kx e^{+i ang}
    }
}

// ---------------- fc0: concat(x,grid) @ fc0_w + b, NCHW, zero-pad to 34x34 ----
__global__ __launch_bounds__(256) void k_fc0(const void* __restrict__ xin,
                                             const void* __restrict__ grd,
                                             const void* __restrict__ w,
                                             const void* __restrict__ bias,
                                             bf16* __restrict__ h,
                                             const float* __restrict__ flg){
    __shared__ float sin_[32*42];
    __shared__ float sw[42*64];
    __shared__ float sb[64];
    const bool f32 = (flg[0] > 0.5f);
    int bid = blockIdx.x;          // b*34 + y
    int b = bid / 34, y = bid - b*34;
    int t = threadIdx.x;
    bf16* hb = h + (size_t)b*73984 + y*34;
    if (y >= 32){
        for (int e = t; e < 2176; e += 256){
            int c = e / 34, x = e - c*34;
            hb[(size_t)c*1156 + x] = __float2bfloat16(0.f);
        }
        return;
    }
    for (int idx = t; idx < 2688; idx += 256) sw[idx] = rdf(w, idx, f32);
    if (t < 64) sb[t] = rdf(bias, t, f32);
    size_t xbase = (size_t)(b*32 + y)*32*40;
    for (int idx = t; idx < 1280; idx += 256){
        int x = idx / 40, k = idx - x*40;
        sin_[x*42 + k] = rdf(xin, xbase + idx, f32);
    }
    size_t gbase = (size_t)(b*32 + y)*32*2;
    if (t < 64){
        int x = t >> 1, k2 = t & 1;
        sin_[x*42 + 40 + k2] = rdf(grd, gbase + x*2 + k2, f32);
    }
    __syncthreads();
    for (int e = t; e < 2048; e += 256){
        int x = e & 31, c = e >> 5;
        float acc = sb[c];
        #pragma unroll
        for (int k = 0; k < 42; ++k)
            acc += sin_[x*42 + k] * sw[k*64 + c];
        hb[(size_t)c*1156 + x] = __float2bfloat16(acc);
    }
    for (int e = t; e < 128; e += 256){
        int c = e >> 1, x = 32 + (e & 1);
        hb[(size_t)c*1156 + x] = __float2bfloat16(0.f);
    }
}

// ---------------- forward truncated DFT, 4 channels per block ----------------
// grid 4096 = 256 b x 16 ch-groups
__global__ __launch_bounds__(256) void k_fwd(const bf16* __restrict__ h,
                                             unsigned int* __restrict__ hft,
                                             const float* __restrict__ tabs){
    __shared__ float sh[4624];          // 4 x 1156
    __shared__ float sWfy[1632];
    __shared__ float sWfx[816];
    __shared__ unsigned int st[3264];   // 4 x 816 packed bf16x2 (G intermediates)
    int blk = blockIdx.x;
    int b = blk >> 4, c0 = (blk & 15) * 4;
    int t = threadIdx.x;
    for (int i = t; i < 1632; i += 256) sWfy[i] = tabs[i];
    for (int i = t; i < 816; i += 256) sWfx[i] = tabs[1632 + i];
    const bf16* src = h + (size_t)b*73984 + (size_t)c0*1156;
    for (int i = t; i < 4624; i += 256) sh[i] = bff(src[i]);
    __syncthreads();
    // step 1: G[ch][kyi][x] = sum_y Wfy[kyi][y] * h[ch][y][x]   (2kyi x 2x x 4ch tiles)
    if (t < 204){
        int kyit = t / 17, xt = t - kyit*17;
        int kyi0 = kyit*2, x0 = xt*2;
        float a[4][2][2][2];
        #pragma unroll
        for (int c=0;c<4;++c)
            #pragma unroll
            for (int q=0;q<2;++q){ a[c][q][0][0]=0.f; a[c][q][0][1]=0.f; a[c][q][1][0]=0.f; a[c][q][1][1]=0.f; }
        for (int y = 0; y < 34; ++y){
            int w0 = (kyi0*34 + y)*2, w1 = ((kyi0+1)*34 + y)*2;
            float w0r = sWfy[w0], w0i = sWfy[w0+1];
            float w1r = sWfy[w1], w1i = sWfy[w1+1];
            const float* shy = sh + y*34 + x0;
            #pragma unroll
            for (int c = 0; c < 4; ++c){
                float h0 = shy[c*1156];
                float h1 = shy[c*1156 + 1];
                a[c][0][0][0] += h0*w0r; a[c][0][0][1] += h0*w0i;
                a[c][0][1][0] += h1*w0r; a[c][0][1][1] += h1*w0i;
                a[c][1][0][0] += h0*w1r; a[c][1][0][1] += h0*w1i;
                a[c][1][1][0] += h1*w1r; a[c][1][1][1] += h1*w1i;
            }
        }
        #pragma unroll
        for (int c = 0; c < 4; ++c)
            #pragma unroll
            for (int q = 0; q < 2; ++q){
                int base = c*816 + (kyi0+q)*34 + x0;
                st[base]   = packbf2(a[c][q][0][0], a[c][q][0][1]);
                st[base+1] = packbf2(a[c][q][1][0], a[c][q][1][1]);
            }
    }
    __syncthreads();
    // step 2: F[ch][kyi][kx] = sum_x G[ch][kyi][x] * Wfx[kx][x]   (complex x complex)
    if (t < 144){
        int kyit = t / 12, kx = t - kyit*12;
        int kyi0 = kyit*2;
        float a[4][2][2];
        #pragma unroll
        for (int c=0;c<4;++c){ a[c][0][0]=0.f; a[c][0][1]=0.f; a[c][1][0]=0.f; a[c][1][1]=0.f; }
        for (int x = 0; x < 34; ++x){
            float cr = sWfx[(kx*34+x)*2], ci = sWfx[(kx*34+x)*2+1];
            #pragma unroll
            for (int c = 0; c < 4; ++c){
                float2 g0 = unpackbf2(st[c*816 + kyi0*34 + x]);
                float2 g1 = unpackbf2(st[c*816 + (kyi0+1)*34 + x]);
                a[c][0][0] += g0.x*cr - g0.y*ci;
                a[c][0][1] += g0.x*ci + g0.y*cr;
                a[c][1][0] += g1.x*cr - g1.y*ci;
                a[c][1][1] += g1.x*ci + g1.y*cr;
            }
        }
        #pragma unroll
        for (int c = 0; c < 4; ++c)
            #pragma unroll
            for (int q = 0; q < 2; ++q){
                int m = (kyi0+q)*12 + kx;
                hft[(size_t)m*16384 + (size_t)b*64 + c0 + c] = packbf2(a[c][q][0], a[c][q][1]);
            }
    }
}

// ---------------- per-mode complex channel mix ----------------
// grid 2304 = 288 modes x 8 batch-tiles of 32; split r/i LDS; 4bb x 2o tiles
__global__ __launch_bounds__(256) void k_mix(const unsigned int* __restrict__ hft,
                                             const void* __restrict__ sc_w1,
                                             const void* __restrict__ sc_w2,
                                             unsigned int* __restrict__ mixed, int layer,
                                             const float* __restrict__ flg){
    __shared__ float swr[4096], swi[4096];   // [i][o]
    __shared__ float shr[2048], shi[2048];   // [bb][i]
    const bool f32 = (flg[0] > 0.5f);
    int m  = blockIdx.x >> 3;
    int bt = blockIdx.x & 7;
    int b0 = bt * 32;
    int t = threadIdx.x;
    int kyi = m / 12, kx = m - kyi*12;
    const void* w = (kyi < 12) ? sc_w1 : sc_w2;
    int r = (kyi < 12) ? kyi : kyi - 12;
    size_t wbase = (size_t)layer * 64*64*144*2;
    for (int idx = t; idx < 4096; idx += 256){
        size_t off = wbase + (((size_t)idx*12 + r)*12 + kx)*2;   // idx = i*64+o
        swr[idx] = rdf(w, off, f32);
        swi[idx] = rdf(w, off+1, f32);
    }
    const unsigned int* hsrc = hft + (size_t)m*16384 + (size_t)b0*64;
    for (int idx = t; idx < 2048; idx += 256){
        float2 v = unpackbf2(hsrc[idx]);
        shr[idx] = v.x; shi[idx] = v.y;
    }
    __syncthreads();
    int ot = t & 31, bbt = t >> 5;
    int o0 = ot*2, bb0 = bbt*4;
    float ar[4][2], ai[4][2];
    #pragma unroll
    for (int q=0;q<4;++q){ ar[q][0]=0.f; ar[q][1]=0.f; ai[q][0]=0.f; ai[q][1]=0.f; }
    for (int i = 0; i < 64; ++i){
        float w0r = swr[i*64 + o0], w1r = swr[i*64 + o0 + 1];
        float w0i = swi[i*64 + o0], w1i = swi[i*64 + o0 + 1];
        #pragma unroll
        for (int q = 0; q < 4; ++q){
            float hr = shr[(bb0+q)*64 + i];
            float hi = shi[(bb0+q)*64 + i];
            ar[q][0] += hr*w0r - hi*w0i;  ai[q][0] += hr*w0i + hi*w0r;
            ar[q][1] += hr*w1r - hi*w1i;  ai[q][1] += hr*w1i + hi*w1r;
        }
    }
    #pragma unroll
    for (int q = 0; q < 4; ++q)
        #pragma unroll
        for (int j = 0; j < 2; ++j)
            mixed[((size_t)(b0+bb0+q)*64 + o0 + j)*288 + m] = packbf2(ar[q][j], ai[q][j]);
}

// ---------------- pointwise 64x64 channel GEMM (wc path), IN PLACE -----------
// grid 2304 = 256 b x 9 row-groups of 4; block owns rows -> safe in-place
__global__ __launch_bounds__(256) void k_wc(bf16* __restrict__ h,
                                            const void* __restrict__ wc_w,
                                            const void* __restrict__ wc_b,
                                            int layer,
                                            const float* __restrict__ flg){
    __shared__ float sh[64*136];   // [c][px], px = (y-y0)*34 + x
    __shared__ float sw[64*64];    // [c][o]
    __shared__ float sb[64];
    const bool f32 = (flg[0] > 0.5f);
    int blk = blockIdx.x;
    int b = blk / 9, g = blk - b*9;
    int y0 = g*4;
    int nrow = 34 - y0; if (nrow > 4) nrow = 4;
    int t = threadIdx.x;
    size_t wbase = (size_t)layer*4096;
    for (int idx = t; idx < 4096; idx += 256){
        int o = idx >> 6, c = idx & 63;
        sw[c*64 + o] = rdf(wc_w, wbase + idx, f32);
    }
    if (t < 64) sb[t] = rdf(wc_b, layer*64 + t, f32);
    bf16* hb = h + (size_t)b*73984 + y0*34;
    for (int e = t; e < 8704; e += 256){
        int c = e / 136, px = e - c*136;
        sh[e] = bff(hb[(size_t)c*1156 + px]);   // may read garbage past npx; never used
    }
    __syncthreads();
    for (int tau = t; tau < 272; tau += 256){
        int ot = tau / 34, pxt = tau - ot*34;
        int o0 = ot*8;
        float acc[4][8];
        #pragma unroll
        for (int j=0;j<4;++j)
            #pragma unroll
            for (int k=0;k<8;++k) acc[j][k] = sb[o0+k];
        for (int c = 0; c < 64; ++c){
            float hv[4], wv[8];
            #pragma unroll
            for (int j=0;j<4;++j) hv[j] = sh[c*136 + pxt + j*34];
            #pragma unroll
            for (int k=0;k<8;++k) wv[k] = sw[c*64 + o0 + k];
            #pragma unroll
            for (int j=0;j<4;++j)
                #pragma unroll
                for (int k=0;k<8;++k) acc[j][k] += hv[j]*wv[k];
        }
        #pragma unroll
        for (int j=0;j<4;++j){
            if (j < nrow){
                #pragma unroll
                for (int k=0;k<8;++k)
                    hb[(size_t)(o0+k)*1156 + pxt + j*34] = __float2bfloat16(acc[j][k]);
            }
        }
    }
}

// ---------------- inverse truncated DFT, 4 planes per block; in-place add ----
// grid 4096 = 256 b x 16 o-groups
__global__ __launch_bounds__(256) void k_inv(const unsigned int* __restrict__ mixed,
                                             const float* __restrict__ tabs,
                                             bf16* __restrict__ hio, int layer){
    __shared__ float smr[1152], smi[1152];   // [ch][288]
    __shared__ float sgr[3264], sgi[3264];   // [ch][kyi*34+x]
    __shared__ float sWix[816];
    __shared__ float sWiy[1632];
    int blk = blockIdx.x;
    int b = blk >> 4, o0 = (blk & 15) * 4;
    int t = threadIdx.x;
    for (int i = t; i < 816; i += 256) sWix[i] = tabs[2448 + i];
    for (int i = t; i < 1632; i += 256) sWiy[i] = tabs[3264 + i];
    const unsigned int* msrc = mixed + ((size_t)b*64 + o0)*288;
    for (int i = t; i < 1152; i += 256){
        float2 v = unpackbf2(msrc[i]);
        smr[i] = v.x; smi[i] = v.y;
    }
    __syncthreads();
    // step A: g[ch][kyi][x] = sum_kx F[ch][kyi][kx] * Wix[kx][x]
    if (t < 204){
        int kyit = t / 17, xt = t - kyit*17;
        int kyi0 = kyit*2;
        int x0 = xt, x1 = xt + 17;
        float g[4][2][2][2];
        #pragma unroll
        for (int c=0;c<4;++c)
            #pragma unroll
            for (int q=0;q<2;++q){ g[c][q][0][0]=0.f; g[c][q][0][1]=0.f; g[c][q][1][0]=0.f; g[c][q][1][1]=0.f; }
        for (int kx = 0; kx < 12; ++kx){
            float c0 = sWix[(kx*34+x0)*2], s0 = sWix[(kx*34+x0)*2+1];
            float c1 = sWix[(kx*34+x1)*2], s1 = sWix[(kx*34+x1)*2+1];
            #pragma unroll
            for (int c = 0; c < 4; ++c){
                float fr0 = smr[c*288 + kyi0*12 + kx],     fi0 = smi[c*288 + kyi0*12 + kx];
                float fr1 = smr[c*288 + (kyi0+1)*12 + kx], fi1 = smi[c*288 + (kyi0+1)*12 + kx];
                g[c][0][0][0] += fr0*c0 - fi0*s0;  g[c][0][0][1] += fr0*s0 + fi0*c0;
                g[c][0][1][0] += fr0*c1 - fi0*s1;  g[c][0][1][1] += fr0*s1 + fi0*c1;
                g[c][1][0][0] += fr1*c0 - fi1*s0;  g[c][1][0][1] += fr1*s0 + fi1*c0;
                g[c][1][1][0] += fr1*c1 - fi1*s1;  g[c][1][1][1] += fr1*s1 + fi1*c1;
            }
        }
        #pragma unroll
        for (int c = 0; c < 4; ++c)
            #pragma unroll
            for (int q = 0; q < 2; ++q){
                int base = c*816 + (kyi0+q)*34;
                sgr[base + x0] = g[c][q][0][0];  sgi[base + x0] = g[c][q][0][1];
                sgr[base + x1] = g[c][q][1][0];  sgi[base + x1] = g[c][q][1][1];
            }
    }
    __syncthreads();
    // step B: out[ch][y][x] = sum_kyi Re(g[ch][kyi][x] * Wiy[kyi][y])
    if (t < 162){
        int cp = t / 81, rr = t - cp*81;
        int yt = rr / 9, xt = rr - yt*9;
        int ch0 = cp*2;
        float acc[2][4][4];
        #pragma unroll
        for (int c=0;c<2;++c)
            #pragma unroll
            for (int jy=0;jy<4;++jy)
                #pragma unroll
                for (int jx=0;jx<4;++jx) acc[c][jy][jx] = 0.f;
        for (int kyi = 0; kyi < 24; ++kyi){
            float wr[4], wi[4];
            #pragma unroll
            for (int jy = 0; jy < 4; ++jy){
                int y = yt + jy*9;
                bool v = (y < 34);
                int idx = (kyi*34 + (v ? y : 0))*2;
                wr[jy] = v ? sWiy[idx]   : 0.f;
                wi[jy] = v ? sWiy[idx+1] : 0.f;
            }
            float gr[2][4], gi[2][4];
            #pragma unroll
            for (int c = 0; c < 2; ++c)
                #pragma unroll
                for (int jx = 0; jx < 4; ++jx){
                    int x = xt + jx*9;
                    bool v = (x < 34);
                    int idx = (ch0+c)*816 + kyi*34 + (v ? x : 0);
                    gr[c][jx] = v ? sgr[idx] : 0.f;
                    gi[c][jx] = v ? sgi[idx] : 0.f;
                }
            #pragma unroll
            for (int c = 0; c < 2; ++c)
                #pragma unroll
                for (int jy = 0; jy < 4; ++jy)
                    #pragma unroll
                    for (int jx = 0; jx < 4; ++jx)
                        acc[c][jy][jx] += gr[c][jx]*wr[jy] - gi[c][jx]*wi[jy];
        }
        bf16* iob = hio + (size_t)b*73984 + (size_t)o0*1156;
        #pragma unroll
        for (int c = 0; c < 2; ++c)
            #pragma unroll
            for (int jy = 0; jy < 4; ++jy)
                #pragma unroll
                for (int jx = 0; jx < 4; ++jx){
                    int y = yt + jy*9, x = xt + jx*9;
                    if (y < 34 && x < 34){
                        size_t off = (size_t)(ch0+c)*1156 + y*34 + x;
                        float v = acc[c][jy][jx] + bff(iob[off]);
                        if (layer < 3) v = gelu_f(v);
                        iob[off] = __float2bfloat16(v);
                    }
                }
    }
}

// ---------------- 8x8/stride4 VALID conv -> gelu -> pe2 scale ----------------
__global__ __launch_bounds__(256) void k_pe(const bf16* __restrict__ h,
                                            const void* __restrict__ pw,
                                            const void* __restrict__ pb,
                                            const void* __restrict__ p2w,
                                            const void* __restrict__ p2b,
                                            float* __restrict__ p49,
                                            const float* __restrict__ flg){
    __shared__ float red[256];
    const bool f32 = (flg[0] > 0.5f);
    int bid = blockIdx.x;          // b*49 + py*7 + px
    int b = bid / 49, r = bid - b*49;
    int py = r / 7, px = r - py*7;
    int t = threadIdx.x;
    const bf16* hb = h + (size_t)b*73984 + (py*4)*34 + px*4;
    float partial = 0.f;
    for (int tt = t; tt < 4096; tt += 256){
        int c = tt >> 6, k = tt & 63, ky = k >> 3, kx = k & 7;
        partial += bff(hb[(size_t)c*1156 + ky*34 + kx]) * rdf(pw, tt, f32);
    }
    red[t] = partial;
    __syncthreads();
    for (int s = 128; s > 0; s >>= 1){
        if (t < s) red[t] += red[t + s];
        __syncthreads();
    }
    if (t == 0){
        float v = red[0] + rdf(pb, 0, f32);
        v = gelu_f(v);
        p49[bid] = v * rdf(p2w, 0, f32) + rdf(p2b, 0, f32);
    }
}

// ---------------- sentence MLP 384->32->32->16 (relu,relu,lin) ---------------
__global__ __launch_bounds__(64) void k_sent(const void* __restrict__ se,
                                             const void* __restrict__ w1, const void* __restrict__ b1,
                                             const void* __restrict__ w2, const void* __restrict__ b2,
                                             const void* __restrict__ w3, const void* __restrict__ b3,
                                             float* __restrict__ outv,
                                             const float* __restrict__ flg){
    __shared__ float s1[32], s2[32];
    const bool f32 = (flg[0] > 0.5f);
    int b = blockIdx.x, t = threadIdx.x;
    if (t < 32){
        float acc = rdf(b1, t, f32);
        size_t rbase = (size_t)b*384;
        for (int k = 0; k < 384; ++k) acc += rdf(se, rbase + k, f32) * rdf(w1, k*32 + t, f32);
        s1[t] = fmaxf(acc, 0.f);
    }
    __syncthreads();
    if (t < 32){
        float acc = rdf(b2, t, f32);
        for (int k = 0; k < 32; ++k) acc += s1[k] * rdf(w2, k*32 + t, f32);
        s2[t] = fmaxf(acc, 0.f);
    }
    __syncthreads();
    if (t < 16){
        float acc = rdf(b3, t, f32);
        for (int k = 0; k < 32; ++k) acc += s2[k] * rdf(w3, k*16 + t, f32);
        outv[b*16 + t] = acc;
    }
}

// ---------------- xp MLP 49->32->32->16 (silu,silu,lin) ----------------------
__global__ __launch_bounds__(64) void k_xp(const float* __restrict__ p49,
                                           const void* __restrict__ w1, const void* __restrict__ b1,
                                           const void* __restrict__ w2, const void* __restrict__ b2,
                                           const void* __restrict__ w3, const void* __restrict__ b3,
                                           float* __restrict__ outv,
                                           const float* __restrict__ flg){
    __shared__ float s1[32], s2[32];
    const bool f32 = (flg[0] > 0.5f);
    int b = blockIdx.x, t = threadIdx.x;
    if (t < 32){
        float acc = rdf(b1, t, f32);
        const float* row = p49 + b*49;
        for (int k = 0; k < 49; ++k) acc += row[k] * rdf(w1, k*32 + t, f32);
        s1[t] = silu_f(acc);
    }
    __syncthreads();
    if (t < 32){
        float acc = rdf(b2, t, f32);
        for (int k = 0; k < 32; ++k) acc += s1[k] * rdf(w2, k*32 + t, f32);
        s2[t] = silu_f(acc);
    }
    __syncthreads();
    if (t < 16){
        float acc = rdf(b3, t, f32);
        for (int k = 0; k < 32; ++k) acc += s2[k] * rdf(w3, k*16 + t, f32);
        outv[b*16 + t] = acc;
    }
}

// ---------------- pu MLP 32->128->256->1156 (silu,silu,lin) ------------------
__global__ __launch_bounds__(256) void k_pu(const float* __restrict__ xemb,
                                            const float* __restrict__ semb,
                                            const void* __restrict__ w1, const void* __restrict__ b1,
                                            const void* __restrict__ w2, const void* __restrict__ b2,
                                            const void* __restrict__ w3, const void* __restrict__ b3,
                                            float* __restrict__ emb,
                                            const float* __restrict__ flg){
    __shared__ float ein[32];
    __shared__ float h1[128];
    __shared__ float h2[256];
    const bool f32 = (flg[0] > 0.5f);
    int b = blockIdx.x, t = threadIdx.x;
    if (t < 16) ein[t] = xemb[b*16 + t];
    else if (t < 32) ein[t] = semb[b*16 + (t - 16)];
    __syncthreads();
    if (t < 128){
        float acc = rdf(b1, t, f32);
        for (int k = 0; k < 32; ++k) acc += ein[k] * rdf(w1, k*128 + t, f32);
        h1[t] = silu_f(acc);
    }
    __syncthreads();
    {
        float acc = rdf(b2, t, f32);
        for (int k = 0; k < 128; ++k) acc += h1[k] * rdf(w2, k*256 + t, f32);
        h2[t] = silu_f(acc);
    }
    __syncthreads();
    for (int e = t; e < 1156; e += 256){
        float acc = rdf(b3, e, f32);
        for (int k = 0; k < 256; ++k) acc += h2[k] * rdf(w3, k*1156 + e, f32);
        emb[(size_t)b*1156 + e] = acc;
    }
}

// ---------------- final: crop, concat emb, fc1+gelu, fc2 ---------------------
// grid 512 = 256 b x 2 halves; weights staged ONCE per block; 4px x 8j tiles
__global__ __launch_bounds__(256) void k_final(const bf16* __restrict__ h,
                                               const float* __restrict__ emb,
                                               const void* __restrict__ w1, const void* __restrict__ b1,
                                               const void* __restrict__ w2, const void* __restrict__ b2,
                                               void* __restrict__ out,
                                               const float* __restrict__ flg){
    __shared__ unsigned short sw1[8320];   // [c][j] bf16
    __shared__ float sb1[128];
    __shared__ float sw2[512];             // [j][k]
    __shared__ float sb2[4];
    __shared__ unsigned short sinp[4160];  // [c][px] bf16, 64-px tile (2 rows)
    __shared__ unsigned short shid[128*66];// [j][px] bf16, padded row 66
    const bool f32 = (flg[0] > 0.5f);
    int blk = blockIdx.x;
    int b = blk >> 1, g0 = (blk & 1)*8;
    int t = threadIdx.x;
    for (int i = t; i < 8320; i += 256) sw1[i] = f2us(rdf(w1, i, f32));
    if (t < 128) sb1[t] = rdf(b1, t, f32);
    for (int i = t; i < 512; i += 256) sw2[i] = rdf(w2, i, f32);
    if (t < 4) sb2[t] = rdf(b2, t, f32);
    const bf16* hb = h + (size_t)b*73984;
    const float* eb = emb + (size_t)b*1156;
    int pxt = t & 15, jt = t >> 4;
    int j0 = jt*8;
    for (int gg = 0; gg < 8; ++gg){
        int y0 = (g0 + gg)*2;
        __syncthreads();   // also guards weight staging on gg=0, LDS reuse after
        for (int e = t; e < 4160; e += 256){
            int c = e >> 6, p = e & 63;
            int y = y0 + (p >> 5), x = p & 31;
            float v = (c < 64) ? bff(hb[(size_t)c*1156 + y*34 + x]) : eb[y*34 + x];
            sinp[e] = f2us(v);
        }
        __syncthreads();
        float acc[4][8];
        #pragma unroll
        for (int j=0;j<4;++j)
            #pragma unroll
            for (int k=0;k<8;++k) acc[j][k] = sb1[j0+k];
        for (int c = 0; c < 65; ++c){
            float hv[4], wv[8];
            #pragma unroll
            for (int j=0;j<4;++j) hv[j] = us2f(sinp[c*64 + pxt + j*16]);
            #pragma unroll
            for (int k=0;k<8;++k) wv[k] = us2f(sw1[c*128 + j0 + k]);
            #pragma unroll
            for (int j=0;j<4;++j)
                #pragma unroll
                for (int k=0;k<8;++k) acc[j][k] += hv[j]*wv[k];
        }
        #pragma unroll
        for (int j=0;j<4;++j)
            #pragma unroll
            for (int k=0;k<8;++k)
                shid[(j0+k)*66 + pxt + j*16] = f2us(gelu_f(acc[j][k]));
        __syncthreads();
        {
            int px = t >> 2, k = t & 3;
            float a2 = sb2[k];
            for (int j = 0; j < 128; ++j)
                a2 += us2f(shid[j*66 + px]) * sw2[j*4 + k];
            int y = y0 + (px >> 5), x = px & 31;
            size_t o = ((size_t)(b*32 + y)*32 + x)*4 + k;
            if (f32) ((float*)out)[o] = a2;
            else     ((bf16*)out)[o] = __float2bfloat16(a2);
        }
    }
}

extern "C" void kernel_launch(void* const* d_in, const int* in_sizes, int n_in,
                              void* d_out, int out_size, void* d_ws, size_t ws_size,
                              hipStream_t stream) {
    (void)in_sizes; (void)n_in; (void)out_size; (void)ws_size;
    const void* x     = d_in[0];
    const void* grd   = d_in[1];
    const void* se    = d_in[2];
    const void* fc0_w = d_in[3];
    const void* fc0_b = d_in[4];
    const void* sc_w1 = d_in[5];
    const void* sc_w2 = d_in[6];
    const void* wc_w  = d_in[7];
    const void* wc_b  = d_in[8];
    const void* pe1_w = d_in[9];
    const void* pe1_b = d_in[10];
    const void* pe2_w = d_in[11];
    const void* pe2_b = d_in[12];
    const void* sp_w1 = d_in[13];
    const void* sp_b1 = d_in[14];
    const void* sp_w2 = d_in[15];
    const void* sp_b2 = d_in[16];
    const void* sp_w3 = d_in[17];
    const void* sp_b3 = d_in[18];
    const void* xp_w1 = d_in[19];
    const void* xp_b1 = d_in[20];
    const void* xp_w2 = d_in[21];
    const void* xp_b2 = d_in[22];
    const void* xp_w3 = d_in[23];
    const void* xp_b3 = d_in[24];
    const void* pu_w1 = d_in[25];
    const void* pu_b1 = d_in[26];
    const void* pu_w2 = d_in[27];
    const void* pu_b2 = d_in[28];
    const void* pu_w3 = d_in[29];
    const void* pu_b3 = d_in[30];
    const void* fc1_w = d_in[31];
    const void* fc1_b = d_in[32];
    const void* fc2_w = d_in[33];
    const void* fc2_b = d_in[34];

    // workspace layout (float-unit offsets); total ~77 MB
    float* ws    = (float*)d_ws;
    bf16*  hA    = (bf16*)ws;                         // 18,939,904 bf16
    unsigned int* hft   = (unsigned int*)(ws + 9469952);   // 4,718,592 dwords (bf16x2)
    unsigned int* mixed = (unsigned int*)(ws + 14188544);  // 4,718,592 dwords (bf16x2)
    float* tabs  = ws + 18907136;                     // 4,896
    float* p49   = ws + 18912032;                     // 12,544
    float* semb  = ws + 18924576;                     // 4,096
    float* xemb  = ws + 18928672;                     // 4,096
    float* emb   = ws + 18932768;                     // 295,936
    float* flag  = ws + 19228704;                     // 1

    k_probe<<<1, 256, 0, stream>>>(x, flag);
    k_tables<<<1, 256, 0, stream>>>(tabs);
    k_fc0<<<256*34, 256, 0, stream>>>(x, grd, fc0_w, fc0_b, hA, flag);

    for (int l = 0; l < 4; ++l){
        k_fwd<<<4096, 256, 0, stream>>>(hA, hft, tabs);
        k_mix<<<2304, 256, 0, stream>>>(hft, sc_w1, sc_w2, mixed, l, flag);
        k_wc <<<2304, 256, 0, stream>>>(hA, wc_w, wc_b, l, flag);
        k_inv<<<4096, 256, 0, stream>>>(mixed, tabs, hA, l);
    }

    k_pe  <<<256*49, 256, 0, stream>>>(hA, pe1_w, pe1_b, pe2_w, pe2_b, p49, flag);
    k_sent<<<256, 64, 0, stream>>>(se, sp_w1, sp_b1, sp_w2, sp_b2, sp_w3, sp_b3, semb, flag);
    k_xp  <<<256, 64, 0, stream>>>(p49, xp_w1, xp_b1, xp_w2, xp_b2, xp_w3, xp_b3, xemb, flag);
    k_pu  <<<256, 256, 0, stream>>>(xemb, semb, pu_w1, pu_b1, pu_w2, pu_b2, pu_w3, pu_b3, emb, flag);
    k_final<<<512, 256, 0, stream>>>(hA, emb, fc1_w, fc1_b, fc2_w, fc2_b, d_out, flag);
}

// Round 4
// 2039.938 us; speedup vs baseline: 2.1342x; 1.2301x over previous
//
#include <hip/hip_runtime.h>
#include <hip/hip_bf16.h>
#include <math.h>

typedef __hip_bfloat16 bf16;

__device__ __forceinline__ float bff(const bf16 x){ return __bfloat162float(x); }
__device__ __forceinline__ float gelu_f(float v){
    return 0.5f * v * (1.f + erff(v * 0.70710678118654752f));
}
__device__ __forceinline__ float silu_f(float v){
    return v / (1.f + expf(-v));
}
// dtype-agnostic input read: f32 ? fp32 : bf16
__device__ __forceinline__ float rdf(const void* p, size_t i, bool f32){
    return f32 ? ((const float*)p)[i] : __bfloat162float(((const bf16*)p)[i]);
}
__device__ __forceinline__ unsigned int packbf2(float a, float b){
    __hip_bfloat162 v;
    v.x = __float2bfloat16(a);
    v.y = __float2bfloat16(b);
    return *reinterpret_cast<unsigned int*>(&v);
}
__device__ __forceinline__ float2 unpackbf2(unsigned int u){
    __hip_bfloat162 v = *reinterpret_cast<__hip_bfloat162*>(&u);
    return make_float2(__bfloat162float(v.x), __bfloat162float(v.y));
}
__device__ __forceinline__ float us2f(unsigned short u){
    unsigned int x = ((unsigned int)u) << 16;
    return __uint_as_float(x);
}
__device__ __forceinline__ unsigned short f2us(float f){
    bf16 v = __float2bfloat16(f);
    return *reinterpret_cast<unsigned short*>(&v);
}

// Geometry
// B=256, C=64, H=W=34 (padded), modes: ky in {0..11, 22..33} (24), kx in 0..11 (12)
// h layout (ws, bf16): [b][c][y][x], stride c = 1156, stride b = 73984
// hft layout: [m][b*64+c] packed bf16x2 (r,i) dwords, m = kyi*12+kx
// mixed layout: [(b*64+o)*288 + m] packed bf16x2 dwords

// ---------------- dtype probe ----------------
__global__ __launch_bounds__(256) void k_probe(const void* x, float* flag){
    __shared__ int wild;
    int t = threadIdx.x;
    if (t == 0) wild = 0;
    __syncthreads();
    const bf16* xb = (const bf16*)x;
    for (int i = t; i < 1024; i += 256){
        float v = bff(xb[i]);
        if (!(fabsf(v) < 1e10f)) wild = 1;
    }
    __syncthreads();
    if (t == 0) flag[0] = wild ? 1.f : 0.f;
}

// ---------------- tables ----------------
__global__ __launch_bounds__(256) void k_tables(float* tabs){
    int t = threadIdx.x;
    float* Wfy = tabs;          // 24*34*2
    float* Wfx = tabs + 1632;   // 12*34*2
    float* Wix = tabs + 2448;   // 12*34*2
    float* Wiy = tabs + 3264;   // 24*34*2
    const float TWO_PI = 6.283185307179586f;
    for (int e = t; e < 24*34; e += 256){
        int kyi = e / 34, y = e % 34;
        int ky = (kyi < 12) ? kyi : kyi + 10;
        int ph = (ky * y) % 34;
        float ang = TWO_PI * (float)ph / 34.0f;
        float s, c;
        sincosf(ang, &s, &c);
        Wfy[e*2]   = c;   Wfy[e*2+1] = -s;           // e^{-i ang}
        Wiy[e*2]   = c * (1.0f/1156.0f);
        Wiy[e*2+1] = s * (1.0f/1156.0f);             // (1/HW) e^{+i ang}
    }
    for (int e = t; e < 12*34; e += 256){
        int kx = e / 34, x = e % 34;
        int ph = (kx * x) % 34;
        float ang = TWO_PI * (float)ph / 34.0f;
        float s, c;
        sincosf(ang, &s, &c);
        Wfx[e*2] = c; Wfx[e*2+1] = -s;               // e^{-i ang}
        float ck = (kx == 0) ? 1.0f : 2.0f;
        Wix[e*2] = ck * c; Wix[e*2+1] = ck * s;      // c_kx e^{+i ang}
    }
}

// ---------------- fc0: concat(x,grid) @ fc0_w + b, NCHW, zero-pad to 34x34 ----
// 4x-by-2c register tiles: 8 FMA per 6 LDS reads
__global__ __launch_bounds__(256) void k_fc0(const void* __restrict__ xin,
                                             const void* __restrict__ grd,
                                             const void* __restrict__ w,
                                             const void* __restrict__ bias,
                                             bf16* __restrict__ h,
                                             const float* __restrict__ flg){
    __shared__ float sin_[32*42];
    __shared__ float sw[42*64];
    __shared__ float sb[64];
    const bool f32 = (flg[0] > 0.5f);
    int bid = blockIdx.x;          // b*34 + y
    int b = bid / 34, y = bid - b*34;
    int t = threadIdx.x;
    bf16* hb = h + (size_t)b*73984 + y*34;
    if (y >= 32){
        for (int e = t; e < 2176; e += 256){
            int c = e / 34, x = e - c*34;
            hb[(size_t)c*1156 + x] = __float2bfloat16(0.f);
        }
        return;
    }
    for (int idx = t; idx < 2688; idx += 256) sw[idx] = rdf(w, idx, f32);
    if (t < 64) sb[t] = rdf(bias, t, f32);
    size_t xbase = (size_t)(b*32 + y)*32*40;
    for (int idx = t; idx < 1280; idx += 256){
        int x = idx / 40, k = idx - x*40;
        sin_[x*42 + k] = rdf(xin, xbase + idx, f32);
    }
    size_t gbase = (size_t)(b*32 + y)*32*2;
    if (t < 64){
        int x = t >> 1, k2 = t & 1;
        sin_[x*42 + 40 + k2] = rdf(grd, gbase + x*2 + k2, f32);
    }
    __syncthreads();
    {
        int xt = t & 7, ct = t >> 3;    // 8 x-tiles x 32 c-tiles
        int x0 = xt*4, c0 = ct*2;
        float acc[2][4];
        #pragma unroll
        for (int cc=0;cc<2;++cc)
            #pragma unroll
            for (int j=0;j<4;++j) acc[cc][j] = sb[c0+cc];
        for (int k = 0; k < 42; ++k){
            float sv[4], wv[2];
            #pragma unroll
            for (int j=0;j<4;++j) sv[j] = sin_[(x0+j)*42 + k];
            #pragma unroll
            for (int cc=0;cc<2;++cc) wv[cc] = sw[k*64 + c0 + cc];
            #pragma unroll
            for (int cc=0;cc<2;++cc)
                #pragma unroll
                for (int j=0;j<4;++j) acc[cc][j] += sv[j]*wv[cc];
        }
        #pragma unroll
        for (int cc=0;cc<2;++cc)
            #pragma unroll
            for (int j=0;j<4;++j)
                hb[(size_t)(c0+cc)*1156 + x0 + j] = __float2bfloat16(acc[cc][j]);
    }
    for (int e = t; e < 128; e += 256){
        int c = e >> 1, x = 32 + (e & 1);
        hb[(size_t)c*1156 + x] = __float2bfloat16(0.f);
    }
}

// ---------------- forward truncated DFT, 4 channels per block ----------------
// grid 4096 = 256 b x 16 ch-groups; sh packed bf16x2 -> 32KB LDS
__global__ __launch_bounds__(256) void k_fwd(const bf16* __restrict__ h,
                                             unsigned int* __restrict__ hft,
                                             const float* __restrict__ tabs){
    __shared__ unsigned int shp[2312];  // 4 x 578 packed pairs (x even, x+1)
    __shared__ float sWfy[1632];
    __shared__ float sWfx[816];
    __shared__ unsigned int st[3264];   // 4 x 816 packed bf16x2 (G intermediates)
    int blk = blockIdx.x;
    int b = blk >> 4, c0 = (blk & 15) * 4;
    int t = threadIdx.x;
    for (int i = t; i < 1632; i += 256) sWfy[i] = tabs[i];
    for (int i = t; i < 816; i += 256) sWfx[i] = tabs[1632 + i];
    const unsigned int* srcp = (const unsigned int*)(h + (size_t)b*73984 + (size_t)c0*1156);
    for (int i = t; i < 2312; i += 256) shp[i] = srcp[i];
    __syncthreads();
    // step 1: G[ch][kyi][x] = sum_y Wfy[kyi][y] * h[ch][y][x]
    if (t < 204){
        int kyit = t / 17, xt = t - kyit*17;
        int kyi0 = kyit*2, x0 = xt*2;
        float a[4][2][2][2];
        #pragma unroll
        for (int c=0;c<4;++c)
            #pragma unroll
            for (int q=0;q<2;++q){ a[c][q][0][0]=0.f; a[c][q][0][1]=0.f; a[c][q][1][0]=0.f; a[c][q][1][1]=0.f; }
        for (int y = 0; y < 34; ++y){
            int w0 = (kyi0*34 + y)*2, w1 = ((kyi0+1)*34 + y)*2;
            float w0r = sWfy[w0], w0i = sWfy[w0+1];
            float w1r = sWfy[w1], w1i = sWfy[w1+1];
            #pragma unroll
            for (int c = 0; c < 4; ++c){
                float2 hp = unpackbf2(shp[c*578 + y*17 + xt]);
                float h0 = hp.x, h1 = hp.y;
                a[c][0][0][0] += h0*w0r; a[c][0][0][1] += h0*w0i;
                a[c][0][1][0] += h1*w0r; a[c][0][1][1] += h1*w0i;
                a[c][1][0][0] += h0*w1r; a[c][1][0][1] += h0*w1i;
                a[c][1][1][0] += h1*w1r; a[c][1][1][1] += h1*w1i;
            }
        }
        #pragma unroll
        for (int c = 0; c < 4; ++c)
            #pragma unroll
            for (int q = 0; q < 2; ++q){
                int base = c*816 + (kyi0+q)*34 + x0;
                st[base]   = packbf2(a[c][q][0][0], a[c][q][0][1]);
                st[base+1] = packbf2(a[c][q][1][0], a[c][q][1][1]);
            }
    }
    __syncthreads();
    // step 2: F[ch][kyi][kx] = sum_x G[ch][kyi][x] * Wfx[kx][x]
    if (t < 144){
        int kyit = t / 12, kx = t - kyit*12;
        int kyi0 = kyit*2;
        float a[4][2][2];
        #pragma unroll
        for (int c=0;c<4;++c){ a[c][0][0]=0.f; a[c][0][1]=0.f; a[c][1][0]=0.f; a[c][1][1]=0.f; }
        for (int x = 0; x < 34; ++x){
            float cr = sWfx[(kx*34+x)*2], ci = sWfx[(kx*34+x)*2+1];
            #pragma unroll
            for (int c = 0; c < 4; ++c){
                float2 g0 = unpackbf2(st[c*816 + kyi0*34 + x]);
                float2 g1 = unpackbf2(st[c*816 + (kyi0+1)*34 + x]);
                a[c][0][0] += g0.x*cr - g0.y*ci;
                a[c][0][1] += g0.x*ci + g0.y*cr;
                a[c][1][0] += g1.x*cr - g1.y*ci;
                a[c][1][1] += g1.x*ci + g1.y*cr;
            }
        }
        #pragma unroll
        for (int c = 0; c < 4; ++c)
            #pragma unroll
            for (int q = 0; q < 2; ++q){
                int m = (kyi0+q)*12 + kx;
                hft[(size_t)m*16384 + (size_t)b*64 + c0 + c] = packbf2(a[c][q][0], a[c][q][1]);
            }
    }
}

// ---------------- per-mode complex channel mix ----------------
// grid 2304 = 288 modes x 8 batch-tiles of 32; packed w (16KB) + f32 h (16KB)
__global__ __launch_bounds__(256) void k_mix(const unsigned int* __restrict__ hft,
                                             const void* __restrict__ sc_w1,
                                             const void* __restrict__ sc_w2,
                                             unsigned int* __restrict__ mixed, int layer,
                                             const float* __restrict__ flg){
    __shared__ unsigned int swp[4096];       // (wr,wi) per [i*64+o]
    __shared__ float shr[2048], shi[2048];   // [bb][i]
    const bool f32 = (flg[0] > 0.5f);
    int m  = blockIdx.x >> 3;
    int bt = blockIdx.x & 7;
    int b0 = bt * 32;
    int t = threadIdx.x;
    int kyi = m / 12, kx = m - kyi*12;
    const void* w = (kyi < 12) ? sc_w1 : sc_w2;
    int r = (kyi < 12) ? kyi : kyi - 12;
    size_t wbase = (size_t)layer * 64*64*144*2;
    for (int idx = t; idx < 4096; idx += 256){
        size_t off = wbase + (((size_t)idx*12 + r)*12 + kx)*2;   // idx = i*64+o
        swp[idx] = packbf2(rdf(w, off, f32), rdf(w, off+1, f32));
    }
    const unsigned int* hsrc = hft + (size_t)m*16384 + (size_t)b0*64;
    for (int idx = t; idx < 2048; idx += 256){
        float2 v = unpackbf2(hsrc[idx]);
        shr[idx] = v.x; shi[idx] = v.y;
    }
    __syncthreads();
    int ot = t & 31, bbt = t >> 5;
    int o0 = ot*2, bb0 = bbt*4;
    float ar[4][2], ai[4][2];
    #pragma unroll
    for (int q=0;q<4;++q){ ar[q][0]=0.f; ar[q][1]=0.f; ai[q][0]=0.f; ai[q][1]=0.f; }
    for (int i = 0; i < 64; ++i){
        float2 w0 = unpackbf2(swp[i*64 + o0]);
        float2 w1 = unpackbf2(swp[i*64 + o0 + 1]);
        #pragma unroll
        for (int q = 0; q < 4; ++q){
            float hr = shr[(bb0+q)*64 + i];
            float hi = shi[(bb0+q)*64 + i];
            ar[q][0] += hr*w0.x - hi*w0.y;  ai[q][0] += hr*w0.y + hi*w0.x;
            ar[q][1] += hr*w1.x - hi*w1.y;  ai[q][1] += hr*w1.y + hi*w1.x;
        }
    }
    #pragma unroll
    for (int q = 0; q < 4; ++q)
        #pragma unroll
        for (int j = 0; j < 2; ++j)
            mixed[((size_t)(b0+bb0+q)*64 + o0 + j)*288 + m] = packbf2(ar[q][j], ai[q][j]);
}

// ---------------- pointwise 64x64 channel GEMM (wc path), IN PLACE -----------
// grid 2304 = 256 b x 9 row-groups of 4; bf16-packed LDS -> 26KB, 6 blocks/CU
__global__ __launch_bounds__(256) void k_wc(bf16* __restrict__ h,
                                            const void* __restrict__ wc_w,
                                            const void* __restrict__ wc_b,
                                            int layer,
                                            const float* __restrict__ flg){
    __shared__ unsigned int shhp[4352];   // [c][68 dwords] = [c][136 u16 px]
    __shared__ unsigned int swp[2048];    // [c][oh] pairs (o even, o+1)
    __shared__ float sb[64];
    const bool f32 = (flg[0] > 0.5f);
    unsigned short* sh16 = (unsigned short*)shhp;
    int blk = blockIdx.x;
    int b = blk / 9, g = blk - b*9;
    int y0 = g*4;
    int nrow = 34 - y0; if (nrow > 4) nrow = 4;
    int t = threadIdx.x;
    size_t wbase = (size_t)layer*4096;
    for (int idx = t; idx < 2048; idx += 256){
        int oh = idx >> 6, c = idx & 63;
        swp[c*32 + oh] = packbf2(rdf(wc_w, wbase + (size_t)(2*oh)*64 + c, f32),
                                 rdf(wc_w, wbase + (size_t)(2*oh+1)*64 + c, f32));
    }
    if (t < 64) sb[t] = rdf(wc_b, layer*64 + t, f32);
    bf16* hb = h + (size_t)b*73984 + y0*34;
    for (int e = t; e < 4352; e += 256){
        int c = e / 68, d = e - c*68;
        shhp[e] = ((const unsigned int*)(hb + (size_t)c*1156))[d];  // trailing garbage unused
    }
    __syncthreads();
    for (int tau = t; tau < 272; tau += 256){
        int ot = tau / 34, pxt = tau - ot*34;
        int o0 = ot*8;
        float acc[4][8];
        #pragma unroll
        for (int j=0;j<4;++j)
            #pragma unroll
            for (int k=0;k<8;++k) acc[j][k] = sb[o0+k];
        for (int c = 0; c < 64; ++c){
            float hv[4], wv[8];
            #pragma unroll
            for (int j=0;j<4;++j) hv[j] = us2f(sh16[c*136 + pxt + j*34]);
            #pragma unroll
            for (int d=0;d<4;++d){
                float2 wp = unpackbf2(swp[c*32 + (o0>>1) + d]);
                wv[2*d] = wp.x; wv[2*d+1] = wp.y;
            }
            #pragma unroll
            for (int j=0;j<4;++j)
                #pragma unroll
                for (int k=0;k<8;++k) acc[j][k] += hv[j]*wv[k];
        }
        #pragma unroll
        for (int j=0;j<4;++j){
            if (j < nrow){
                #pragma unroll
                for (int k=0;k<8;++k)
                    hb[(size_t)(o0+k)*1156 + pxt + j*34] = __float2bfloat16(acc[j][k]);
            }
        }
    }
}

// ---------------- inverse truncated DFT, 4 planes per block; in-place add ----
// grid 4096 = 256 b x 16 o-groups; packed sm/sg -> 27.5KB LDS, 5 blocks/CU
__global__ __launch_bounds__(256) void k_inv(const unsigned int* __restrict__ mixed,
                                             const float* __restrict__ tabs,
                                             bf16* __restrict__ hio, int layer){
    __shared__ unsigned int smp[1152];   // [ch][288] packed (r,i)
    __shared__ unsigned int sgp[3264];   // [ch][kyi*34+x] packed (gr,gi)
    __shared__ float sWix[816];
    __shared__ float sWiy[1632];
    int blk = blockIdx.x;
    int b = blk >> 4, o0 = (blk & 15) * 4;
    int t = threadIdx.x;
    for (int i = t; i < 816; i += 256) sWix[i] = tabs[2448 + i];
    for (int i = t; i < 1632; i += 256) sWiy[i] = tabs[3264 + i];
    const unsigned int* msrc = mixed + ((size_t)b*64 + o0)*288;
    for (int i = t; i < 1152; i += 256) smp[i] = msrc[i];
    __syncthreads();
    // step A: g[ch][kyi][x] = sum_kx F[ch][kyi][kx] * Wix[kx][x]
    if (t < 204){
        int kyit = t / 17, xt = t - kyit*17;
        int kyi0 = kyit*2;
        int x0 = xt, x1 = xt + 17;
        float g[4][2][2][2];
        #pragma unroll
        for (int c=0;c<4;++c)
            #pragma unroll
            for (int q=0;q<2;++q){ g[c][q][0][0]=0.f; g[c][q][0][1]=0.f; g[c][q][1][0]=0.f; g[c][q][1][1]=0.f; }
        for (int kx = 0; kx < 12; ++kx){
            float c0 = sWix[(kx*34+x0)*2], s0 = sWix[(kx*34+x0)*2+1];
            float c1 = sWix[(kx*34+x1)*2], s1 = sWix[(kx*34+x1)*2+1];
            #pragma unroll
            for (int c = 0; c < 4; ++c){
                float2 f0 = unpackbf2(smp[c*288 + kyi0*12 + kx]);
                float2 f1 = unpackbf2(smp[c*288 + (kyi0+1)*12 + kx]);
                g[c][0][0][0] += f0.x*c0 - f0.y*s0;  g[c][0][0][1] += f0.x*s0 + f0.y*c0;
                g[c][0][1][0] += f0.x*c1 - f0.y*s1;  g[c][0][1][1] += f0.x*s1 + f0.y*c1;
                g[c][1][0][0] += f1.x*c0 - f1.y*s0;  g[c][1][0][1] += f1.x*s0 + f1.y*c0;
                g[c][1][1][0] += f1.x*c1 - f1.y*s1;  g[c][1][1][1] += f1.x*s1 + f1.y*c1;
            }
        }
        #pragma unroll
        for (int c = 0; c < 4; ++c)
            #pragma unroll
            for (int q = 0; q < 2; ++q){
                int base = c*816 + (kyi0+q)*34;
                sgp[base + x0] = packbf2(g[c][q][0][0], g[c][q][0][1]);
                sgp[base + x1] = packbf2(g[c][q][1][0], g[c][q][1][1]);
            }
    }
    __syncthreads();
    // step B: out[ch][y][x] = sum_kyi Re(g[ch][kyi][x] * Wiy[kyi][y])
    if (t < 162){
        int cp = t / 81, rr = t - cp*81;
        int yt = rr / 9, xt = rr - yt*9;
        int ch0 = cp*2;
        float acc[2][4][4];
        #pragma unroll
        for (int c=0;c<2;++c)
            #pragma unroll
            for (int jy=0;jy<4;++jy)
                #pragma unroll
                for (int jx=0;jx<4;++jx) acc[c][jy][jx] = 0.f;
        for (int kyi = 0; kyi < 24; ++kyi){
            float wr[4], wi[4];
            #pragma unroll
            for (int jy = 0; jy < 4; ++jy){
                int y = yt + jy*9;
                bool v = (y < 34);
                int idx = (kyi*34 + (v ? y : 0))*2;
                wr[jy] = v ? sWiy[idx]   : 0.f;
                wi[jy] = v ? sWiy[idx+1] : 0.f;
            }
            float gr[2][4], gi[2][4];
            #pragma unroll
            for (int c = 0; c < 2; ++c)
                #pragma unroll
                for (int jx = 0; jx < 4; ++jx){
                    int x = xt + jx*9;
                    bool v = (x < 34);
                    float2 gg = unpackbf2(sgp[(ch0+c)*816 + kyi*34 + (v ? x : 0)]);
                    gr[c][jx] = v ? gg.x : 0.f;
                    gi[c][jx] = v ? gg.y : 0.f;
                }
            #pragma unroll
            for (int c = 0; c < 2; ++c)
                #pragma unroll
                for (int jy = 0; jy < 4; ++jy)
                    #pragma unroll
                    for (int jx = 0; jx < 4; ++jx)
                        acc[c][jy][jx] += gr[c][jx]*wr[jy] - gi[c][jx]*wi[jy];
        }
        bf16* iob = hio + (size_t)b*73984 + (size_t)o0*1156;
        #pragma unroll
        for (int c = 0; c < 2; ++c)
            #pragma unroll
            for (int jy = 0; jy < 4; ++jy)
                #pragma unroll
                for (int jx = 0; jx < 4; ++jx){
                    int y = yt + jy*9, x = xt + jx*9;
                    if (y < 34 && x < 34){
                        size_t off = (size_t)(ch0+c)*1156 + y*34 + x;
                        float v = acc[c][jy][jx] + bff(iob[off]);
                        if (layer < 3) v = gelu_f(v);
                        iob[off] = __float2bfloat16(v);
                    }
                }
    }
}

// ---------------- 8x8/stride4 VALID conv -> gelu -> pe2 scale ----------------
__global__ __launch_bounds__(256) void k_pe(const bf16* __restrict__ h,
                                            const void* __restrict__ pw,
                                            const void* __restrict__ pb,
                                            const void* __restrict__ p2w,
                                            const void* __restrict__ p2b,
                                            float* __restrict__ p49,
                                            const float* __restrict__ flg){
    __shared__ float red[256];
    const bool f32 = (flg[0] > 0.5f);
    int bid = blockIdx.x;          // b*49 + py*7 + px
    int b = bid / 49, r = bid - b*49;
    int py = r / 7, px = r - py*7;
    int t = threadIdx.x;
    const bf16* hb = h + (size_t)b*73984 + (py*4)*34 + px*4;
    float partial = 0.f;
    for (int tt = t; tt < 4096; tt += 256){
        int c = tt >> 6, k = tt & 63, ky = k >> 3, kx = k & 7;
        partial += bff(hb[(size_t)c*1156 + ky*34 + kx]) * rdf(pw, tt, f32);
    }
    red[t] = partial;
    __syncthreads();
    for (int s = 128; s > 0; s >>= 1){
        if (t < s) red[t] += red[t + s];
        __syncthreads();
    }
    if (t == 0){
        float v = red[0] + rdf(pb, 0, f32);
        v = gelu_f(v);
        p49[bid] = v * rdf(p2w, 0, f32) + rdf(p2b, 0, f32);
    }
}

// ---------------- sentence MLP 384->32->32->16 (relu,relu,lin) ---------------
__global__ __launch_bounds__(64) void k_sent(const void* __restrict__ se,
                                             const void* __restrict__ w1, const void* __restrict__ b1,
                                             const void* __restrict__ w2, const void* __restrict__ b2,
                                             const void* __restrict__ w3, const void* __restrict__ b3,
                                             float* __restrict__ outv,
                                             const float* __restrict__ flg){
    __shared__ float s1[32], s2[32];
    const bool f32 = (flg[0] > 0.5f);
    int b = blockIdx.x, t = threadIdx.x;
    if (t < 32){
        float acc = rdf(b1, t, f32);
        size_t rbase = (size_t)b*384;
        for (int k = 0; k < 384; ++k) acc += rdf(se, rbase + k, f32) * rdf(w1, k*32 + t, f32);
        s1[t] = fmaxf(acc, 0.f);
    }
    __syncthreads();
    if (t < 32){
        float acc = rdf(b2, t, f32);
        for (int k = 0; k < 32; ++k) acc += s1[k] * rdf(w2, k*32 + t, f32);
        s2[t] = fmaxf(acc, 0.f);
    }
    __syncthreads();
    if (t < 16){
        float acc = rdf(b3, t, f32);
        for (int k = 0; k < 32; ++k) acc += s2[k] * rdf(w3, k*16 + t, f32);
        outv[b*16 + t] = acc;
    }
}

// ---------------- xp MLP 49->32->32->16 (silu,silu,lin) ----------------------
__global__ __launch_bounds__(64) void k_xp(const float* __restrict__ p49,
                                           const void* __restrict__ w1, const void* __restrict__ b1,
                                           const void* __restrict__ w2, const void* __restrict__ b2,
                                           const void* __restrict__ w3, const void* __restrict__ b3,
                                           float* __restrict__ outv,
                                           const float* __restrict__ flg){
    __shared__ float s1[32], s2[32];
    const bool f32 = (flg[0] > 0.5f);
    int b = blockIdx.x, t = threadIdx.x;
    if (t < 32){
        float acc = rdf(b1, t, f32);
        const float* row = p49 + b*49;
        for (int k = 0; k < 49; ++k) acc += row[k] * rdf(w1, k*32 + t, f32);
        s1[t] = silu_f(acc);
    }
    __syncthreads();
    if (t < 32){
        float acc = rdf(b2, t, f32);
        for (int k = 0; k < 32; ++k) acc += s1[k] * rdf(w2, k*32 + t, f32);
        s2[t] = silu_f(acc);
    }
    __syncthreads();
    if (t < 16){
        float acc = rdf(b3, t, f32);
        for (int k = 0; k < 32; ++k) acc += s2[k] * rdf(w3, k*16 + t, f32);
        outv[b*16 + t] = acc;
    }
}

// ---------------- pu MLP part A: 32->128->256 (silu,silu) --------------------
__global__ __launch_bounds__(256) void k_puA(const float* __restrict__ xemb,
                                             const float* __restrict__ semb,
                                             const void* __restrict__ w1, const void* __restrict__ b1,
                                             const void* __restrict__ w2, const void* __restrict__ b2,
                                             float* __restrict__ h2buf,
                                             const float* __restrict__ flg){
    __shared__ float ein[32];
    __shared__ float h1[128];
    const bool f32 = (flg[0] > 0.5f);
    int b = blockIdx.x, t = threadIdx.x;
    if (t < 16) ein[t] = xemb[b*16 + t];
    else if (t < 32) ein[t] = semb[b*16 + (t - 16)];
    __syncthreads();
    if (t < 128){
        float acc = rdf(b1, t, f32);
        for (int k = 0; k < 32; ++k) acc += ein[k] * rdf(w1, k*128 + t, f32);
        h1[t] = silu_f(acc);
    }
    __syncthreads();
    {
        float acc = rdf(b2, t, f32);
        for (int k = 0; k < 128; ++k) acc += h1[k] * rdf(w2, k*256 + t, f32);
        h2buf[(size_t)b*256 + t] = silu_f(acc);
    }
}

// ---------------- pu MLP part B: 256->1156 GEMM ------------------------------
// grid 1280 = 256 b (fast) x 5 n-chunks of 232
__global__ __launch_bounds__(256) void k_puB(const float* __restrict__ h2buf,
                                             const void* __restrict__ w3, const void* __restrict__ b3,
                                             float* __restrict__ emb,
                                             const float* __restrict__ flg){
    __shared__ float sh2[256];
    const bool f32 = (flg[0] > 0.5f);
    int blk = blockIdx.x;
    int b = blk & 255, nc = blk >> 8;
    int t = threadIdx.x;
    sh2[t] = h2buf[(size_t)b*256 + t];
    __syncthreads();
    int e = nc*232 + t;
    if (t < 232 && e < 1156){
        float acc = rdf(b3, e, f32);
        if (f32){
            const float* wp = (const float*)w3 + e;
            #pragma unroll 4
            for (int k = 0; k < 256; ++k) acc += sh2[k] * wp[(size_t)k*1156];
        } else {
            const bf16* wp = (const bf16*)w3 + e;
            #pragma unroll 4
            for (int k = 0; k < 256; ++k) acc += sh2[k] * bff(wp[(size_t)k*1156]);
        }
        emb[(size_t)b*1156 + e] = acc;
    }
}

// ---------------- final: crop, concat emb, fc1+gelu, fc2 ---------------------
// grid 512 = 256 b x 2 halves; 4 iters of 4 rows (128 px); 8px x 8j dword tiles
__global__ __launch_bounds__(256) void k_final(const bf16* __restrict__ h,
                                               const float* __restrict__ emb,
                                               const void* __restrict__ w1, const void* __restrict__ b1,
                                               const void* __restrict__ w2, const void* __restrict__ b2,
                                               void* __restrict__ out,
                                               const float* __restrict__ flg){
    __shared__ unsigned int sw1p[4160];     // [c][j/2] packed pairs (j even)
    __shared__ float sb1[128];
    __shared__ float sw2[512];              // [j][k]
    __shared__ float sb2[4];
    __shared__ unsigned int sinpp[4160];    // [c][px/2] packed pairs
    __shared__ unsigned short shid[128*132];// [j][px] bf16 padded
    const bool f32 = (flg[0] > 0.5f);
    int blk = blockIdx.x;
    int b = blk >> 1, half = blk & 1;
    int t = threadIdx.x;
    for (int i = t; i < 4160; i += 256){
        int c = i >> 6, j2 = i & 63;
        sw1p[i] = packbf2(rdf(w1, (size_t)c*128 + j2*2, f32),
                          rdf(w1, (size_t)c*128 + j2*2 + 1, f32));
    }
    if (t < 128) sb1[t] = rdf(b1, t, f32);
    for (int i = t; i < 512; i += 256) sw2[i] = rdf(w2, i, f32);
    if (t < 4) sb2[t] = rdf(b2, t, f32);
    const bf16* hb = h + (size_t)b*73984;
    const float* eb = emb + (size_t)b*1156;
    int pxt = t & 15, jt = t >> 4;   // 16 x 16
    int px0 = pxt*8, j0 = jt*8;
    for (int it = 0; it < 4; ++it){
        int y0 = half*16 + it*4;     // 4 rows = 128 px
        __syncthreads();
        for (int i = t; i < 4160; i += 256){
            int c = i >> 6, p2 = i & 63;
            int px = p2*2;
            int y = y0 + (px >> 5), x = px & 31;
            float v0 = (c < 64) ? bff(hb[(size_t)c*1156 + y*34 + x]) : eb[y*34 + x];
            int px1 = px + 1;
            int y1 = y0 + (px1 >> 5), x1 = px1 & 31;
            float v1 = (c < 64) ? bff(hb[(size_t)c*1156 + y1*34 + x1]) : eb[y1*34 + x1];
            sinpp[i] = packbf2(v0, v1);
        }
        __syncthreads();
        float acc[8][8];
        #pragma unroll
        for (int j=0;j<8;++j)
            #pragma unroll
            for (int k=0;k<8;++k) acc[j][k] = sb1[j0+k];
        for (int c = 0; c < 65; ++c){
            float hv[8], wv[8];
            #pragma unroll
            for (int d = 0; d < 4; ++d){
                float2 hp = unpackbf2(sinpp[c*64 + (px0>>1) + d]);
                hv[2*d] = hp.x; hv[2*d+1] = hp.y;
                float2 wp = unpackbf2(sw1p[c*64 + (j0>>1) + d]);
                wv[2*d] = wp.x; wv[2*d+1] = wp.y;
            }
            #pragma unroll
            for (int j=0;j<8;++j)
                #pragma unroll
                for (int k=0;k<8;++k) acc[j][k] += hv[j]*wv[k];
        }
        #pragma unroll
        for (int j=0;j<8;++j)
            #pragma unroll
            for (int k=0;k<8;++k)
                shid[(j0+k)*132 + px0 + j] = f2us(gelu_f(acc[j][k]));
        __syncthreads();
        {
            int px = t & 127, kk = t >> 7;   // kk in {0,1} -> k = 2kk, 2kk+1
            float a0 = sb2[kk*2], a1 = sb2[kk*2+1];
            for (int j = 0; j < 128; ++j){
                float hvv = us2f(shid[j*132 + px]);
                a0 += hvv * sw2[j*4 + kk*2];
                a1 += hvv * sw2[j*4 + kk*2 + 1];
            }
            int y = y0 + (px >> 5), x = px & 31;
            size_t o = ((size_t)(b*32 + y)*32 + x)*4 + kk*2;
            if (f32){ ((float*)out)[o] = a0; ((float*)out)[o+1] = a1; }
            else { ((bf16*)out)[o] = __float2bfloat16(a0); ((bf16*)out)[o+1] = __float2bfloat16(a1); }
        }
    }
}

extern "C" void kernel_launch(void* const* d_in, const int* in_sizes, int n_in,
                              void* d_out, int out_size, void* d_ws, size_t ws_size,
                              hipStream_t stream) {
    (void)in_sizes; (void)n_in; (void)out_size; (void)ws_size;
    const void* x     = d_in[0];
    const void* grd   = d_in[1];
    const void* se    = d_in[2];
    const void* fc0_w = d_in[3];
    const void* fc0_b = d_in[4];
    const void* sc_w1 = d_in[5];
    const void* sc_w2 = d_in[6];
    const void* wc_w  = d_in[7];
    const void* wc_b  = d_in[8];
    const void* pe1_w = d_in[9];
    const void* pe1_b = d_in[10];
    const void* pe2_w = d_in[11];
    const void* pe2_b = d_in[12];
    const void* sp_w1 = d_in[13];
    const void* sp_b1 = d_in[14];
    const void* sp_w2 = d_in[15];
    const void* sp_b2 = d_in[16];
    const void* sp_w3 = d_in[17];
    const void* sp_b3 = d_in[18];
    const void* xp_w1 = d_in[19];
    const void* xp_b1 = d_in[20];
    const void* xp_w2 = d_in[21];
    const void* xp_b2 = d_in[22];
    const void* xp_w3 = d_in[23];
    const void* xp_b3 = d_in[24];
    const void* pu_w1 = d_in[25];
    const void* pu_b1 = d_in[26];
    const void* pu_w2 = d_in[27];
    const void* pu_b2 = d_in[28];
    const void* pu_w3 = d_in[29];
    const void* pu_b3 = d_in[30];
    const void* fc1_w = d_in[31];
    const void* fc1_b = d_in[32];
    const void* fc2_w = d_in[33];
    const void* fc2_b = d_in[34];

    // workspace layout (float-unit offsets); total ~77 MB
    float* ws    = (float*)d_ws;
    bf16*  hA    = (bf16*)ws;                              // 18,939,904 bf16
    unsigned int* hft   = (unsigned int*)(ws + 9469952);   // 4,718,592 dwords
    unsigned int* mixed = (unsigned int*)(ws + 14188544);  // 4,718,592 dwords
    float* tabs  = ws + 18907136;                          // 4,896
    float* p49   = ws + 18912032;                          // 12,544
    float* semb  = ws + 18924576;                          // 4,096
    float* xemb  = ws + 18928672;                          // 4,096
    float* emb   = ws + 18932768;                          // 295,936
    float* flag  = ws + 19228704;                          // 1
    float* h2buf = (float*)hft;                            // reuse: hft dead after layer loop

    k_probe<<<1, 256, 0, stream>>>(x, flag);
    k_tables<<<1, 256, 0, stream>>>(tabs);
    k_fc0<<<256*34, 256, 0, stream>>>(x, grd, fc0_w, fc0_b, hA, flag);

    for (int l = 0; l < 4; ++l){
        k_fwd<<<4096, 256, 0, stream>>>(hA, hft, tabs);
        k_mix<<<2304, 256, 0, stream>>>(hft, sc_w1, sc_w2, mixed, l, flag);
        k_wc <<<2304, 256, 0, stream>>>(hA, wc_w, wc_b, l, flag);
        k_inv<<<4096, 256, 0, stream>>>(mixed, tabs, hA, l);
    }

    k_pe  <<<256*49, 256, 0, stream>>>(hA, pe1_w, pe1_b, pe2_w, pe2_b, p49, flag);
    k_sent<<<256, 64, 0, stream>>>(se, sp_w1, sp_b1, sp_w2, sp_b2, sp_w3, sp_b3, semb, flag);
    k_xp  <<<256, 64, 0, stream>>>(p49, xp_w1, xp_b1, xp_w2, xp_b2, xp_w3, xp_b3, xemb, flag);
    k_puA <<<256, 256, 0, stream>>>(xemb, semb, pu_w1, pu_b1, pu_w2, pu_b2, h2buf, flag);
    k_puB <<<1280, 256, 0, stream>>>(h2buf, pu_w3, pu_b3, emb, flag);
    k_final<<<512, 256, 0, stream>>>(hA, emb, fc1_w, fc1_b, fc2_w, fc2_b, d_out, flag);
}

// Round 5
// 1792.208 us; speedup vs baseline: 2.4292x; 1.1382x over previous
//
#include <hip/hip_runtime.h>
#include <hip/hip_bf16.h>
#include <math.h>

typedef __hip_bfloat16 bf16;
typedef __bf16 bfv8 __attribute__((ext_vector_type(8)));
typedef float fv4 __attribute__((ext_vector_type(4)));

__device__ __forceinline__ float bff(const bf16 x){ return __bfloat162float(x); }
__device__ __forceinline__ float gelu_f(float v){
    return 0.5f * v * (1.f + erff(v * 0.70710678118654752f));
}
__device__ __forceinline__ float silu_f(float v){
    return v / (1.f + expf(-v));
}
// dtype-agnostic input read: f32 ? fp32 : bf16
__device__ __forceinline__ float rdf(const void* p, size_t i, bool f32){
    return f32 ? ((const float*)p)[i] : __bfloat162float(((const bf16*)p)[i]);
}
__device__ __forceinline__ unsigned int packbf2(float a, float b){
    __hip_bfloat162 v;
    v.x = __float2bfloat16(a);
    v.y = __float2bfloat16(b);
    return *reinterpret_cast<unsigned int*>(&v);
}
__device__ __forceinline__ float2 unpackbf2(unsigned int u){
    __hip_bfloat162 v = *reinterpret_cast<__hip_bfloat162*>(&u);
    return make_float2(__bfloat162float(v.x), __bfloat162float(v.y));
}
__device__ __forceinline__ float us2f(unsigned short u){
    unsigned int x = ((unsigned int)u) << 16;
    return __uint_as_float(x);
}
__device__ __forceinline__ unsigned short f2us(float f){
    bf16 v = __float2bfloat16(f);
    return *reinterpret_cast<unsigned short*>(&v);
}

// Geometry
// B=256, C=64, H=W=34 (padded), modes: ky in {0..11, 22..33} (24), kx in 0..11 (12)
// h layout (ws, bf16): [b][c][y][x], stride c = 1156, stride b = 73984
// hftA layout: [m][b][k] bf16, k in [0,128): k<64 = Re(F)[c=k], k>=64 = Im(F)[c=k-64]
// mixed layout: [(b*64+o)*288 + m] packed bf16x2 dwords (r,i)

// ---------------- dtype probe ----------------
__global__ __launch_bounds__(256) void k_probe(const void* x, float* flag){
    __shared__ int wild;
    int t = threadIdx.x;
    if (t == 0) wild = 0;
    __syncthreads();
    const bf16* xb = (const bf16*)x;
    for (int i = t; i < 1024; i += 256){
        float v = bff(xb[i]);
        if (!(fabsf(v) < 1e10f)) wild = 1;
    }
    __syncthreads();
    if (t == 0) flag[0] = wild ? 1.f : 0.f;
}

// ---------------- tables ----------------
__global__ __launch_bounds__(256) void k_tables(float* tabs){
    int t = threadIdx.x;
    float* Wfy = tabs;          // 24*34*2
    float* Wfx = tabs + 1632;   // 12*34*2
    float* Wix = tabs + 2448;   // 12*34*2
    float* Wiy = tabs + 3264;   // 24*34*2
    const float TWO_PI = 6.283185307179586f;
    for (int e = t; e < 24*34; e += 256){
        int kyi = e / 34, y = e % 34;
        int ky = (kyi < 12) ? kyi : kyi + 10;
        int ph = (ky * y) % 34;
        float ang = TWO_PI * (float)ph / 34.0f;
        float s, c;
        sincosf(ang, &s, &c);
        Wfy[e*2]   = c;   Wfy[e*2+1] = -s;           // e^{-i ang}
        Wiy[e*2]   = c * (1.0f/1156.0f);
        Wiy[e*2+1] = s * (1.0f/1156.0f);             // (1/HW) e^{+i ang}
    }
    for (int e = t; e < 12*34; e += 256){
        int kx = e / 34, x = e % 34;
        int ph = (kx * x) % 34;
        float ang = TWO_PI * (float)ph / 34.0f;
        float s, c;
        sincosf(ang, &s, &c);
        Wfx[e*2] = c; Wfx[e*2+1] = -s;               // e^{-i ang}
        float ck = (kx == 0) ? 1.0f : 2.0f;
        Wix[e*2] = ck * c; Wix[e*2+1] = ck * s;      // c_kx e^{+i ang}
    }
}

// ---------------- fc0: concat(x,grid) @ fc0_w + b, NCHW, zero-pad to 34x34 ----
__global__ __launch_bounds__(256) void k_fc0(const void* __restrict__ xin,
                                             const void* __restrict__ grd,
                                             const void* __restrict__ w,
                                             const void* __restrict__ bias,
                                             bf16* __restrict__ h,
                                             const float* __restrict__ flg){
    __shared__ float sin_[32*42];
    __shared__ float sw[42*64];
    __shared__ float sb[64];
    const bool f32 = (flg[0] > 0.5f);
    int bid = blockIdx.x;          // b*34 + y
    int b = bid / 34, y = bid - b*34;
    int t = threadIdx.x;
    bf16* hb = h + (size_t)b*73984 + y*34;
    if (y >= 32){
        for (int e = t; e < 2176; e += 256){
            int c = e / 34, x = e - c*34;
            hb[(size_t)c*1156 + x] = __float2bfloat16(0.f);
        }
        return;
    }
    for (int idx = t; idx < 2688; idx += 256) sw[idx] = rdf(w, idx, f32);
    if (t < 64) sb[t] = rdf(bias, t, f32);
    size_t xbase = (size_t)(b*32 + y)*32*40;
    for (int idx = t; idx < 1280; idx += 256){
        int x = idx / 40, k = idx - x*40;
        sin_[x*42 + k] = rdf(xin, xbase + idx, f32);
    }
    size_t gbase = (size_t)(b*32 + y)*32*2;
    if (t < 64){
        int x = t >> 1, k2 = t & 1;
        sin_[x*42 + 40 + k2] = rdf(grd, gbase + x*2 + k2, f32);
    }
    __syncthreads();
    {
        int xt = t & 7, ct = t >> 3;    // 8 x-tiles x 32 c-tiles
        int x0 = xt*4, c0 = ct*2;
        float acc[2][4];
        #pragma unroll
        for (int cc=0;cc<2;++cc)
            #pragma unroll
            for (int j=0;j<4;++j) acc[cc][j] = sb[c0+cc];
        for (int k = 0; k < 42; ++k){
            float sv[4], wv[2];
            #pragma unroll
            for (int j=0;j<4;++j) sv[j] = sin_[(x0+j)*42 + k];
            #pragma unroll
            for (int cc=0;cc<2;++cc) wv[cc] = sw[k*64 + c0 + cc];
            #pragma unroll
            for (int cc=0;cc<2;++cc)
                #pragma unroll
                for (int j=0;j<4;++j) acc[cc][j] += sv[j]*wv[cc];
        }
        #pragma unroll
        for (int cc=0;cc<2;++cc)
            #pragma unroll
            for (int j=0;j<4;++j)
                hb[(size_t)(c0+cc)*1156 + x0 + j] = __float2bfloat16(acc[cc][j]);
    }
    for (int e = t; e < 128; e += 256){
        int c = e >> 1, x = 32 + (e & 1);
        hb[(size_t)c*1156 + x] = __float2bfloat16(0.f);
    }
}

// ---------------- forward truncated DFT, 4 channels per block ----------------
// grid 4096 = 256 b x 16 ch-groups; writes hftA [m][b][k] (A-panel layout)
__global__ __launch_bounds__(256) void k_fwd(const bf16* __restrict__ h,
                                             unsigned int* __restrict__ hftA,
                                             const float* __restrict__ tabs){
    __shared__ unsigned int shp[2312];  // 4 x 578 packed pairs (x even, x+1)
    __shared__ float sWfy[1632];
    __shared__ float sWfx[816];
    __shared__ unsigned int st[3264];   // 4 x 816 packed bf16x2 (G intermediates)
    int blk = blockIdx.x;
    int b = blk >> 4, c0 = (blk & 15) * 4;
    int t = threadIdx.x;
    for (int i = t; i < 1632; i += 256) sWfy[i] = tabs[i];
    for (int i = t; i < 816; i += 256) sWfx[i] = tabs[1632 + i];
    const unsigned int* srcp = (const unsigned int*)(h + (size_t)b*73984 + (size_t)c0*1156);
    for (int i = t; i < 2312; i += 256) shp[i] = srcp[i];
    __syncthreads();
    // step 1: G[ch][kyi][x] = sum_y Wfy[kyi][y] * h[ch][y][x]
    if (t < 204){
        int kyit = t / 17, xt = t - kyit*17;
        int kyi0 = kyit*2, x0 = xt*2;
        float a[4][2][2][2];
        #pragma unroll
        for (int c=0;c<4;++c)
            #pragma unroll
            for (int q=0;q<2;++q){ a[c][q][0][0]=0.f; a[c][q][0][1]=0.f; a[c][q][1][0]=0.f; a[c][q][1][1]=0.f; }
        for (int y = 0; y < 34; ++y){
            int w0 = (kyi0*34 + y)*2, w1 = ((kyi0+1)*34 + y)*2;
            float w0r = sWfy[w0], w0i = sWfy[w0+1];
            float w1r = sWfy[w1], w1i = sWfy[w1+1];
            #pragma unroll
            for (int c = 0; c < 4; ++c){
                float2 hp = unpackbf2(shp[c*578 + y*17 + xt]);
                float h0 = hp.x, h1 = hp.y;
                a[c][0][0][0] += h0*w0r; a[c][0][0][1] += h0*w0i;
                a[c][0][1][0] += h1*w0r; a[c][0][1][1] += h1*w0i;
                a[c][1][0][0] += h0*w1r; a[c][1][0][1] += h0*w1i;
                a[c][1][1][0] += h1*w1r; a[c][1][1][1] += h1*w1i;
            }
        }
        #pragma unroll
        for (int c = 0; c < 4; ++c)
            #pragma unroll
            for (int q = 0; q < 2; ++q){
                int base = c*816 + (kyi0+q)*34 + x0;
                st[base]   = packbf2(a[c][q][0][0], a[c][q][0][1]);
                st[base+1] = packbf2(a[c][q][1][0], a[c][q][1][1]);
            }
    }
    __syncthreads();
    // step 2: F[ch][kyi][kx] = sum_x G[ch][kyi][x] * Wfx[kx][x]
    if (t < 144){
        int kyit = t / 12, kx = t - kyit*12;
        int kyi0 = kyit*2;
        float a[4][2][2];
        #pragma unroll
        for (int c=0;c<4;++c){ a[c][0][0]=0.f; a[c][0][1]=0.f; a[c][1][0]=0.f; a[c][1][1]=0.f; }
        for (int x = 0; x < 34; ++x){
            float cr = sWfx[(kx*34+x)*2], ci = sWfx[(kx*34+x)*2+1];
            #pragma unroll
            for (int c = 0; c < 4; ++c){
                float2 g0 = unpackbf2(st[c*816 + kyi0*34 + x]);
                float2 g1 = unpackbf2(st[c*816 + (kyi0+1)*34 + x]);
                a[c][0][0] += g0.x*cr - g0.y*ci;
                a[c][0][1] += g0.x*ci + g0.y*cr;
                a[c][1][0] += g1.x*cr - g1.y*ci;
                a[c][1][1] += g1.x*ci + g1.y*cr;
            }
        }
        // hftA[m][b][k]: real at k=c0..c0+3, imag at k=64+c0..64+c0+3 (dword-packed)
        #pragma unroll
        for (int q = 0; q < 2; ++q){
            int m = (kyi0+q)*12 + kx;
            size_t base = (size_t)m*16384 + (size_t)b*64 + (c0 >> 1);
            hftA[base]      = packbf2(a[0][q][0], a[1][q][0]);
            hftA[base + 1]  = packbf2(a[2][q][0], a[3][q][0]);
            hftA[base + 32] = packbf2(a[0][q][1], a[1][q][1]);
            hftA[base + 33] = packbf2(a[2][q][1], a[3][q][1]);
        }
    }
}

// ---------------- per-mode channel mix as bf16 MFMA GEMM ---------------------
// grid 576 = 288 modes x 2 M-halves of 128; C[128,128] = A[128,128] x B[128,128]
// A = [Hr | Hi] (direct from hftA), B = [[Wr, Wi], [-Wi, Wr]] staged as BT in LDS
__global__ __launch_bounds__(256) void k_mixm(const unsigned short* __restrict__ hftA,
                                              const void* __restrict__ sc_w1,
                                              const void* __restrict__ sc_w2,
                                              unsigned int* __restrict__ mixed, int layer,
                                              const float* __restrict__ flg){
    __shared__ unsigned short sB[128*136];   // BT[n][k], row stride 136 (conflict-free frags)
    const bool f32 = (flg[0] > 0.5f);
    int m  = blockIdx.x >> 1;
    int mh = blockIdx.x & 1;
    int b0 = mh * 128;
    int t = threadIdx.x;
    int kyi = m / 12, kx = m - kyi*12;
    const void* w = (kyi < 12) ? sc_w1 : sc_w2;
    int r = (kyi < 12) ? kyi : kyi - 12;
    size_t wbase = (size_t)layer * 64*64*144*2;
    for (int idx = t; idx < 4096; idx += 256){     // idx = i*64+o
        int i = idx >> 6, o = idx & 63;
        size_t off = wbase + (((size_t)idx*12 + r)*12 + kx)*2;
        float wr = rdf(w, off, f32);
        float wi = rdf(w, off+1, f32);
        sB[o*136 + i]           = f2us(wr);
        sB[(o+64)*136 + i]      = f2us(wi);
        sB[o*136 + i + 64]      = f2us(-wi);
        sB[(o+64)*136 + i + 64] = f2us(wr);
    }
    __syncthreads();
    int ln = t & 15, qd = (t & 63) >> 4, wv = t >> 6;
    // A fragments: A[row=b0+wv*32+tm*16+ln][k=ks*32+qd*8+j], contiguous 16B loads
    bfv8 af[2][4];
    const unsigned short* abase = hftA + (size_t)m*32768 + (size_t)(b0 + wv*32 + ln)*128 + qd*8;
    #pragma unroll
    for (int tm = 0; tm < 2; ++tm)
        #pragma unroll
        for (int ks = 0; ks < 4; ++ks)
            af[tm][ks] = *reinterpret_cast<const bfv8*>(abase + tm*2048 + ks*32);
    fv4 acc[2][8];
    #pragma unroll
    for (int tm=0;tm<2;++tm)
        #pragma unroll
        for (int tn=0;tn<8;++tn) acc[tm][tn] = (fv4){0.f,0.f,0.f,0.f};
    #pragma unroll
    for (int ks = 0; ks < 4; ++ks){
        bfv8 bfr[8];
        #pragma unroll
        for (int tn = 0; tn < 8; ++tn)
            bfr[tn] = *reinterpret_cast<const bfv8*>(&sB[(tn*16 + ln)*136 + ks*32 + qd*8]);
        #pragma unroll
        for (int tm = 0; tm < 2; ++tm)
            #pragma unroll
            for (int tn = 0; tn < 8; ++tn)
                acc[tm][tn] = __builtin_amdgcn_mfma_f32_16x16x32_bf16(af[tm][ks], bfr[tn], acc[tm][tn], 0, 0, 0);
    }
    __syncthreads();
    // C -> LDS (reuse sB): C[row][col], row stride 136; C/D map row=qd*4+r, col=ln
    #pragma unroll
    for (int tm = 0; tm < 2; ++tm)
        #pragma unroll
        for (int tn = 0; tn < 8; ++tn)
            #pragma unroll
            for (int rr = 0; rr < 4; ++rr){
                int row = wv*32 + tm*16 + qd*4 + rr;
                int col = tn*16 + ln;
                sB[row*136 + col] = f2us(acc[tm][tn][rr]);
            }
    __syncthreads();
    // pack (r,i) and write mixed[(b*64+o)*288+m]
    for (int idx = t; idx < 8192; idx += 256){
        int row = idx >> 6, o = idx & 63;
        unsigned int pr = ((unsigned int)sB[row*136 + o]) |
                          (((unsigned int)sB[row*136 + o + 64]) << 16);
        mixed[((size_t)(b0 + row)*64 + o)*288 + m] = pr;
    }
}

// ---------------- pointwise 64x64 channel GEMM (wc path), IN PLACE -----------
// grid 2304 = 256 b x 9 row-groups of 4; bf16-packed LDS
__global__ __launch_bounds__(256) void k_wc(bf16* __restrict__ h,
                                            const void* __restrict__ wc_w,
                                            const void* __restrict__ wc_b,
                                            int layer,
                                            const float* __restrict__ flg){
    __shared__ unsigned int shhp[4352];   // [c][68 dwords] = [c][136 u16 px]
    __shared__ unsigned int swp[2048];    // [c][oh] pairs (o even, o+1)
    __shared__ float sb[64];
    const bool f32 = (flg[0] > 0.5f);
    unsigned short* sh16 = (unsigned short*)shhp;
    int blk = blockIdx.x;
    int b = blk / 9, g = blk - b*9;
    int y0 = g*4;
    int nrow = 34 - y0; if (nrow > 4) nrow = 4;
    int t = threadIdx.x;
    size_t wbase = (size_t)layer*4096;
    for (int idx = t; idx < 2048; idx += 256){
        int oh = idx >> 6, c = idx & 63;
        swp[c*32 + oh] = packbf2(rdf(wc_w, wbase + (size_t)(2*oh)*64 + c, f32),
                                 rdf(wc_w, wbase + (size_t)(2*oh+1)*64 + c, f32));
    }
    if (t < 64) sb[t] = rdf(wc_b, layer*64 + t, f32);
    bf16* hb = h + (size_t)b*73984 + y0*34;
    for (int e = t; e < 4352; e += 256){
        int c = e / 68, d = e - c*68;
        shhp[e] = ((const unsigned int*)(hb + (size_t)c*1156))[d];  // trailing garbage unused
    }
    __syncthreads();
    for (int tau = t; tau < 272; tau += 256){
        int ot = tau / 34, pxt = tau - ot*34;
        int o0 = ot*8;
        float acc[4][8];
        #pragma unroll
        for (int j=0;j<4;++j)
            #pragma unroll
            for (int k=0;k<8;++k) acc[j][k] = sb[o0+k];
        for (int c = 0; c < 64; ++c){
            float hv[4], wv[8];
            #pragma unroll
            for (int j=0;j<4;++j) hv[j] = us2f(sh16[c*136 + pxt + j*34]);
            #pragma unroll
            for (int d=0;d<4;++d){
                float2 wp = unpackbf2(swp[c*32 + (o0>>1) + d]);
                wv[2*d] = wp.x; wv[2*d+1] = wp.y;
            }
            #pragma unroll
            for (int j=0;j<4;++j)
                #pragma unroll
                for (int k=0;k<8;++k) acc[j][k] += hv[j]*wv[k];
        }
        #pragma unroll
        for (int j=0;j<4;++j){
            if (j < nrow){
                #pragma unroll
                for (int k=0;k<8;++k)
                    hb[(size_t)(o0+k)*1156 + pxt + j*34] = __float2bfloat16(acc[j][k]);
            }
        }
    }
}

// ---------------- inverse truncated DFT, 4 planes per block; in-place add ----
// grid 4096 = 256 b x 16 o-groups; packed sm/sg
__global__ __launch_bounds__(256) void k_inv(const unsigned int* __restrict__ mixed,
                                             const float* __restrict__ tabs,
                                             bf16* __restrict__ hio, int layer){
    __shared__ unsigned int smp[1152];   // [ch][288] packed (r,i)
    __shared__ unsigned int sgp[3264];   // [ch][kyi*34+x] packed (gr,gi)
    __shared__ float sWix[816];
    __shared__ float sWiy[1632];
    int blk = blockIdx.x;
    int b = blk >> 4, o0 = (blk & 15) * 4;
    int t = threadIdx.x;
    for (int i = t; i < 816; i += 256) sWix[i] = tabs[2448 + i];
    for (int i = t; i < 1632; i += 256) sWiy[i] = tabs[3264 + i];
    const unsigned int* msrc = mixed + ((size_t)b*64 + o0)*288;
    for (int i = t; i < 1152; i += 256) smp[i] = msrc[i];
    __syncthreads();
    // step A: g[ch][kyi][x] = sum_kx F[ch][kyi][kx] * Wix[kx][x]
    if (t < 204){
        int kyit = t / 17, xt = t - kyit*17;
        int kyi0 = kyit*2;
        int x0 = xt, x1 = xt + 17;
        float g[4][2][2][2];
        #pragma unroll
        for (int c=0;c<4;++c)
            #pragma unroll
            for (int q=0;q<2;++q){ g[c][q][0][0]=0.f; g[c][q][0][1]=0.f; g[c][q][1][0]=0.f; g[c][q][1][1]=0.f; }
        for (int kx = 0; kx < 12; ++kx){
            float c0 = sWix[(kx*34+x0)*2], s0 = sWix[(kx*34+x0)*2+1];
            float c1 = sWix[(kx*34+x1)*2], s1 = sWix[(kx*34+x1)*2+1];
            #pragma unroll
            for (int c = 0; c < 4; ++c){
                float2 f0 = unpackbf2(smp[c*288 + kyi0*12 + kx]);
                float2 f1 = unpackbf2(smp[c*288 + (kyi0+1)*12 + kx]);
                g[c][0][0][0] += f0.x*c0 - f0.y*s0;  g[c][0][0][1] += f0.x*s0 + f0.y*c0;
                g[c][0][1][0] += f0.x*c1 - f0.y*s1;  g[c][0][1][1] += f0.x*s1 + f0.y*c1;
                g[c][1][0][0] += f1.x*c0 - f1.y*s0;  g[c][1][0][1] += f1.x*s0 + f1.y*c0;
                g[c][1][1][0] += f1.x*c1 - f1.y*s1;  g[c][1][1][1] += f1.x*s1 + f1.y*c1;
            }
        }
        #pragma unroll
        for (int c = 0; c < 4; ++c)
            #pragma unroll
            for (int q = 0; q < 2; ++q){
                int base = c*816 + (kyi0+q)*34;
                sgp[base + x0] = packbf2(g[c][q][0][0], g[c][q][0][1]);
                sgp[base + x1] = packbf2(g[c][q][1][0], g[c][q][1][1]);
            }
    }
    __syncthreads();
    // step B: out[ch][y][x] = sum_kyi Re(g[ch][kyi][x] * Wiy[kyi][y])
    if (t < 162){
        int cp = t / 81, rr = t - cp*81;
        int yt = rr / 9, xt = rr - yt*9;
        int ch0 = cp*2;
        float acc[2][4][4];
        #pragma unroll
        for (int c=0;c<2;++c)
            #pragma unroll
            for (int jy=0;jy<4;++jy)
                #pragma unroll
                for (int jx=0;jx<4;++jx) acc[c][jy][jx] = 0.f;
        for (int kyi = 0; kyi < 24; ++kyi){
            float wr[4], wi[4];
            #pragma unroll
            for (int jy = 0; jy < 4; ++jy){
                int y = yt + jy*9;
                bool v = (y < 34);
                int idx = (kyi*34 + (v ? y : 0))*2;
                wr[jy] = v ? sWiy[idx]   : 0.f;
                wi[jy] = v ? sWiy[idx+1] : 0.f;
            }
            float gr[2][4], gi[2][4];
            #pragma unroll
            for (int c = 0; c < 2; ++c)
                #pragma unroll
                for (int jx = 0; jx < 4; ++jx){
                    int x = xt + jx*9;
                    bool v = (x < 34);
                    float2 gg = unpackbf2(sgp[(ch0+c)*816 + kyi*34 + (v ? x : 0)]);
                    gr[c][jx] = v ? gg.x : 0.f;
                    gi[c][jx] = v ? gg.y : 0.f;
                }
            #pragma unroll
            for (int c = 0; c < 2; ++c)
                #pragma unroll
                for (int jy = 0; jy < 4; ++jy)
                    #pragma unroll
                    for (int jx = 0; jx < 4; ++jx)
                        acc[c][jy][jx] += gr[c][jx]*wr[jy] - gi[c][jx]*wi[jy];
        }
        bf16* iob = hio + (size_t)b*73984 + (size_t)o0*1156;
        #pragma unroll
        for (int c = 0; c < 2; ++c)
            #pragma unroll
            for (int jy = 0; jy < 4; ++jy)
                #pragma unroll
                for (int jx = 0; jx < 4; ++jx){
                    int y = yt + jy*9, x = xt + jx*9;
                    if (y < 34 && x < 34){
                        size_t off = (size_t)(ch0+c)*1156 + y*34 + x;
                        float v = acc[c][jy][jx] + bff(iob[off]);
                        if (layer < 3) v = gelu_f(v);
                        iob[off] = __float2bfloat16(v);
                    }
                }
    }
}

// ---------------- 8x8/stride4 VALID conv -> gelu -> pe2 scale ----------------
__global__ __launch_bounds__(256) void k_pe(const bf16* __restrict__ h,
                                            const void* __restrict__ pw,
                                            const void* __restrict__ pb,
                                            const void* __restrict__ p2w,
                                            const void* __restrict__ p2b,
                                            float* __restrict__ p49,
                                            const float* __restrict__ flg){
    __shared__ float red[256];
    const bool f32 = (flg[0] > 0.5f);
    int bid = blockIdx.x;          // b*49 + py*7 + px
    int b = bid / 49, r = bid - b*49;
    int py = r / 7, px = r - py*7;
    int t = threadIdx.x;
    const bf16* hb = h + (size_t)b*73984 + (py*4)*34 + px*4;
    float partial = 0.f;
    for (int tt = t; tt < 4096; tt += 256){
        int c = tt >> 6, k = tt & 63, ky = k >> 3, kx = k & 7;
        partial += bff(hb[(size_t)c*1156 + ky*34 + kx]) * rdf(pw, tt, f32);
    }
    red[t] = partial;
    __syncthreads();
    for (int s = 128; s > 0; s >>= 1){
        if (t < s) red[t] += red[t + s];
        __syncthreads();
    }
    if (t == 0){
        float v = red[0] + rdf(pb, 0, f32);
        v = gelu_f(v);
        p49[bid] = v * rdf(p2w, 0, f32) + rdf(p2b, 0, f32);
    }
}

// ---------------- sentence MLP 384->32->32->16 (relu,relu,lin) ---------------
__global__ __launch_bounds__(64) void k_sent(const void* __restrict__ se,
                                             const void* __restrict__ w1, const void* __restrict__ b1,
                                             const void* __restrict__ w2, const void* __restrict__ b2,
                                             const void* __restrict__ w3, const void* __restrict__ b3,
                                             float* __restrict__ outv,
                                             const float* __restrict__ flg){
    __shared__ float s1[32], s2[32];
    const bool f32 = (flg[0] > 0.5f);
    int b = blockIdx.x, t = threadIdx.x;
    if (t < 32){
        float acc = rdf(b1, t, f32);
        size_t rbase = (size_t)b*384;
        for (int k = 0; k < 384; ++k) acc += rdf(se, rbase + k, f32) * rdf(w1, k*32 + t, f32);
        s1[t] = fmaxf(acc, 0.f);
    }
    __syncthreads();
    if (t < 32){
        float acc = rdf(b2, t, f32);
        for (int k = 0; k < 32; ++k) acc += s1[k] * rdf(w2, k*32 + t, f32);
        s2[t] = fmaxf(acc, 0.f);
    }
    __syncthreads();
    if (t < 16){
        float acc = rdf(b3, t, f32);
        for (int k = 0; k < 32; ++k) acc += s2[k] * rdf(w3, k*16 + t, f32);
        outv[b*16 + t] = acc;
    }
}

// ---------------- xp MLP 49->32->32->16 (silu,silu,lin) ----------------------
__global__ __launch_bounds__(64) void k_xp(const float* __restrict__ p49,
                                           const void* __restrict__ w1, const void* __restrict__ b1,
                                           const void* __restrict__ w2, const void* __restrict__ b2,
                                           const void* __restrict__ w3, const void* __restrict__ b3,
                                           float* __restrict__ outv,
                                           const float* __restrict__ flg){
    __shared__ float s1[32], s2[32];
    const bool f32 = (flg[0] > 0.5f);
    int b = blockIdx.x, t = threadIdx.x;
    if (t < 32){
        float acc = rdf(b1, t, f32);
        const float* row = p49 + b*49;
        for (int k = 0; k < 49; ++k) acc += row[k] * rdf(w1, k*32 + t, f32);
        s1[t] = silu_f(acc);
    }
    __syncthreads();
    if (t < 32){
        float acc = rdf(b2, t, f32);
        for (int k = 0; k < 32; ++k) acc += s1[k] * rdf(w2, k*32 + t, f32);
        s2[t] = silu_f(acc);
    }
    __syncthreads();
    if (t < 16){
        float acc = rdf(b3, t, f32);
        for (int k = 0; k < 32; ++k) acc += s2[k] * rdf(w3, k*16 + t, f32);
        outv[b*16 + t] = acc;
    }
}

// ---------------- pu MLP part A: 32->128->256 (silu,silu) --------------------
__global__ __launch_bounds__(256) void k_puA(const float* __restrict__ xemb,
                                             const float* __restrict__ semb,
                                             const void* __restrict__ w1, const void* __restrict__ b1,
                                             const void* __restrict__ w2, const void* __restrict__ b2,
                                             float* __restrict__ h2buf,
                                             const float* __restrict__ flg){
    __shared__ float ein[32];
    __shared__ float h1[128];
    const bool f32 = (flg[0] > 0.5f);
    int b = blockIdx.x, t = threadIdx.x;
    if (t < 16) ein[t] = xemb[b*16 + t];
    else if (t < 32) ein[t] = semb[b*16 + (t - 16)];
    __syncthreads();
    if (t < 128){
        float acc = rdf(b1, t, f32);
        for (int k = 0; k < 32; ++k) acc += ein[k] * rdf(w1, k*128 + t, f32);
        h1[t] = silu_f(acc);
    }
    __syncthreads();
    {
        float acc = rdf(b2, t, f32);
        for (int k = 0; k < 128; ++k) acc += h1[k] * rdf(w2, k*256 + t, f32);
        h2buf[(size_t)b*256 + t] = silu_f(acc);
    }
}

// ---------------- pu MLP part B: 256->1156 GEMM ------------------------------
// grid 1280 = 256 b (fast) x 5 n-chunks of 232
__global__ __launch_bounds__(256) void k_puB(const float* __restrict__ h2buf,
                                             const void* __restrict__ w3, const void* __restrict__ b3,
                                             float* __restrict__ emb,
                                             const float* __restrict__ flg){
    __shared__ float sh2[256];
    const bool f32 = (flg[0] > 0.5f);
    int blk = blockIdx.x;
    int b = blk & 255, nc = blk >> 8;
    int t = threadIdx.x;
    sh2[t] = h2buf[(size_t)b*256 + t];
    __syncthreads();
    int e = nc*232 + t;
    if (t < 232 && e < 1156){
        float acc = rdf(b3, e, f32);
        if (f32){
            const float* wp = (const float*)w3 + e;
            #pragma unroll 4
            for (int k = 0; k < 256; ++k) acc += sh2[k] * wp[(size_t)k*1156];
        } else {
            const bf16* wp = (const bf16*)w3 + e;
            #pragma unroll 4
            for (int k = 0; k < 256; ++k) acc += sh2[k] * bff(wp[(size_t)k*1156]);
        }
        emb[(size_t)b*1156 + e] = acc;
    }
}

// ---------------- final: crop, concat emb, fc1+gelu, fc2 ---------------------
// grid 512 = 256 b x 2 halves; 4 iters of 4 rows (128 px); 8px x 8j dword tiles
__global__ __launch_bounds__(256) void k_final(const bf16* __restrict__ h,
                                               const float* __restrict__ emb,
                                               const void* __restrict__ w1, const void* __restrict__ b1,
                                               const void* __restrict__ w2, const void* __restrict__ b2,
                                               void* __restrict__ out,
                                               const float* __restrict__ flg){
    __shared__ unsigned int sw1p[4160];     // [c][j/2] packed pairs (j even)
    __shared__ float sb1[128];
    __shared__ float sw2[512];              // [j][k]
    __shared__ float sb2[4];
    __shared__ unsigned int sinpp[4160];    // [c][px/2] packed pairs
    __shared__ unsigned short shid[128*132];// [j][px] bf16 padded
    const bool f32 = (flg[0] > 0.5f);
    int blk = blockIdx.x;
    int b = blk >> 1, half = blk & 1;
    int t = threadIdx.x;
    for (int i = t; i < 4160; i += 256){
        int c = i >> 6, j2 = i & 63;
        sw1p[i] = packbf2(rdf(w1, (size_t)c*128 + j2*2, f32),
                          rdf(w1, (size_t)c*128 + j2*2 + 1, f32));
    }
    if (t < 128) sb1[t] = rdf(b1, t, f32);
    for (int i = t; i < 512; i += 256) sw2[i] = rdf(w2, i, f32);
    if (t < 4) sb2[t] = rdf(b2, t, f32);
    const bf16* hb = h + (size_t)b*73984;
    const float* eb = emb + (size_t)b*1156;
    int pxt = t & 15, jt = t >> 4;   // 16 x 16
    int px0 = pxt*8, j0 = jt*8;
    for (int it = 0; it < 4; ++it){
        int y0 = half*16 + it*4;     // 4 rows = 128 px
        __syncthreads();
        for (int i = t; i < 4160; i += 256){
            int c = i >> 6, p2 = i & 63;
            int px = p2*2;
            int y = y0 + (px >> 5), x = px & 31;
            float v0 = (c < 64) ? bff(hb[(size_t)c*1156 + y*34 + x]) : eb[y*34 + x];
            int px1 = px + 1;
            int y1 = y0 + (px1 >> 5), x1 = px1 & 31;
            float v1 = (c < 64) ? bff(hb[(size_t)c*1156 + y1*34 + x1]) : eb[y1*34 + x1];
            sinpp[i] = packbf2(v0, v1);
        }
        __syncthreads();
        float acc[8][8];
        #pragma unroll
        for (int j=0;j<8;++j)
            #pragma unroll
            for (int k=0;k<8;++k) acc[j][k] = sb1[j0+k];
        for (int c = 0; c < 65; ++c){
            float hv[8], wv[8];
            #pragma unroll
            for (int d = 0; d < 4; ++d){
                float2 hp = unpackbf2(sinpp[c*64 + (px0>>1) + d]);
                hv[2*d] = hp.x; hv[2*d+1] = hp.y;
                float2 wp = unpackbf2(sw1p[c*64 + (j0>>1) + d]);
                wv[2*d] = wp.x; wv[2*d+1] = wp.y;
            }
            #pragma unroll
            for (int j=0;j<8;++j)
                #pragma unroll
                for (int k=0;k<8;++k) acc[j][k] += hv[j]*wv[k];
        }
        #pragma unroll
        for (int j=0;j<8;++j)
            #pragma unroll
            for (int k=0;k<8;++k)
                shid[(j0+k)*132 + px0 + j] = f2us(gelu_f(acc[j][k]));
        __syncthreads();
        {
            int px = t & 127, kk = t >> 7;   // kk in {0,1} -> k = 2kk, 2kk+1
            float a0 = sb2[kk*2], a1 = sb2[kk*2+1];
            for (int j = 0; j < 128; ++j){
                float hvv = us2f(shid[j*132 + px]);
                a0 += hvv * sw2[j*4 + kk*2];
                a1 += hvv * sw2[j*4 + kk*2 + 1];
            }
            int y = y0 + (px >> 5), x = px & 31;
            size_t o = ((size_t)(b*32 + y)*32 + x)*4 + kk*2;
            if (f32){ ((float*)out)[o] = a0; ((float*)out)[o+1] = a1; }
            else { ((bf16*)out)[o] = __float2bfloat16(a0); ((bf16*)out)[o+1] = __float2bfloat16(a1); }
        }
    }
}

extern "C" void kernel_launch(void* const* d_in, const int* in_sizes, int n_in,
                              void* d_out, int out_size, void* d_ws, size_t ws_size,
                              hipStream_t stream) {
    (void)in_sizes; (void)n_in; (void)out_size; (void)ws_size;
    const void* x     = d_in[0];
    const void* grd   = d_in[1];
    const void* se    = d_in[2];
    const void* fc0_w = d_in[3];
    const void* fc0_b = d_in[4];
    const void* sc_w1 = d_in[5];
    const void* sc_w2 = d_in[6];
    const void* wc_w  = d_in[7];
    const void* wc_b  = d_in[8];
    const void* pe1_w = d_in[9];
    const void* pe1_b = d_in[10];
    const void* pe2_w = d_in[11];
    const void* pe2_b = d_in[12];
    const void* sp_w1 = d_in[13];
    const void* sp_b1 = d_in[14];
    const void* sp_w2 = d_in[15];
    const void* sp_b2 = d_in[16];
    const void* sp_w3 = d_in[17];
    const void* sp_b3 = d_in[18];
    const void* xp_w1 = d_in[19];
    const void* xp_b1 = d_in[20];
    const void* xp_w2 = d_in[21];
    const void* xp_b2 = d_in[22];
    const void* xp_w3 = d_in[23];
    const void* xp_b3 = d_in[24];
    const void* pu_w1 = d_in[25];
    const void* pu_b1 = d_in[26];
    const void* pu_w2 = d_in[27];
    const void* pu_b2 = d_in[28];
    const void* pu_w3 = d_in[29];
    const void* pu_b3 = d_in[30];
    const void* fc1_w = d_in[31];
    const void* fc1_b = d_in[32];
    const void* fc2_w = d_in[33];
    const void* fc2_b = d_in[34];

    // workspace layout (float-unit offsets); total ~77 MB
    float* ws    = (float*)d_ws;
    bf16*  hA    = (bf16*)ws;                              // 18,939,904 bf16
    unsigned int* hft   = (unsigned int*)(ws + 9469952);   // 4,718,592 dwords (hftA panels)
    unsigned int* mixed = (unsigned int*)(ws + 14188544);  // 4,718,592 dwords
    float* tabs  = ws + 18907136;                          // 4,896
    float* p49   = ws + 18912032;                          // 12,544
    float* semb  = ws + 18924576;                          // 4,096
    float* xemb  = ws + 18928672;                          // 4,096
    float* emb   = ws + 18932768;                          // 295,936
    float* flag  = ws + 19228704;                          // 1
    float* h2buf = (float*)hft;                            // reuse: hft dead after layer loop

    k_probe<<<1, 256, 0, stream>>>(x, flag);
    k_tables<<<1, 256, 0, stream>>>(tabs);
    k_fc0<<<256*34, 256, 0, stream>>>(x, grd, fc0_w, fc0_b, hA, flag);

    for (int l = 0; l < 4; ++l){
        k_fwd<<<4096, 256, 0, stream>>>(hA, hft, tabs);
        k_mixm<<<576, 256, 0, stream>>>((const unsigned short*)hft, sc_w1, sc_w2, mixed, l, flag);
        k_wc <<<2304, 256, 0, stream>>>(hA, wc_w, wc_b, l, flag);
        k_inv<<<4096, 256, 0, stream>>>(mixed, tabs, hA, l);
    }

    k_pe  <<<256*49, 256, 0, stream>>>(hA, pe1_w, pe1_b, pe2_w, pe2_b, p49, flag);
    k_sent<<<256, 64, 0, stream>>>(se, sp_w1, sp_b1, sp_w2, sp_b2, sp_w3, sp_b3, semb, flag);
    k_xp  <<<256, 64, 0, stream>>>(p49, xp_w1, xp_b1, xp_w2, xp_b2, xp_w3, xp_b3, xemb, flag);
    k_puA <<<256, 256, 0, stream>>>(xemb, semb, pu_w1, pu_b1, pu_w2, pu_b2, h2buf, flag);
    k_puB <<<1280, 256, 0, stream>>>(h2buf, pu_w3, pu_b3, emb, flag);
    k_final<<<512, 256, 0, stream>>>(hA, emb, fc1_w, fc1_b, fc2_w, fc2_b, d_out, flag);
}

// Round 6
// 1771.481 us; speedup vs baseline: 2.4576x; 1.0117x over previous
//
#include <hip/hip_runtime.h>
#include <hip/hip_bf16.h>
#include <math.h>

typedef __hip_bfloat16 bf16;
typedef __bf16 bfv8 __attribute__((ext_vector_type(8)));
typedef float fv4 __attribute__((ext_vector_type(4)));

__device__ __forceinline__ float bff(const bf16 x){ return __bfloat162float(x); }
__device__ __forceinline__ float gelu_f(float v){
    return 0.5f * v * (1.f + erff(v * 0.70710678118654752f));
}
__device__ __forceinline__ float silu_f(float v){
    return v / (1.f + expf(-v));
}
// dtype-agnostic input read: f32 ? fp32 : bf16
__device__ __forceinline__ float rdf(const void* p, size_t i, bool f32){
    return f32 ? ((const float*)p)[i] : __bfloat162float(((const bf16*)p)[i]);
}
__device__ __forceinline__ unsigned int packbf2(float a, float b){
    __hip_bfloat162 v;
    v.x = __float2bfloat16(a);
    v.y = __float2bfloat16(b);
    return *reinterpret_cast<unsigned int*>(&v);
}
__device__ __forceinline__ float2 unpackbf2(unsigned int u){
    __hip_bfloat162 v = *reinterpret_cast<__hip_bfloat162*>(&u);
    return make_float2(__bfloat162float(v.x), __bfloat162float(v.y));
}
__device__ __forceinline__ float us2f(unsigned short u){
    unsigned int x = ((unsigned int)u) << 16;
    return __uint_as_float(x);
}
__device__ __forceinline__ unsigned short f2us(float f){
    bf16 v = __float2bfloat16(f);
    return *reinterpret_cast<unsigned short*>(&v);
}

// Geometry
// B=256, C=64, H=W=34 (padded), modes: ky in {0..11, 22..33} (24), kx in 0..11 (12)
// h layout (ws, bf16): [b][c][y][x], stride c = 1156, stride b = 73984
// hftA layout: [m][b][k] bf16, k in [0,128): k<64 = Re(F)[c=k], k>=64 = Im(F)[c=k-64]
// mixed layout: [(b*64+o)*288 + m] packed bf16x2 dwords (r,i)

// ---------------- dtype probe ----------------
__global__ __launch_bounds__(256) void k_probe(const void* x, float* flag){
    __shared__ int wild;
    int t = threadIdx.x;
    if (t == 0) wild = 0;
    __syncthreads();
    const bf16* xb = (const bf16*)x;
    for (int i = t; i < 1024; i += 256){
        float v = bff(xb[i]);
        if (!(fabsf(v) < 1e10f)) wild = 1;
    }
    __syncthreads();
    if (t == 0) flag[0] = wild ? 1.f : 0.f;
}

// ---------------- tables ----------------
__global__ __launch_bounds__(256) void k_tables(float* tabs){
    int t = threadIdx.x;
    float* Wfy = tabs;          // 24*34*2
    float* Wfx = tabs + 1632;   // 12*34*2
    float* Wix = tabs + 2448;   // 12*34*2
    float* Wiy = tabs + 3264;   // 24*34*2
    const float TWO_PI = 6.283185307179586f;
    for (int e = t; e < 24*34; e += 256){
        int kyi = e / 34, y = e % 34;
        int ky = (kyi < 12) ? kyi : kyi + 10;
        int ph = (ky * y) % 34;
        float ang = TWO_PI * (float)ph / 34.0f;
        float s, c;
        sincosf(ang, &s, &c);
        Wfy[e*2]   = c;   Wfy[e*2+1] = -s;           // e^{-i ang}
        Wiy[e*2]   = c * (1.0f/1156.0f);
        Wiy[e*2+1] = s * (1.0f/1156.0f);             // (1/HW) e^{+i ang}
    }
    for (int e = t; e < 12*34; e += 256){
        int kx = e / 34, x = e % 34;
        int ph = (kx * x) % 34;
        float ang = TWO_PI * (float)ph / 34.0f;
        float s, c;
        sincosf(ang, &s, &c);
        Wfx[e*2] = c; Wfx[e*2+1] = -s;               // e^{-i ang}
        float ck = (kx == 0) ? 1.0f : 2.0f;
        Wix[e*2] = ck * c; Wix[e*2+1] = ck * s;      // c_kx e^{+i ang}
    }
}

// ---------------- fc0: concat(x,grid) @ fc0_w + b, NCHW, zero-pad to 34x34 ----
__global__ __launch_bounds__(256) void k_fc0(const void* __restrict__ xin,
                                             const void* __restrict__ grd,
                                             const void* __restrict__ w,
                                             const void* __restrict__ bias,
                                             bf16* __restrict__ h,
                                             const float* __restrict__ flg){
    __shared__ float sin_[32*42];
    __shared__ float sw[42*64];
    __shared__ float sb[64];
    const bool f32 = (flg[0] > 0.5f);
    int bid = blockIdx.x;          // b*34 + y
    int b = bid / 34, y = bid - b*34;
    int t = threadIdx.x;
    bf16* hb = h + (size_t)b*73984 + y*34;
    if (y >= 32){
        for (int e = t; e < 2176; e += 256){
            int c = e / 34, x = e - c*34;
            hb[(size_t)c*1156 + x] = __float2bfloat16(0.f);
        }
        return;
    }
    for (int idx = t; idx < 2688; idx += 256) sw[idx] = rdf(w, idx, f32);
    if (t < 64) sb[t] = rdf(bias, t, f32);
    size_t xbase = (size_t)(b*32 + y)*32*40;
    for (int idx = t; idx < 1280; idx += 256){
        int x = idx / 40, k = idx - x*40;
        sin_[x*42 + k] = rdf(xin, xbase + idx, f32);
    }
    size_t gbase = (size_t)(b*32 + y)*32*2;
    if (t < 64){
        int x = t >> 1, k2 = t & 1;
        sin_[x*42 + 40 + k2] = rdf(grd, gbase + x*2 + k2, f32);
    }
    __syncthreads();
    {
        int xt = t & 7, ct = t >> 3;    // 8 x-tiles x 32 c-tiles
        int x0 = xt*4, c0 = ct*2;
        float acc[2][4];
        #pragma unroll
        for (int cc=0;cc<2;++cc)
            #pragma unroll
            for (int j=0;j<4;++j) acc[cc][j] = sb[c0+cc];
        for (int k = 0; k < 42; ++k){
            float sv[4], wv[2];
            #pragma unroll
            for (int j=0;j<4;++j) sv[j] = sin_[(x0+j)*42 + k];
            #pragma unroll
            for (int cc=0;cc<2;++cc) wv[cc] = sw[k*64 + c0 + cc];
            #pragma unroll
            for (int cc=0;cc<2;++cc)
                #pragma unroll
                for (int j=0;j<4;++j) acc[cc][j] += sv[j]*wv[cc];
        }
        #pragma unroll
        for (int cc=0;cc<2;++cc)
            #pragma unroll
            for (int j=0;j<4;++j)
                hb[(size_t)(c0+cc)*1156 + x0 + j] = __float2bfloat16(acc[cc][j]);
    }
    for (int e = t; e < 128; e += 256){
        int c = e >> 1, x = 32 + (e & 1);
        hb[(size_t)c*1156 + x] = __float2bfloat16(0.f);
    }
}

// ---------------- forward truncated DFT, 4 channels per block ----------------
// grid 4096 = 256 b x 16 ch-groups; writes hftA [m][b][k] (A-panel layout)
__global__ __launch_bounds__(256) void k_fwd(const bf16* __restrict__ h,
                                             unsigned int* __restrict__ hftA,
                                             const float* __restrict__ tabs){
    __shared__ unsigned int shp[2312];  // 4 x 578 packed pairs (x even, x+1)
    __shared__ float sWfy[1632];
    __shared__ float sWfx[816];
    __shared__ unsigned int st[3264];   // 4 x 816 packed bf16x2 (G intermediates)
    int blk = blockIdx.x;
    int b = blk >> 4, c0 = (blk & 15) * 4;
    int t = threadIdx.x;
    for (int i = t; i < 1632; i += 256) sWfy[i] = tabs[i];
    for (int i = t; i < 816; i += 256) sWfx[i] = tabs[1632 + i];
    const unsigned int* srcp = (const unsigned int*)(h + (size_t)b*73984 + (size_t)c0*1156);
    for (int i = t; i < 2312; i += 256) shp[i] = srcp[i];
    __syncthreads();
    // step 1: G[ch][kyi][x] = sum_y Wfy[kyi][y] * h[ch][y][x]
    if (t < 204){
        int kyit = t / 17, xt = t - kyit*17;
        int kyi0 = kyit*2, x0 = xt*2;
        float a[4][2][2][2];
        #pragma unroll
        for (int c=0;c<4;++c)
            #pragma unroll
            for (int q=0;q<2;++q){ a[c][q][0][0]=0.f; a[c][q][0][1]=0.f; a[c][q][1][0]=0.f; a[c][q][1][1]=0.f; }
        for (int y = 0; y < 34; ++y){
            int w0 = (kyi0*34 + y)*2, w1 = ((kyi0+1)*34 + y)*2;
            float w0r = sWfy[w0], w0i = sWfy[w0+1];
            float w1r = sWfy[w1], w1i = sWfy[w1+1];
            #pragma unroll
            for (int c = 0; c < 4; ++c){
                float2 hp = unpackbf2(shp[c*578 + y*17 + xt]);
                float h0 = hp.x, h1 = hp.y;
                a[c][0][0][0] += h0*w0r; a[c][0][0][1] += h0*w0i;
                a[c][0][1][0] += h1*w0r; a[c][0][1][1] += h1*w0i;
                a[c][1][0][0] += h0*w1r; a[c][1][0][1] += h0*w1i;
                a[c][1][1][0] += h1*w1r; a[c][1][1][1] += h1*w1i;
            }
        }
        #pragma unroll
        for (int c = 0; c < 4; ++c)
            #pragma unroll
            for (int q = 0; q < 2; ++q){
                int base = c*816 + (kyi0+q)*34 + x0;
                st[base]   = packbf2(a[c][q][0][0], a[c][q][0][1]);
                st[base+1] = packbf2(a[c][q][1][0], a[c][q][1][1]);
            }
    }
    __syncthreads();
    // step 2: F[ch][kyi][kx] = sum_x G[ch][kyi][x] * Wfx[kx][x]
    if (t < 144){
        int kyit = t / 12, kx = t - kyit*12;
        int kyi0 = kyit*2;
        float a[4][2][2];
        #pragma unroll
        for (int c=0;c<4;++c){ a[c][0][0]=0.f; a[c][0][1]=0.f; a[c][1][0]=0.f; a[c][1][1]=0.f; }
        for (int x = 0; x < 34; ++x){
            float cr = sWfx[(kx*34+x)*2], ci = sWfx[(kx*34+x)*2+1];
            #pragma unroll
            for (int c = 0; c < 4; ++c){
                float2 g0 = unpackbf2(st[c*816 + kyi0*34 + x]);
                float2 g1 = unpackbf2(st[c*816 + (kyi0+1)*34 + x]);
                a[c][0][0] += g0.x*cr - g0.y*ci;
                a[c][0][1] += g0.x*ci + g0.y*cr;
                a[c][1][0] += g1.x*cr - g1.y*ci;
                a[c][1][1] += g1.x*ci + g1.y*cr;
            }
        }
        // hftA[m][b][k]: real at k=c0..c0+3, imag at k=64+c0..64+c0+3 (dword-packed)
        #pragma unroll
        for (int q = 0; q < 2; ++q){
            int m = (kyi0+q)*12 + kx;
            size_t base = (size_t)m*16384 + (size_t)b*64 + (c0 >> 1);
            hftA[base]      = packbf2(a[0][q][0], a[1][q][0]);
            hftA[base + 1]  = packbf2(a[2][q][0], a[3][q][0]);
            hftA[base + 32] = packbf2(a[0][q][1], a[1][q][1]);
            hftA[base + 33] = packbf2(a[2][q][1], a[3][q][1]);
        }
    }
}

// ---------------- per-mode channel mix as bf16 MFMA GEMM ---------------------
// grid 576 = 288 modes x 2 M-halves of 128; C[128,128] = A[128,128] x B[128,128]
// A = [Hr | Hi] (direct from hftA), B = [[Wr, Wi], [-Wi, Wr]] staged as BT in LDS
__global__ __launch_bounds__(256) void k_mixm(const unsigned short* __restrict__ hftA,
                                              const void* __restrict__ sc_w1,
                                              const void* __restrict__ sc_w2,
                                              unsigned int* __restrict__ mixed, int layer,
                                              const float* __restrict__ flg){
    __shared__ unsigned short sB[128*136];   // BT[n][k], row stride 136 (conflict-free frags)
    const bool f32 = (flg[0] > 0.5f);
    int m  = blockIdx.x >> 1;
    int mh = blockIdx.x & 1;
    int b0 = mh * 128;
    int t = threadIdx.x;
    int kyi = m / 12, kx = m - kyi*12;
    const void* w = (kyi < 12) ? sc_w1 : sc_w2;
    int r = (kyi < 12) ? kyi : kyi - 12;
    size_t wbase = (size_t)layer * 64*64*144*2;
    for (int idx = t; idx < 4096; idx += 256){     // idx = i*64+o
        int i = idx >> 6, o = idx & 63;
        size_t off = wbase + (((size_t)idx*12 + r)*12 + kx)*2;
        float wr = rdf(w, off, f32);
        float wi = rdf(w, off+1, f32);
        sB[o*136 + i]           = f2us(wr);
        sB[(o+64)*136 + i]      = f2us(wi);
        sB[o*136 + i + 64]      = f2us(-wi);
        sB[(o+64)*136 + i + 64] = f2us(wr);
    }
    __syncthreads();
    int ln = t & 15, qd = (t & 63) >> 4, wv = t >> 6;
    // A fragments: A[row=b0+wv*32+tm*16+ln][k=ks*32+qd*8+j], contiguous 16B loads
    bfv8 af[2][4];
    const unsigned short* abase = hftA + (size_t)m*32768 + (size_t)(b0 + wv*32 + ln)*128 + qd*8;
    #pragma unroll
    for (int tm = 0; tm < 2; ++tm)
        #pragma unroll
        for (int ks = 0; ks < 4; ++ks)
            af[tm][ks] = *reinterpret_cast<const bfv8*>(abase + tm*2048 + ks*32);
    fv4 acc[2][8];
    #pragma unroll
    for (int tm=0;tm<2;++tm)
        #pragma unroll
        for (int tn=0;tn<8;++tn) acc[tm][tn] = (fv4){0.f,0.f,0.f,0.f};
    #pragma unroll
    for (int ks = 0; ks < 4; ++ks){
        bfv8 bfr[8];
        #pragma unroll
        for (int tn = 0; tn < 8; ++tn)
            bfr[tn] = *reinterpret_cast<const bfv8*>(&sB[(tn*16 + ln)*136 + ks*32 + qd*8]);
        #pragma unroll
        for (int tm = 0; tm < 2; ++tm)
            #pragma unroll
            for (int tn = 0; tn < 8; ++tn)
                acc[tm][tn] = __builtin_amdgcn_mfma_f32_16x16x32_bf16(af[tm][ks], bfr[tn], acc[tm][tn], 0, 0, 0);
    }
    __syncthreads();
    // C -> LDS (reuse sB): C[row][col], row stride 136; C/D map row=qd*4+r, col=ln
    #pragma unroll
    for (int tm = 0; tm < 2; ++tm)
        #pragma unroll
        for (int tn = 0; tn < 8; ++tn)
            #pragma unroll
            for (int rr = 0; rr < 4; ++rr){
                int row = wv*32 + tm*16 + qd*4 + rr;
                int col = tn*16 + ln;
                sB[row*136 + col] = f2us(acc[tm][tn][rr]);
            }
    __syncthreads();
    // pack (r,i) and write mixed[(b*64+o)*288+m]
    for (int idx = t; idx < 8192; idx += 256){
        int row = idx >> 6, o = idx & 63;
        unsigned int pr = ((unsigned int)sB[row*136 + o]) |
                          (((unsigned int)sB[row*136 + o + 64]) << 16);
        mixed[((size_t)(b0 + row)*64 + o)*288 + m] = pr;
    }
}

// ---------------- pointwise 64x64 channel GEMM (wc path), IN PLACE -----------
// grid 2304 = 256 b x 9 row-groups of 4; bf16-packed LDS
__global__ __launch_bounds__(256) void k_wc(bf16* __restrict__ h,
                                            const void* __restrict__ wc_w,
                                            const void* __restrict__ wc_b,
                                            int layer,
                                            const float* __restrict__ flg){
    __shared__ unsigned int shhp[4352];   // [c][68 dwords] = [c][136 u16 px]
    __shared__ unsigned int swp[2048];    // [c][oh] pairs (o even, o+1)
    __shared__ float sb[64];
    const bool f32 = (flg[0] > 0.5f);
    unsigned short* sh16 = (unsigned short*)shhp;
    int blk = blockIdx.x;
    int b = blk / 9, g = blk - b*9;
    int y0 = g*4;
    int nrow = 34 - y0; if (nrow > 4) nrow = 4;
    int t = threadIdx.x;
    size_t wbase = (size_t)layer*4096;
    for (int idx = t; idx < 2048; idx += 256){
        int oh = idx >> 6, c = idx & 63;
        swp[c*32 + oh] = packbf2(rdf(wc_w, wbase + (size_t)(2*oh)*64 + c, f32),
                                 rdf(wc_w, wbase + (size_t)(2*oh+1)*64 + c, f32));
    }
    if (t < 64) sb[t] = rdf(wc_b, layer*64 + t, f32);
    bf16* hb = h + (size_t)b*73984 + y0*34;
    for (int e = t; e < 4352; e += 256){
        int c = e / 68, d = e - c*68;
        shhp[e] = ((const unsigned int*)(hb + (size_t)c*1156))[d];  // trailing garbage unused
    }
    __syncthreads();
    for (int tau = t; tau < 272; tau += 256){
        int ot = tau / 34, pxt = tau - ot*34;
        int o0 = ot*8;
        float acc[4][8];
        #pragma unroll
        for (int j=0;j<4;++j)
            #pragma unroll
            for (int k=0;k<8;++k) acc[j][k] = sb[o0+k];
        for (int c = 0; c < 64; ++c){
            float hv[4], wv[8];
            #pragma unroll
            for (int j=0;j<4;++j) hv[j] = us2f(sh16[c*136 + pxt + j*34]);
            #pragma unroll
            for (int d=0;d<4;++d){
                float2 wp = unpackbf2(swp[c*32 + (o0>>1) + d]);
                wv[2*d] = wp.x; wv[2*d+1] = wp.y;
            }
            #pragma unroll
            for (int j=0;j<4;++j)
                #pragma unroll
                for (int k=0;k<8;++k) acc[j][k] += hv[j]*wv[k];
        }
        #pragma unroll
        for (int j=0;j<4;++j){
            if (j < nrow){
                #pragma unroll
                for (int k=0;k<8;++k)
                    hb[(size_t)(o0+k)*1156 + pxt + j*34] = __float2bfloat16(acc[j][k]);
            }
        }
    }
}

// ---------------- inverse truncated DFT as MFMA GEMMs; in-place add + gelu ---
// grid 4096 = 256 b x 16 o-groups of 4.
// Step A: G = F x Wix  — M=96 (4ch x 24kyi), K=24->32 (fr,fi per kx), N=68->80 (gr,gi per x)
// Step B: out = W2 x G^T per ch — M=34->48 (y), K=48->64 (2kyi+ri), N=34->48 (x)
__global__ __launch_bounds__(256) void k_invm(const unsigned int* __restrict__ mixed,
                                              const float* __restrict__ tabs,
                                              bf16* __restrict__ hio, int layer){
    __shared__ unsigned short sA[96*40];    // A[(ch*24+kyi)][k=2kx+ri], k 24..31 zero
    __shared__ unsigned short sBT[80*40];   // BT[n=2x+ri][k=2kx+ri2]
    __shared__ unsigned short sW2[48*72];   // W2[y][k=2kyi+ri], y>=34 / k>=48 zero
    __shared__ unsigned short sG[4*48*72];  // per ch: G^T[x][k=2kyi+ri], x>=34 / k>=48 zero
    int blk = blockIdx.x;
    int b = blk >> 4, o0 = (blk & 15) * 4;
    int t = threadIdx.x;
    const float* Wix = tabs + 2448;
    const float* Wiy = tabs + 3264;
    // fill sA from mixed (pure bit-copy of bf16 halves)
    const unsigned int* msrc = mixed + ((size_t)b*64 + o0)*288;
    for (int i = t; i < 1152; i += 256){
        int ch = i / 288, m = i - ch*288;
        int kyi = m / 12, kx = m - kyi*12;
        unsigned int u = msrc[i];
        int row = ch*24 + kyi;
        sA[row*40 + 2*kx]     = (unsigned short)(u & 0xFFFFu);
        sA[row*40 + 2*kx + 1] = (unsigned short)(u >> 16);
    }
    for (int i = t; i < 768; i += 256){      // zero K-pad 24..31
        int row = i >> 3, k = 24 + (i & 7);
        sA[row*40 + k] = 0;
    }
    // fill sBT (Wix expanded complex->real), 80 x 32
    for (int i = t; i < 2560; i += 256){
        int n = i >> 5, k = i & 31;
        float v = 0.f;
        if (n < 68 && k < 24){
            int x = n >> 1, ri = n & 1, kx = k >> 1, ri2 = k & 1;
            float c = Wix[(kx*34 + x)*2];
            float s = Wix[(kx*34 + x)*2 + 1];
            v = (ri == 0) ? (ri2 == 0 ? c : -s) : (ri2 == 0 ? s : c);
        }
        sBT[n*40 + k] = f2us(v);
    }
    // fill sW2 (Wiy expanded), 48 x 64
    for (int i = t; i < 3072; i += 256){
        int y = i >> 6, k = i & 63;
        float v = 0.f;
        if (y < 34 && k < 48){
            int kyi = k >> 1, ri = k & 1;
            v = Wiy[(kyi*34 + y)*2 + ri];
            if (ri) v = -v;
        }
        sW2[y*72 + k] = f2us(v);
    }
    // zero sG
    for (int i = t; i < 13824; i += 256) sG[i] = 0;
    __syncthreads();
    int ln = t & 15, qd = (t & 63) >> 4, wv = t >> 6;
    // ---- step A: 30 tiles (6 M x 5 N), K=32, round-robin over waves ----
    for (int tau = wv; tau < 30; tau += 4){
        int mt = tau / 5, nt = tau - mt*5;
        bfv8 a = *reinterpret_cast<const bfv8*>(&sA[(mt*16 + ln)*40 + qd*8]);
        bfv8 bb = *reinterpret_cast<const bfv8*>(&sBT[(nt*16 + ln)*40 + qd*8]);
        fv4 acc = (fv4){0.f,0.f,0.f,0.f};
        acc = __builtin_amdgcn_mfma_f32_16x16x32_bf16(a, bb, acc, 0, 0, 0);
        int col = nt*16 + ln;
        if (col < 68){
            int x = col >> 1, ri = col & 1;
            #pragma unroll
            for (int rr = 0; rr < 4; ++rr){
                int row = mt*16 + qd*4 + rr;
                int ch = row / 24, kyi = row - ch*24;
                sG[(ch*48 + x)*72 + 2*kyi + ri] = f2us(acc[rr]);
            }
        }
    }
    __syncthreads();
    // ---- step B: wave = ch; 3x3 tiles, K=64 (2 MFMAs) ----
    int ch = wv;
    bf16* iob = hio + (size_t)b*73984 + (size_t)(o0 + ch)*1156;
    #pragma unroll
    for (int mt = 0; mt < 3; ++mt){
        bfv8 a0 = *reinterpret_cast<const bfv8*>(&sW2[(mt*16 + ln)*72 + qd*8]);
        bfv8 a1 = *reinterpret_cast<const bfv8*>(&sW2[(mt*16 + ln)*72 + 32 + qd*8]);
        #pragma unroll
        for (int nt = 0; nt < 3; ++nt){
            bfv8 b0 = *reinterpret_cast<const bfv8*>(&sG[(ch*48 + nt*16 + ln)*72 + qd*8]);
            bfv8 b1 = *reinterpret_cast<const bfv8*>(&sG[(ch*48 + nt*16 + ln)*72 + 32 + qd*8]);
            fv4 acc = (fv4){0.f,0.f,0.f,0.f};
            acc = __builtin_amdgcn_mfma_f32_16x16x32_bf16(a0, b0, acc, 0, 0, 0);
            acc = __builtin_amdgcn_mfma_f32_16x16x32_bf16(a1, b1, acc, 0, 0, 0);
            int x = nt*16 + ln;
            if (x < 34){
                #pragma unroll
                for (int rr = 0; rr < 4; ++rr){
                    int y = mt*16 + qd*4 + rr;
                    if (y < 34){
                        size_t off = (size_t)y*34 + x;
                        float v = acc[rr] + bff(iob[off]);
                        if (layer < 3) v = gelu_f(v);
                        iob[off] = __float2bfloat16(v);
                    }
                }
            }
        }
    }
}

// ---------------- 8x8/stride4 VALID conv -> gelu -> pe2 scale ----------------
__global__ __launch_bounds__(256) void k_pe(const bf16* __restrict__ h,
                                            const void* __restrict__ pw,
                                            const void* __restrict__ pb,
                                            const void* __restrict__ p2w,
                                            const void* __restrict__ p2b,
                                            float* __restrict__ p49,
                                            const float* __restrict__ flg){
    __shared__ float red[256];
    const bool f32 = (flg[0] > 0.5f);
    int bid = blockIdx.x;          // b*49 + py*7 + px
    int b = bid / 49, r = bid - b*49;
    int py = r / 7, px = r - py*7;
    int t = threadIdx.x;
    const bf16* hb = h + (size_t)b*73984 + (py*4)*34 + px*4;
    float partial = 0.f;
    for (int tt = t; tt < 4096; tt += 256){
        int c = tt >> 6, k = tt & 63, ky = k >> 3, kx = k & 7;
        partial += bff(hb[(size_t)c*1156 + ky*34 + kx]) * rdf(pw, tt, f32);
    }
    red[t] = partial;
    __syncthreads();
    for (int s = 128; s > 0; s >>= 1){
        if (t < s) red[t] += red[t + s];
        __syncthreads();
    }
    if (t == 0){
        float v = red[0] + rdf(pb, 0, f32);
        v = gelu_f(v);
        p49[bid] = v * rdf(p2w, 0, f32) + rdf(p2b, 0, f32);
    }
}

// ---------------- sentence MLP 384->32->32->16 (relu,relu,lin) ---------------
__global__ __launch_bounds__(64) void k_sent(const void* __restrict__ se,
                                             const void* __restrict__ w1, const void* __restrict__ b1,
                                             const void* __restrict__ w2, const void* __restrict__ b2,
                                             const void* __restrict__ w3, const void* __restrict__ b3,
                                             float* __restrict__ outv,
                                             const float* __restrict__ flg){
    __shared__ float s1[32], s2[32];
    const bool f32 = (flg[0] > 0.5f);
    int b = blockIdx.x, t = threadIdx.x;
    if (t < 32){
        float acc = rdf(b1, t, f32);
        size_t rbase = (size_t)b*384;
        for (int k = 0; k < 384; ++k) acc += rdf(se, rbase + k, f32) * rdf(w1, k*32 + t, f32);
        s1[t] = fmaxf(acc, 0.f);
    }
    __syncthreads();
    if (t < 32){
        float acc = rdf(b2, t, f32);
        for (int k = 0; k < 32; ++k) acc += s1[k] * rdf(w2, k*32 + t, f32);
        s2[t] = fmaxf(acc, 0.f);
    }
    __syncthreads();
    if (t < 16){
        float acc = rdf(b3, t, f32);
        for (int k = 0; k < 32; ++k) acc += s2[k] * rdf(w3, k*16 + t, f32);
        outv[b*16 + t] = acc;
    }
}

// ---------------- xp MLP 49->32->32->16 (silu,silu,lin) ----------------------
__global__ __launch_bounds__(64) void k_xp(const float* __restrict__ p49,
                                           const void* __restrict__ w1, const void* __restrict__ b1,
                                           const void* __restrict__ w2, const void* __restrict__ b2,
                                           const void* __restrict__ w3, const void* __restrict__ b3,
                                           float* __restrict__ outv,
                                           const float* __restrict__ flg){
    __shared__ float s1[32], s2[32];
    const bool f32 = (flg[0] > 0.5f);
    int b = blockIdx.x, t = threadIdx.x;
    if (t < 32){
        float acc = rdf(b1, t, f32);
        const float* row = p49 + b*49;
        for (int k = 0; k < 49; ++k) acc += row[k] * rdf(w1, k*32 + t, f32);
        s1[t] = silu_f(acc);
    }
    __syncthreads();
    if (t < 32){
        float acc = rdf(b2, t, f32);
        for (int k = 0; k < 32; ++k) acc += s1[k] * rdf(w2, k*32 + t, f32);
        s2[t] = silu_f(acc);
    }
    __syncthreads();
    if (t < 16){
        float acc = rdf(b3, t, f32);
        for (int k = 0; k < 32; ++k) acc += s2[k] * rdf(w3, k*16 + t, f32);
        outv[b*16 + t] = acc;
    }
}

// ---------------- pu MLP part A: 32->128->256 (silu,silu) --------------------
__global__ __launch_bounds__(256) void k_puA(const float* __restrict__ xemb,
                                             const float* __restrict__ semb,
                                             const void* __restrict__ w1, const void* __restrict__ b1,
                                             const void* __restrict__ w2, const void* __restrict__ b2,
                                             float* __restrict__ h2buf,
                                             const float* __restrict__ flg){
    __shared__ float ein[32];
    __shared__ float h1[128];
    const bool f32 = (flg[0] > 0.5f);
    int b = blockIdx.x, t = threadIdx.x;
    if (t < 16) ein[t] = xemb[b*16 + t];
    else if (t < 32) ein[t] = semb[b*16 + (t - 16)];
    __syncthreads();
    if (t < 128){
        float acc = rdf(b1, t, f32);
        for (int k = 0; k < 32; ++k) acc += ein[k] * rdf(w1, k*128 + t, f32);
        h1[t] = silu_f(acc);
    }
    __syncthreads();
    {
        float acc = rdf(b2, t, f32);
        for (int k = 0; k < 128; ++k) acc += h1[k] * rdf(w2, k*256 + t, f32);
        h2buf[(size_t)b*256 + t] = silu_f(acc);
    }
}

// ---------------- pu MLP part B: 256->1156 GEMM ------------------------------
// grid 1280 = 256 b (fast) x 5 n-chunks of 232
__global__ __launch_bounds__(256) void k_puB(const float* __restrict__ h2buf,
                                             const void* __restrict__ w3, const void* __restrict__ b3,
                                             float* __restrict__ emb,
                                             const float* __restrict__ flg){
    __shared__ float sh2[256];
    const bool f32 = (flg[0] > 0.5f);
    int blk = blockIdx.x;
    int b = blk & 255, nc = blk >> 8;
    int t = threadIdx.x;
    sh2[t] = h2buf[(size_t)b*256 + t];
    __syncthreads();
    int e = nc*232 + t;
    if (t < 232 && e < 1156){
        float acc = rdf(b3, e, f32);
        if (f32){
            const float* wp = (const float*)w3 + e;
            #pragma unroll 4
            for (int k = 0; k < 256; ++k) acc += sh2[k] * wp[(size_t)k*1156];
        } else {
            const bf16* wp = (const bf16*)w3 + e;
            #pragma unroll 4
            for (int k = 0; k < 256; ++k) acc += sh2[k] * bff(wp[(size_t)k*1156]);
        }
        emb[(size_t)b*1156 + e] = acc;
    }
}

// ---------------- final: crop, concat emb, fc1+gelu, fc2 ---------------------
// grid 512 = 256 b x 2 halves; 4 iters of 4 rows (128 px); 8px x 8j dword tiles
__global__ __launch_bounds__(256) void k_final(const bf16* __restrict__ h,
                                               const float* __restrict__ emb,
                                               const void* __restrict__ w1, const void* __restrict__ b1,
                                               const void* __restrict__ w2, const void* __restrict__ b2,
                                               void* __restrict__ out,
                                               const float* __restrict__ flg){
    __shared__ unsigned int sw1p[4160];     // [c][j/2] packed pairs (j even)
    __shared__ float sb1[128];
    __shared__ float sw2[512];              // [j][k]
    __shared__ float sb2[4];
    __shared__ unsigned int sinpp[4160];    // [c][px/2] packed pairs
    __shared__ unsigned short shid[128*132];// [j][px] bf16 padded
    const bool f32 = (flg[0] > 0.5f);
    int blk = blockIdx.x;
    int b = blk >> 1, half = blk & 1;
    int t = threadIdx.x;
    for (int i = t; i < 4160; i += 256){
        int c = i >> 6, j2 = i & 63;
        sw1p[i] = packbf2(rdf(w1, (size_t)c*128 + j2*2, f32),
                          rdf(w1, (size_t)c*128 + j2*2 + 1, f32));
    }
    if (t < 128) sb1[t] = rdf(b1, t, f32);
    for (int i = t; i < 512; i += 256) sw2[i] = rdf(w2, i, f32);
    if (t < 4) sb2[t] = rdf(b2, t, f32);
    const bf16* hb = h + (size_t)b*73984;
    const float* eb = emb + (size_t)b*1156;
    int pxt = t & 15, jt = t >> 4;   // 16 x 16
    int px0 = pxt*8, j0 = jt*8;
    for (int it = 0; it < 4; ++it){
        int y0 = half*16 + it*4;     // 4 rows = 128 px
        __syncthreads();
        for (int i = t; i < 4160; i += 256){
            int c = i >> 6, p2 = i & 63;
            int px = p2*2;
            int y = y0 + (px >> 5), x = px & 31;
            float v0 = (c < 64) ? bff(hb[(size_t)c*1156 + y*34 + x]) : eb[y*34 + x];
            int px1 = px + 1;
            int y1 = y0 + (px1 >> 5), x1 = px1 & 31;
            float v1 = (c < 64) ? bff(hb[(size_t)c*1156 + y1*34 + x1]) : eb[y1*34 + x1];
            sinpp[i] = packbf2(v0, v1);
        }
        __syncthreads();
        float acc[8][8];
        #pragma unroll
        for (int j=0;j<8;++j)
            #pragma unroll
            for (int k=0;k<8;++k) acc[j][k] = sb1[j0+k];
        for (int c = 0; c < 65; ++c){
            float hv[8], wv[8];
            #pragma unroll
            for (int d = 0; d < 4; ++d){
                float2 hp = unpackbf2(sinpp[c*64 + (px0>>1) + d]);
                hv[2*d] = hp.x; hv[2*d+1] = hp.y;
                float2 wp = unpackbf2(sw1p[c*64 + (j0>>1) + d]);
                wv[2*d] = wp.x; wv[2*d+1] = wp.y;
            }
            #pragma unroll
            for (int j=0;j<8;++j)
                #pragma unroll
                for (int k=0;k<8;++k) acc[j][k] += hv[j]*wv[k];
        }
        #pragma unroll
        for (int j=0;j<8;++j)
            #pragma unroll
            for (int k=0;k<8;++k)
                shid[(j0+k)*132 + px0 + j] = f2us(gelu_f(acc[j][k]));
        __syncthreads();
        {
            int px = t & 127, kk = t >> 7;   // kk in {0,1} -> k = 2kk, 2kk+1
            float a0 = sb2[kk*2], a1 = sb2[kk*2+1];
            for (int j = 0; j < 128; ++j){
                float hvv = us2f(shid[j*132 + px]);
                a0 += hvv * sw2[j*4 + kk*2];
                a1 += hvv * sw2[j*4 + kk*2 + 1];
            }
            int y = y0 + (px >> 5), x = px & 31;
            size_t o = ((size_t)(b*32 + y)*32 + x)*4 + kk*2;
            if (f32){ ((float*)out)[o] = a0; ((float*)out)[o+1] = a1; }
            else { ((bf16*)out)[o] = __float2bfloat16(a0); ((bf16*)out)[o+1] = __float2bfloat16(a1); }
        }
    }
}

extern "C" void kernel_launch(void* const* d_in, const int* in_sizes, int n_in,
                              void* d_out, int out_size, void* d_ws, size_t ws_size,
                              hipStream_t stream) {
    (void)in_sizes; (void)n_in; (void)out_size; (void)ws_size;
    const void* x     = d_in[0];
    const void* grd   = d_in[1];
    const void* se    = d_in[2];
    const void* fc0_w = d_in[3];
    const void* fc0_b = d_in[4];
    const void* sc_w1 = d_in[5];
    const void* sc_w2 = d_in[6];
    const void* wc_w  = d_in[7];
    const void* wc_b  = d_in[8];
    const void* pe1_w = d_in[9];
    const void* pe1_b = d_in[10];
    const void* pe2_w = d_in[11];
    const void* pe2_b = d_in[12];
    const void* sp_w1 = d_in[13];
    const void* sp_b1 = d_in[14];
    const void* sp_w2 = d_in[15];
    const void* sp_b2 = d_in[16];
    const void* sp_w3 = d_in[17];
    const void* sp_b3 = d_in[18];
    const void* xp_w1 = d_in[19];
    const void* xp_b1 = d_in[20];
    const void* xp_w2 = d_in[21];
    const void* xp_b2 = d_in[22];
    const void* xp_w3 = d_in[23];
    const void* xp_b3 = d_in[24];
    const void* pu_w1 = d_in[25];
    const void* pu_b1 = d_in[26];
    const void* pu_w2 = d_in[27];
    const void* pu_b2 = d_in[28];
    const void* pu_w3 = d_in[29];
    const void* pu_b3 = d_in[30];
    const void* fc1_w = d_in[31];
    const void* fc1_b = d_in[32];
    const void* fc2_w = d_in[33];
    const void* fc2_b = d_in[34];

    // workspace layout (float-unit offsets); total ~77 MB
    float* ws    = (float*)d_ws;
    bf16*  hA    = (bf16*)ws;                              // 18,939,904 bf16
    unsigned int* hft   = (unsigned int*)(ws + 9469952);   // 4,718,592 dwords (hftA panels)
    unsigned int* mixed = (unsigned int*)(ws + 14188544);  // 4,718,592 dwords
    float* tabs  = ws + 18907136;                          // 4,896
    float* p49   = ws + 18912032;                          // 12,544
    float* semb  = ws + 18924576;                          // 4,096
    float* xemb  = ws + 18928672;                          // 4,096
    float* emb   = ws + 18932768;                          // 295,936
    float* flag  = ws + 19228704;                          // 1
    float* h2buf = (float*)hft;                            // reuse: hft dead after layer loop

    k_probe<<<1, 256, 0, stream>>>(x, flag);
    k_tables<<<1, 256, 0, stream>>>(tabs);
    k_fc0<<<256*34, 256, 0, stream>>>(x, grd, fc0_w, fc0_b, hA, flag);

    for (int l = 0; l < 4; ++l){
        k_fwd<<<4096, 256, 0, stream>>>(hA, hft, tabs);
        k_mixm<<<576, 256, 0, stream>>>((const unsigned short*)hft, sc_w1, sc_w2, mixed, l, flag);
        k_wc <<<2304, 256, 0, stream>>>(hA, wc_w, wc_b, l, flag);
        k_invm<<<4096, 256, 0, stream>>>(mixed, tabs, hA, l);
    }

    k_pe  <<<256*49, 256, 0, stream>>>(hA, pe1_w, pe1_b, pe2_w, pe2_b, p49, flag);
    k_sent<<<256, 64, 0, stream>>>(se, sp_w1, sp_b1, sp_w2, sp_b2, sp_w3, sp_b3, semb, flag);
    k_xp  <<<256, 64, 0, stream>>>(p49, xp_w1, xp_b1, xp_w2, xp_b2, xp_w3, xp_b3, xemb, flag);
    k_puA <<<256, 256, 0, stream>>>(xemb, semb, pu_w1, pu_b1, pu_w2, pu_b2, h2buf, flag);
    k_puB <<<1280, 256, 0, stream>>>(h2buf, pu_w3, pu_b3, emb, flag);
    k_final<<<512, 256, 0, stream>>>(hA, emb, fc1_w, fc1_b, fc2_w, fc2_b, d_out, flag);
}

// Round 7
// 1704.486 us; speedup vs baseline: 2.5542x; 1.0393x over previous
//
#include <hip/hip_runtime.h>
#include <hip/hip_bf16.h>
#include <math.h>

typedef __hip_bfloat16 bf16;
typedef __bf16 bfv8 __attribute__((ext_vector_type(8)));
typedef float fv4 __attribute__((ext_vector_type(4)));

__device__ __forceinline__ float bff(const bf16 x){ return __bfloat162float(x); }
__device__ __forceinline__ float gelu_f(float v){
    return 0.5f * v * (1.f + erff(v * 0.70710678118654752f));
}
__device__ __forceinline__ float silu_f(float v){
    return v / (1.f + expf(-v));
}
// dtype-agnostic input read: f32 ? fp32 : bf16
__device__ __forceinline__ float rdf(const void* p, size_t i, bool f32){
    return f32 ? ((const float*)p)[i] : __bfloat162float(((const bf16*)p)[i]);
}
__device__ __forceinline__ unsigned int packbf2(float a, float b){
    __hip_bfloat162 v;
    v.x = __float2bfloat16(a);
    v.y = __float2bfloat16(b);
    return *reinterpret_cast<unsigned int*>(&v);
}
__device__ __forceinline__ float2 unpackbf2(unsigned int u){
    __hip_bfloat162 v = *reinterpret_cast<__hip_bfloat162*>(&u);
    return make_float2(__bfloat162float(v.x), __bfloat162float(v.y));
}
__device__ __forceinline__ float us2f(unsigned short u){
    unsigned int x = ((unsigned int)u) << 16;
    return __uint_as_float(x);
}
__device__ __forceinline__ unsigned short f2us(float f){
    bf16 v = __float2bfloat16(f);
    return *reinterpret_cast<unsigned short*>(&v);
}

// Geometry
// B=256, C=64, H=W=34 (padded), modes: ky in {0..11, 22..33} (24), kx in 0..11 (12)
// h layout (ws, bf16): [b][c][y][x], stride c = 1156, stride b = 73984
// hftA layout: [m][b][k] bf16, k in [0,128): k<64 = Re(F)[c=k], k>=64 = Im(F)[c=k-64]
// mixed layout: [(b*64+o)*288 + m] packed bf16x2 dwords (r,i)

// ---------------- dtype probe ----------------
__global__ __launch_bounds__(256) void k_probe(const void* x, float* flag){
    __shared__ int wild;
    int t = threadIdx.x;
    if (t == 0) wild = 0;
    __syncthreads();
    const bf16* xb = (const bf16*)x;
    for (int i = t; i < 1024; i += 256){
        float v = bff(xb[i]);
        if (!(fabsf(v) < 1e10f)) wild = 1;
    }
    __syncthreads();
    if (t == 0) flag[0] = wild ? 1.f : 0.f;
}

// ---------------- tables ----------------
__global__ __launch_bounds__(256) void k_tables(float* tabs){
    int t = threadIdx.x;
    float* Wfy = tabs;          // 24*34*2
    float* Wfx = tabs + 1632;   // 12*34*2
    float* Wix = tabs + 2448;   // 12*34*2
    float* Wiy = tabs + 3264;   // 24*34*2
    const float TWO_PI = 6.283185307179586f;
    for (int e = t; e < 24*34; e += 256){
        int kyi = e / 34, y = e % 34;
        int ky = (kyi < 12) ? kyi : kyi + 10;
        int ph = (ky * y) % 34;
        float ang = TWO_PI * (float)ph / 34.0f;
        float s, c;
        sincosf(ang, &s, &c);
        Wfy[e*2]   = c;   Wfy[e*2+1] = -s;           // e^{-i ang}
        Wiy[e*2]   = c * (1.0f/1156.0f);
        Wiy[e*2+1] = s * (1.0f/1156.0f);             // (1/HW) e^{+i ang}
    }
    for (int e = t; e < 12*34; e += 256){
        int kx = e / 34, x = e % 34;
        int ph = (kx * x) % 34;
        float ang = TWO_PI * (float)ph / 34.0f;
        float s, c;
        sincosf(ang, &s, &c);
        Wfx[e*2] = c; Wfx[e*2+1] = -s;               // e^{-i ang}
        float ck = (kx == 0) ? 1.0f : 2.0f;
        Wix[e*2] = ck * c; Wix[e*2+1] = ck * s;      // c_kx e^{+i ang}
    }
}

// ---------------- fc0: concat(x,grid) @ fc0_w + b, NCHW, zero-pad to 34x34 ----
__global__ __launch_bounds__(256) void k_fc0(const void* __restrict__ xin,
                                             const void* __restrict__ grd,
                                             const void* __restrict__ w,
                                             const void* __restrict__ bias,
                                             bf16* __restrict__ h,
                                             const float* __restrict__ flg){
    __shared__ float sin_[32*42];
    __shared__ float sw[42*64];
    __shared__ float sb[64];
    const bool f32 = (flg[0] > 0.5f);
    int bid = blockIdx.x;          // b*34 + y
    int b = bid / 34, y = bid - b*34;
    int t = threadIdx.x;
    bf16* hb = h + (size_t)b*73984 + y*34;
    if (y >= 32){
        for (int e = t; e < 2176; e += 256){
            int c = e / 34, x = e - c*34;
            hb[(size_t)c*1156 + x] = __float2bfloat16(0.f);
        }
        return;
    }
    for (int idx = t; idx < 2688; idx += 256) sw[idx] = rdf(w, idx, f32);
    if (t < 64) sb[t] = rdf(bias, t, f32);
    size_t xbase = (size_t)(b*32 + y)*32*40;
    for (int idx = t; idx < 1280; idx += 256){
        int x = idx / 40, k = idx - x*40;
        sin_[x*42 + k] = rdf(xin, xbase + idx, f32);
    }
    size_t gbase = (size_t)(b*32 + y)*32*2;
    if (t < 64){
        int x = t >> 1, k2 = t & 1;
        sin_[x*42 + 40 + k2] = rdf(grd, gbase + x*2 + k2, f32);
    }
    __syncthreads();
    {
        int xt = t & 7, ct = t >> 3;    // 8 x-tiles x 32 c-tiles
        int x0 = xt*4, c0 = ct*2;
        float acc[2][4];
        #pragma unroll
        for (int cc=0;cc<2;++cc)
            #pragma unroll
            for (int j=0;j<4;++j) acc[cc][j] = sb[c0+cc];
        for (int k = 0; k < 42; ++k){
            float sv[4], wv[2];
            #pragma unroll
            for (int j=0;j<4;++j) sv[j] = sin_[(x0+j)*42 + k];
            #pragma unroll
            for (int cc=0;cc<2;++cc) wv[cc] = sw[k*64 + c0 + cc];
            #pragma unroll
            for (int cc=0;cc<2;++cc)
                #pragma unroll
                for (int j=0;j<4;++j) acc[cc][j] += sv[j]*wv[cc];
        }
        #pragma unroll
        for (int cc=0;cc<2;++cc)
            #pragma unroll
            for (int j=0;j<4;++j)
                hb[(size_t)(c0+cc)*1156 + x0 + j] = __float2bfloat16(acc[cc][j]);
    }
    for (int e = t; e < 128; e += 256){
        int c = e >> 1, x = 32 + (e & 1);
        hb[(size_t)c*1156 + x] = __float2bfloat16(0.f);
    }
}

// ---------------- forward truncated DFT, 4 channels per block ----------------
// grid 4096 = 256 b x 16 ch-groups; writes hftA [m][b][k] (A-panel layout)
__global__ __launch_bounds__(256) void k_fwd(const bf16* __restrict__ h,
                                             unsigned int* __restrict__ hftA,
                                             const float* __restrict__ tabs){
    __shared__ unsigned int shp[2312];  // 4 x 578 packed pairs (x even, x+1)
    __shared__ float sWfy[1632];
    __shared__ float sWfx[816];
    __shared__ unsigned int st[3264];   // 4 x 816 packed bf16x2 (G intermediates)
    int blk = blockIdx.x;
    int b = blk >> 4, c0 = (blk & 15) * 4;
    int t = threadIdx.x;
    for (int i = t; i < 1632; i += 256) sWfy[i] = tabs[i];
    for (int i = t; i < 816; i += 256) sWfx[i] = tabs[1632 + i];
    const unsigned int* srcp = (const unsigned int*)(h + (size_t)b*73984 + (size_t)c0*1156);
    for (int i = t; i < 2312; i += 256) shp[i] = srcp[i];
    __syncthreads();
    // step 1: G[ch][kyi][x] = sum_y Wfy[kyi][y] * h[ch][y][x]
    if (t < 204){
        int kyit = t / 17, xt = t - kyit*17;
        int kyi0 = kyit*2, x0 = xt*2;
        float a[4][2][2][2];
        #pragma unroll
        for (int c=0;c<4;++c)
            #pragma unroll
            for (int q=0;q<2;++q){ a[c][q][0][0]=0.f; a[c][q][0][1]=0.f; a[c][q][1][0]=0.f; a[c][q][1][1]=0.f; }
        for (int y = 0; y < 34; ++y){
            int w0 = (kyi0*34 + y)*2, w1 = ((kyi0+1)*34 + y)*2;
            float w0r = sWfy[w0], w0i = sWfy[w0+1];
            float w1r = sWfy[w1], w1i = sWfy[w1+1];
            #pragma unroll
            for (int c = 0; c < 4; ++c){
                float2 hp = unpackbf2(shp[c*578 + y*17 + xt]);
                float h0 = hp.x, h1 = hp.y;
                a[c][0][0][0] += h0*w0r; a[c][0][0][1] += h0*w0i;
                a[c][0][1][0] += h1*w0r; a[c][0][1][1] += h1*w0i;
                a[c][1][0][0] += h0*w1r; a[c][1][0][1] += h0*w1i;
                a[c][1][1][0] += h1*w1r; a[c][1][1][1] += h1*w1i;
            }
        }
        #pragma unroll
        for (int c = 0; c < 4; ++c)
            #pragma unroll
            for (int q = 0; q < 2; ++q){
                int base = c*816 + (kyi0+q)*34 + x0;
                st[base]   = packbf2(a[c][q][0][0], a[c][q][0][1]);
                st[base+1] = packbf2(a[c][q][1][0], a[c][q][1][1]);
            }
    }
    __syncthreads();
    // step 2: F[ch][kyi][kx] = sum_x G[ch][kyi][x] * Wfx[kx][x]
    if (t < 144){
        int kyit = t / 12, kx = t - kyit*12;
        int kyi0 = kyit*2;
        float a[4][2][2];
        #pragma unroll
        for (int c=0;c<4;++c){ a[c][0][0]=0.f; a[c][0][1]=0.f; a[c][1][0]=0.f; a[c][1][1]=0.f; }
        for (int x = 0; x < 34; ++x){
            float cr = sWfx[(kx*34+x)*2], ci = sWfx[(kx*34+x)*2+1];
            #pragma unroll
            for (int c = 0; c < 4; ++c){
                float2 g0 = unpackbf2(st[c*816 + kyi0*34 + x]);
                float2 g1 = unpackbf2(st[c*816 + (kyi0+1)*34 + x]);
                a[c][0][0] += g0.x*cr - g0.y*ci;
                a[c][0][1] += g0.x*ci + g0.y*cr;
                a[c][1][0] += g1.x*cr - g1.y*ci;
                a[c][1][1] += g1.x*ci + g1.y*cr;
            }
        }
        // hftA[m][b][k]: real at k=c0..c0+3, imag at k=64+c0..64+c0+3 (dword-packed)
        #pragma unroll
        for (int q = 0; q < 2; ++q){
            int m = (kyi0+q)*12 + kx;
            size_t base = (size_t)m*16384 + (size_t)b*64 + (c0 >> 1);
            hftA[base]      = packbf2(a[0][q][0], a[1][q][0]);
            hftA[base + 1]  = packbf2(a[2][q][0], a[3][q][0]);
            hftA[base + 32] = packbf2(a[0][q][1], a[1][q][1]);
            hftA[base + 33] = packbf2(a[2][q][1], a[3][q][1]);
        }
    }
}

// ---------------- per-mode channel mix as bf16 MFMA GEMM ---------------------
// grid 576 = 288 modes x 2 M-halves of 128; C[128,128] = A[128,128] x B[128,128]
// A = [Hr | Hi] (direct from hftA), B = [[Wr, Wi], [-Wi, Wr]] staged as BT in LDS
__global__ __launch_bounds__(256) void k_mixm(const unsigned short* __restrict__ hftA,
                                              const void* __restrict__ sc_w1,
                                              const void* __restrict__ sc_w2,
                                              unsigned int* __restrict__ mixed, int layer,
                                              const float* __restrict__ flg){
    __shared__ unsigned short sB[128*136];   // BT[n][k], row stride 136 (conflict-free frags)
    const bool f32 = (flg[0] > 0.5f);
    int m  = blockIdx.x >> 1;
    int mh = blockIdx.x & 1;
    int b0 = mh * 128;
    int t = threadIdx.x;
    int kyi = m / 12, kx = m - kyi*12;
    const void* w = (kyi < 12) ? sc_w1 : sc_w2;
    int r = (kyi < 12) ? kyi : kyi - 12;
    size_t wbase = (size_t)layer * 64*64*144*2;
    for (int idx = t; idx < 4096; idx += 256){     // idx = i*64+o
        int i = idx >> 6, o = idx & 63;
        size_t off = wbase + (((size_t)idx*12 + r)*12 + kx)*2;
        float wr = rdf(w, off, f32);
        float wi = rdf(w, off+1, f32);
        sB[o*136 + i]           = f2us(wr);
        sB[(o+64)*136 + i]      = f2us(wi);
        sB[o*136 + i + 64]      = f2us(-wi);
        sB[(o+64)*136 + i + 64] = f2us(wr);
    }
    __syncthreads();
    int ln = t & 15, qd = (t & 63) >> 4, wv = t >> 6;
    // A fragments: A[row=b0+wv*32+tm*16+ln][k=ks*32+qd*8+j], contiguous 16B loads
    bfv8 af[2][4];
    const unsigned short* abase = hftA + (size_t)m*32768 + (size_t)(b0 + wv*32 + ln)*128 + qd*8;
    #pragma unroll
    for (int tm = 0; tm < 2; ++tm)
        #pragma unroll
        for (int ks = 0; ks < 4; ++ks)
            af[tm][ks] = *reinterpret_cast<const bfv8*>(abase + tm*2048 + ks*32);
    fv4 acc[2][8];
    #pragma unroll
    for (int tm=0;tm<2;++tm)
        #pragma unroll
        for (int tn=0;tn<8;++tn) acc[tm][tn] = (fv4){0.f,0.f,0.f,0.f};
    #pragma unroll
    for (int ks = 0; ks < 4; ++ks){
        bfv8 bfr[8];
        #pragma unroll
        for (int tn = 0; tn < 8; ++tn)
            bfr[tn] = *reinterpret_cast<const bfv8*>(&sB[(tn*16 + ln)*136 + ks*32 + qd*8]);
        #pragma unroll
        for (int tm = 0; tm < 2; ++tm)
            #pragma unroll
            for (int tn = 0; tn < 8; ++tn)
                acc[tm][tn] = __builtin_amdgcn_mfma_f32_16x16x32_bf16(af[tm][ks], bfr[tn], acc[tm][tn], 0, 0, 0);
    }
    __syncthreads();
    // C -> LDS (reuse sB): C[row][col], row stride 136; C/D map row=qd*4+r, col=ln
    #pragma unroll
    for (int tm = 0; tm < 2; ++tm)
        #pragma unroll
        for (int tn = 0; tn < 8; ++tn)
            #pragma unroll
            for (int rr = 0; rr < 4; ++rr){
                int row = wv*32 + tm*16 + qd*4 + rr;
                int col = tn*16 + ln;
                sB[row*136 + col] = f2us(acc[tm][tn][rr]);
            }
    __syncthreads();
    // pack (r,i) and write mixed[(b*64+o)*288+m]
    for (int idx = t; idx < 8192; idx += 256){
        int row = idx >> 6, o = idx & 63;
        unsigned int pr = ((unsigned int)sB[row*136 + o]) |
                          (((unsigned int)sB[row*136 + o + 64]) << 16);
        mixed[((size_t)(b0 + row)*64 + o)*288 + m] = pr;
    }
}

// ---------------- pointwise 64x64 channel GEMM (wc path), IN PLACE -----------
// grid 2304 = 256 b x 9 row-groups of 4; bf16-packed LDS
__global__ __launch_bounds__(256) void k_wc(bf16* __restrict__ h,
                                            const void* __restrict__ wc_w,
                                            const void* __restrict__ wc_b,
                                            int layer,
                                            const float* __restrict__ flg){
    __shared__ unsigned int shhp[4352];   // [c][68 dwords] = [c][136 u16 px]
    __shared__ unsigned int swp[2048];    // [c][oh] pairs (o even, o+1)
    __shared__ float sb[64];
    const bool f32 = (flg[0] > 0.5f);
    unsigned short* sh16 = (unsigned short*)shhp;
    int blk = blockIdx.x;
    int b = blk / 9, g = blk - b*9;
    int y0 = g*4;
    int nrow = 34 - y0; if (nrow > 4) nrow = 4;
    int t = threadIdx.x;
    size_t wbase = (size_t)layer*4096;
    for (int idx = t; idx < 2048; idx += 256){
        int oh = idx >> 6, c = idx & 63;
        swp[c*32 + oh] = packbf2(rdf(wc_w, wbase + (size_t)(2*oh)*64 + c, f32),
                                 rdf(wc_w, wbase + (size_t)(2*oh+1)*64 + c, f32));
    }
    if (t < 64) sb[t] = rdf(wc_b, layer*64 + t, f32);
    bf16* hb = h + (size_t)b*73984 + y0*34;
    for (int e = t; e < 4352; e += 256){
        int c = e / 68, d = e - c*68;
        shhp[e] = ((const unsigned int*)(hb + (size_t)c*1156))[d];  // trailing garbage unused
    }
    __syncthreads();
    for (int tau = t; tau < 272; tau += 256){
        int ot = tau / 34, pxt = tau - ot*34;
        int o0 = ot*8;
        float acc[4][8];
        #pragma unroll
        for (int j=0;j<4;++j)
            #pragma unroll
            for (int k=0;k<8;++k) acc[j][k] = sb[o0+k];
        for (int c = 0; c < 64; ++c){
            float hv[4], wv[8];
            #pragma unroll
            for (int j=0;j<4;++j) hv[j] = us2f(sh16[c*136 + pxt + j*34]);
            #pragma unroll
            for (int d=0;d<4;++d){
                float2 wp = unpackbf2(swp[c*32 + (o0>>1) + d]);
                wv[2*d] = wp.x; wv[2*d+1] = wp.y;
            }
            #pragma unroll
            for (int j=0;j<4;++j)
                #pragma unroll
                for (int k=0;k<8;++k) acc[j][k] += hv[j]*wv[k];
        }
        #pragma unroll
        for (int j=0;j<4;++j){
            if (j < nrow){
                #pragma unroll
                for (int k=0;k<8;++k)
                    hb[(size_t)(o0+k)*1156 + pxt + j*34] = __float2bfloat16(acc[j][k]);
            }
        }
    }
}

// ---------------- inverse truncated DFT as MFMA GEMMs; in-place add + gelu ---
// grid 4096 = 256 b x 16 o-groups of 4.
__global__ __launch_bounds__(256) void k_invm(const unsigned int* __restrict__ mixed,
                                              const float* __restrict__ tabs,
                                              bf16* __restrict__ hio, int layer){
    __shared__ unsigned short sA[96*40];    // A[(ch*24+kyi)][k=2kx+ri], k 24..31 zero
    __shared__ unsigned short sBT[80*40];   // BT[n=2x+ri][k=2kx+ri2]
    __shared__ unsigned short sW2[48*72];   // W2[y][k=2kyi+ri], y>=34 / k>=48 zero
    __shared__ unsigned short sG[4*48*72];  // per ch: G^T[x][k=2kyi+ri], x>=34 / k>=48 zero
    int blk = blockIdx.x;
    int b = blk >> 4, o0 = (blk & 15) * 4;
    int t = threadIdx.x;
    const float* Wix = tabs + 2448;
    const float* Wiy = tabs + 3264;
    // fill sA from mixed (pure bit-copy of bf16 halves)
    const unsigned int* msrc = mixed + ((size_t)b*64 + o0)*288;
    for (int i = t; i < 1152; i += 256){
        int ch = i / 288, m = i - ch*288;
        int kyi = m / 12, kx = m - kyi*12;
        unsigned int u = msrc[i];
        int row = ch*24 + kyi;
        sA[row*40 + 2*kx]     = (unsigned short)(u & 0xFFFFu);
        sA[row*40 + 2*kx + 1] = (unsigned short)(u >> 16);
    }
    for (int i = t; i < 768; i += 256){      // zero K-pad 24..31
        int row = i >> 3, k = 24 + (i & 7);
        sA[row*40 + k] = 0;
    }
    // fill sBT (Wix expanded complex->real), 80 x 32
    for (int i = t; i < 2560; i += 256){
        int n = i >> 5, k = i & 31;
        float v = 0.f;
        if (n < 68 && k < 24){
            int x = n >> 1, ri = n & 1, kx = k >> 1, ri2 = k & 1;
            float c = Wix[(kx*34 + x)*2];
            float s = Wix[(kx*34 + x)*2 + 1];
            v = (ri == 0) ? (ri2 == 0 ? c : -s) : (ri2 == 0 ? s : c);
        }
        sBT[n*40 + k] = f2us(v);
    }
    // fill sW2 (Wiy expanded), 48 x 64
    for (int i = t; i < 3072; i += 256){
        int y = i >> 6, k = i & 63;
        float v = 0.f;
        if (y < 34 && k < 48){
            int kyi = k >> 1, ri = k & 1;
            v = Wiy[(kyi*34 + y)*2 + ri];
            if (ri) v = -v;
        }
        sW2[y*72 + k] = f2us(v);
    }
    // zero sG
    for (int i = t; i < 13824; i += 256) sG[i] = 0;
    __syncthreads();
    int ln = t & 15, qd = (t & 63) >> 4, wv = t >> 6;
    // ---- step A: 30 tiles (6 M x 5 N), K=32, round-robin over waves ----
    for (int tau = wv; tau < 30; tau += 4){
        int mt = tau / 5, nt = tau - mt*5;
        bfv8 a = *reinterpret_cast<const bfv8*>(&sA[(mt*16 + ln)*40 + qd*8]);
        bfv8 bb = *reinterpret_cast<const bfv8*>(&sBT[(nt*16 + ln)*40 + qd*8]);
        fv4 acc = (fv4){0.f,0.f,0.f,0.f};
        acc = __builtin_amdgcn_mfma_f32_16x16x32_bf16(a, bb, acc, 0, 0, 0);
        int col = nt*16 + ln;
        if (col < 68){
            int x = col >> 1, ri = col & 1;
            #pragma unroll
            for (int rr = 0; rr < 4; ++rr){
                int row = mt*16 + qd*4 + rr;
                int ch = row / 24, kyi = row - ch*24;
                sG[(ch*48 + x)*72 + 2*kyi + ri] = f2us(acc[rr]);
            }
        }
    }
    __syncthreads();
    // ---- step B: wave = ch; 3x3 tiles, K=64 (2 MFMAs) ----
    int ch = wv;
    bf16* iob = hio + (size_t)b*73984 + (size_t)(o0 + ch)*1156;
    #pragma unroll
    for (int mt = 0; mt < 3; ++mt){
        bfv8 a0 = *reinterpret_cast<const bfv8*>(&sW2[(mt*16 + ln)*72 + qd*8]);
        bfv8 a1 = *reinterpret_cast<const bfv8*>(&sW2[(mt*16 + ln)*72 + 32 + qd*8]);
        #pragma unroll
        for (int nt = 0; nt < 3; ++nt){
            bfv8 b0 = *reinterpret_cast<const bfv8*>(&sG[(ch*48 + nt*16 + ln)*72 + qd*8]);
            bfv8 b1 = *reinterpret_cast<const bfv8*>(&sG[(ch*48 + nt*16 + ln)*72 + 32 + qd*8]);
            fv4 acc = (fv4){0.f,0.f,0.f,0.f};
            acc = __builtin_amdgcn_mfma_f32_16x16x32_bf16(a0, b0, acc, 0, 0, 0);
            acc = __builtin_amdgcn_mfma_f32_16x16x32_bf16(a1, b1, acc, 0, 0, 0);
            int x = nt*16 + ln;
            if (x < 34){
                #pragma unroll
                for (int rr = 0; rr < 4; ++rr){
                    int y = mt*16 + qd*4 + rr;
                    if (y < 34){
                        size_t off = (size_t)y*34 + x;
                        float v = acc[rr] + bff(iob[off]);
                        if (layer < 3) v = gelu_f(v);
                        iob[off] = __float2bfloat16(v);
                    }
                }
            }
        }
    }
}

// ---------------- 8x8/stride4 VALID conv -> gelu -> pe2 scale ----------------
__global__ __launch_bounds__(256) void k_pe(const bf16* __restrict__ h,
                                            const void* __restrict__ pw,
                                            const void* __restrict__ pb,
                                            const void* __restrict__ p2w,
                                            const void* __restrict__ p2b,
                                            float* __restrict__ p49,
                                            const float* __restrict__ flg){
    __shared__ float red[256];
    const bool f32 = (flg[0] > 0.5f);
    int bid = blockIdx.x;          // b*49 + py*7 + px
    int b = bid / 49, r = bid - b*49;
    int py = r / 7, px = r - py*7;
    int t = threadIdx.x;
    const bf16* hb = h + (size_t)b*73984 + (py*4)*34 + px*4;
    float partial = 0.f;
    for (int tt = t; tt < 4096; tt += 256){
        int c = tt >> 6, k = tt & 63, ky = k >> 3, kx = k & 7;
        partial += bff(hb[(size_t)c*1156 + ky*34 + kx]) * rdf(pw, tt, f32);
    }
    red[t] = partial;
    __syncthreads();
    for (int s = 128; s > 0; s >>= 1){
        if (t < s) red[t] += red[t + s];
        __syncthreads();
    }
    if (t == 0){
        float v = red[0] + rdf(pb, 0, f32);
        v = gelu_f(v);
        p49[bid] = v * rdf(p2w, 0, f32) + rdf(p2b, 0, f32);
    }
}

// ---------------- sentence MLP 384->32->32->16 (relu,relu,lin) ---------------
__global__ __launch_bounds__(64) void k_sent(const void* __restrict__ se,
                                             const void* __restrict__ w1, const void* __restrict__ b1,
                                             const void* __restrict__ w2, const void* __restrict__ b2,
                                             const void* __restrict__ w3, const void* __restrict__ b3,
                                             float* __restrict__ outv,
                                             const float* __restrict__ flg){
    __shared__ float s1[32], s2[32];
    const bool f32 = (flg[0] > 0.5f);
    int b = blockIdx.x, t = threadIdx.x;
    if (t < 32){
        float acc = rdf(b1, t, f32);
        size_t rbase = (size_t)b*384;
        for (int k = 0; k < 384; ++k) acc += rdf(se, rbase + k, f32) * rdf(w1, k*32 + t, f32);
        s1[t] = fmaxf(acc, 0.f);
    }
    __syncthreads();
    if (t < 32){
        float acc = rdf(b2, t, f32);
        for (int k = 0; k < 32; ++k) acc += s1[k] * rdf(w2, k*32 + t, f32);
        s2[t] = fmaxf(acc, 0.f);
    }
    __syncthreads();
    if (t < 16){
        float acc = rdf(b3, t, f32);
        for (int k = 0; k < 32; ++k) acc += s2[k] * rdf(w3, k*16 + t, f32);
        outv[b*16 + t] = acc;
    }
}

// ---------------- xp MLP 49->32->32->16 (silu,silu,lin) ----------------------
__global__ __launch_bounds__(64) void k_xp(const float* __restrict__ p49,
                                           const void* __restrict__ w1, const void* __restrict__ b1,
                                           const void* __restrict__ w2, const void* __restrict__ b2,
                                           const void* __restrict__ w3, const void* __restrict__ b3,
                                           float* __restrict__ outv,
                                           const float* __restrict__ flg){
    __shared__ float s1[32], s2[32];
    const bool f32 = (flg[0] > 0.5f);
    int b = blockIdx.x, t = threadIdx.x;
    if (t < 32){
        float acc = rdf(b1, t, f32);
        const float* row = p49 + b*49;
        for (int k = 0; k < 49; ++k) acc += row[k] * rdf(w1, k*32 + t, f32);
        s1[t] = silu_f(acc);
    }
    __syncthreads();
    if (t < 32){
        float acc = rdf(b2, t, f32);
        for (int k = 0; k < 32; ++k) acc += s1[k] * rdf(w2, k*32 + t, f32);
        s2[t] = silu_f(acc);
    }
    __syncthreads();
    if (t < 16){
        float acc = rdf(b3, t, f32);
        for (int k = 0; k < 32; ++k) acc += s2[k] * rdf(w3, k*16 + t, f32);
        outv[b*16 + t] = acc;
    }
}

// ---------------- pu MLP part A: 32->128->256 (silu,silu) --------------------
__global__ __launch_bounds__(256) void k_puA(const float* __restrict__ xemb,
                                             const float* __restrict__ semb,
                                             const void* __restrict__ w1, const void* __restrict__ b1,
                                             const void* __restrict__ w2, const void* __restrict__ b2,
                                             float* __restrict__ h2buf,
                                             const float* __restrict__ flg){
    __shared__ float ein[32];
    __shared__ float h1[128];
    const bool f32 = (flg[0] > 0.5f);
    int b = blockIdx.x, t = threadIdx.x;
    if (t < 16) ein[t] = xemb[b*16 + t];
    else if (t < 32) ein[t] = semb[b*16 + (t - 16)];
    __syncthreads();
    if (t < 128){
        float acc = rdf(b1, t, f32);
        for (int k = 0; k < 32; ++k) acc += ein[k] * rdf(w1, k*128 + t, f32);
        h1[t] = silu_f(acc);
    }
    __syncthreads();
    {
        float acc = rdf(b2, t, f32);
        for (int k = 0; k < 128; ++k) acc += h1[k] * rdf(w2, k*256 + t, f32);
        h2buf[(size_t)b*256 + t] = silu_f(acc);
    }
}

// ---------------- pu MLP part B: 256->1156 GEMM ------------------------------
// grid 1280 = 256 b (fast) x 5 n-chunks of 232
__global__ __launch_bounds__(256) void k_puB(const float* __restrict__ h2buf,
                                             const void* __restrict__ w3, const void* __restrict__ b3,
                                             float* __restrict__ emb,
                                             const float* __restrict__ flg){
    __shared__ float sh2[256];
    const bool f32 = (flg[0] > 0.5f);
    int blk = blockIdx.x;
    int b = blk & 255, nc = blk >> 8;
    int t = threadIdx.x;
    sh2[t] = h2buf[(size_t)b*256 + t];
    __syncthreads();
    int e = nc*232 + t;
    if (t < 232 && e < 1156){
        float acc = rdf(b3, e, f32);
        if (f32){
            const float* wp = (const float*)w3 + e;
            #pragma unroll 4
            for (int k = 0; k < 256; ++k) acc += sh2[k] * wp[(size_t)k*1156];
        } else {
            const bf16* wp = (const bf16*)w3 + e;
            #pragma unroll 4
            for (int k = 0; k < 256; ++k) acc += sh2[k] * bff(wp[(size_t)k*1156]);
        }
        emb[(size_t)b*1156 + e] = acc;
    }
}

// ---------------- final: crop, concat emb, fc1(MFMA)+gelu, fc2(MFMA) ---------
// grid 512 = 256 b x 2 halves; 8 iters of 2 rows (64 px).
// fc1: C[64px,128j] = A[px,c<64] x w1 (K=64) + rank-1 emb add; fc2: K=128, N=16(4)
__global__ __launch_bounds__(256, 3) void k_final(const bf16* __restrict__ h,
                                                  const float* __restrict__ emb,
                                                  const void* __restrict__ w1, const void* __restrict__ b1,
                                                  const void* __restrict__ w2, const void* __restrict__ b2,
                                                  void* __restrict__ out,
                                                  const float* __restrict__ flg){
    __shared__ unsigned short sw1t[128*72];   // w1T[j][c], stride 72 (16B-aligned rows)
    __shared__ unsigned short sw2t[16*136];   // w2T[n][j], rows 4..15 zero
    __shared__ float sw1e[128];               // w1[64][j] (emb channel)
    __shared__ float sb1[128];
    __shared__ float sb2[4];
    __shared__ unsigned short spx[64*66];     // input[c][px], stride 66 (odd dwords)
    __shared__ float sembp[64];               // emb[px]
    __shared__ unsigned short sh2[128*66];    // hid[j][px], stride 66
    const bool f32 = (flg[0] > 0.5f);
    int blk = blockIdx.x;
    int b = blk >> 1, half = blk & 1;
    int t = threadIdx.x;
    for (int i = t; i < 8320; i += 256){       // w1 [c=65][j=128]
        int c = i >> 7, j = i & 127;
        float v = rdf(w1, i, f32);
        if (c < 64) sw1t[j*72 + c] = f2us(v);
        else sw1e[j] = v;
    }
    if (t < 128) sb1[t] = rdf(b1, t, f32);
    for (int i = t; i < 2176; i += 256){       // w2 [j=128][k=4] -> w2T[n][j]
        int n = i / 136, j = i - n*136;
        float v = (n < 4 && j < 128) ? rdf(w2, j*4 + n, f32) : 0.f;
        sw2t[i] = f2us(v);
    }
    if (t < 4) sb2[t] = rdf(b2, t, f32);
    __syncthreads();
    int ln = t & 15, qd = (t & 63) >> 4, wv = t >> 6;
    // hoist B fragments (weights) into registers
    bfv8 bw1[8][2];
    #pragma unroll
    for (int tn = 0; tn < 8; ++tn)
        #pragma unroll
        for (int ks = 0; ks < 2; ++ks)
            bw1[tn][ks] = *reinterpret_cast<const bfv8*>(&sw1t[(tn*16 + ln)*72 + ks*32 + qd*8]);
    bfv8 bw2[4];
    #pragma unroll
    for (int ks = 0; ks < 4; ++ks)
        bw2[ks] = *reinterpret_cast<const bfv8*>(&sw2t[ln*136 + ks*32 + qd*8]);
    const bf16* hb = h + (size_t)b*73984;
    const float* eb = emb + (size_t)b*1156;
    for (int it = 0; it < 8; ++it){
        int y0 = half*16 + it*2;               // 2 rows = 64 px
        __syncthreads();
        for (int e = t; e < 2048; e += 256){   // stage spx[c][px] c-major
            int c = e >> 5, d = e & 31;
            int px = d*2;
            int y = y0 + (px >> 5), x = px & 31;
            float v0 = bff(hb[(size_t)c*1156 + y*34 + x]);
            int px1 = px + 1;
            int y1 = y0 + (px1 >> 5), x1 = px1 & 31;
            float v1 = bff(hb[(size_t)c*1156 + y1*34 + x1]);
            ((unsigned int*)spx)[c*33 + d] = packbf2(v0, v1);
        }
        if (t < 64){
            int y = y0 + (t >> 5), x = t & 31;
            sembp[t] = eb[y*34 + x];
        }
        __syncthreads();
        // fc1 MFMA: wave wv owns mtile wv (px = wv*16 + ...)
        fv4 acc[8];
        #pragma unroll
        for (int tn = 0; tn < 8; ++tn) acc[tn] = (fv4){0.f,0.f,0.f,0.f};
        #pragma unroll
        for (int ks = 0; ks < 2; ++ks){
            union { bfv8 v; unsigned short s[8]; } af;
            #pragma unroll
            for (int j = 0; j < 8; ++j)
                af.s[j] = spx[(ks*32 + qd*8 + j)*66 + wv*16 + ln];
            #pragma unroll
            for (int tn = 0; tn < 8; ++tn)
                acc[tn] = __builtin_amdgcn_mfma_f32_16x16x32_bf16(af.v, bw1[tn][ks], acc[tn], 0, 0, 0);
        }
        float ev[4];
        #pragma unroll
        for (int rr = 0; rr < 4; ++rr) ev[rr] = sembp[wv*16 + qd*4 + rr];
        #pragma unroll
        for (int tn = 0; tn < 8; ++tn){
            int col = tn*16 + ln;
            float we = sw1e[col];
            float bb1 = sb1[col];
            #pragma unroll
            for (int rr = 0; rr < 4; ++rr){
                float v = acc[tn][rr] + ev[rr]*we + bb1;
                sh2[col*66 + wv*16 + qd*4 + rr] = f2us(gelu_f(v));
            }
        }
        __syncthreads();
        // fc2 MFMA: K=128, N=16 (4 valid)
        fv4 a2 = (fv4){0.f,0.f,0.f,0.f};
        #pragma unroll
        for (int ks = 0; ks < 4; ++ks){
            union { bfv8 v; unsigned short s[8]; } af;
            #pragma unroll
            for (int j = 0; j < 8; ++j)
                af.s[j] = sh2[(ks*32 + qd*8 + j)*66 + wv*16 + ln];
            a2 = __builtin_amdgcn_mfma_f32_16x16x32_bf16(af.v, bw2[ks], a2, 0, 0, 0);
        }
        if (ln < 4){
            float bb2 = sb2[ln];
            #pragma unroll
            for (int rr = 0; rr < 4; ++rr){
                int pxl = wv*16 + qd*4 + rr;
                int y = y0 + (pxl >> 5), x = pxl & 31;
                size_t o = ((size_t)(b*32 + y)*32 + x)*4 + ln;
                float v = a2[rr] + bb2;
                if (f32) ((float*)out)[o] = v;
                else     ((bf16*)out)[o] = __float2bfloat16(v);
            }
        }
    }
}

extern "C" void kernel_launch(void* const* d_in, const int* in_sizes, int n_in,
                              void* d_out, int out_size, void* d_ws, size_t ws_size,
                              hipStream_t stream) {
    (void)in_sizes; (void)n_in; (void)out_size; (void)ws_size;
    const void* x     = d_in[0];
    const void* grd   = d_in[1];
    const void* se    = d_in[2];
    const void* fc0_w = d_in[3];
    const void* fc0_b = d_in[4];
    const void* sc_w1 = d_in[5];
    const void* sc_w2 = d_in[6];
    const void* wc_w  = d_in[7];
    const void* wc_b  = d_in[8];
    const void* pe1_w = d_in[9];
    const void* pe1_b = d_in[10];
    const void* pe2_w = d_in[11];
    const void* pe2_b = d_in[12];
    const void* sp_w1 = d_in[13];
    const void* sp_b1 = d_in[14];
    const void* sp_w2 = d_in[15];
    const void* sp_b2 = d_in[16];
    const void* sp_w3 = d_in[17];
    const void* sp_b3 = d_in[18];
    const void* xp_w1 = d_in[19];
    const void* xp_b1 = d_in[20];
    const void* xp_w2 = d_in[21];
    const void* xp_b2 = d_in[22];
    const void* xp_w3 = d_in[23];
    const void* xp_b3 = d_in[24];
    const void* pu_w1 = d_in[25];
    const void* pu_b1 = d_in[26];
    const void* pu_w2 = d_in[27];
    const void* pu_b2 = d_in[28];
    const void* pu_w3 = d_in[29];
    const void* pu_b3 = d_in[30];
    const void* fc1_w = d_in[31];
    const void* fc1_b = d_in[32];
    const void* fc2_w = d_in[33];
    const void* fc2_b = d_in[34];

    // workspace layout (float-unit offsets); total ~77 MB
    float* ws    = (float*)d_ws;
    bf16*  hA    = (bf16*)ws;                              // 18,939,904 bf16
    unsigned int* hft   = (unsigned int*)(ws + 9469952);   // 4,718,592 dwords (hftA panels)
    unsigned int* mixed = (unsigned int*)(ws + 14188544);  // 4,718,592 dwords
    float* tabs  = ws + 18907136;                          // 4,896
    float* p49   = ws + 18912032;                          // 12,544
    float* semb  = ws + 18924576;                          // 4,096
    float* xemb  = ws + 18928672;                          // 4,096
    float* emb   = ws + 18932768;                          // 295,936
    float* flag  = ws + 19228704;                          // 1
    float* h2buf = (float*)hft;                            // reuse: hft dead after layer loop

    k_probe<<<1, 256, 0, stream>>>(x, flag);
    k_tables<<<1, 256, 0, stream>>>(tabs);
    k_fc0<<<256*34, 256, 0, stream>>>(x, grd, fc0_w, fc0_b, hA, flag);

    for (int l = 0; l < 4; ++l){
        k_fwd<<<4096, 256, 0, stream>>>(hA, hft, tabs);
        k_mixm<<<576, 256, 0, stream>>>((const unsigned short*)hft, sc_w1, sc_w2, mixed, l, flag);
        k_wc <<<2304, 256, 0, stream>>>(hA, wc_w, wc_b, l, flag);
        k_invm<<<4096, 256, 0, stream>>>(mixed, tabs, hA, l);
    }

    k_pe  <<<256*49, 256, 0, stream>>>(hA, pe1_w, pe1_b, pe2_w, pe2_b, p49, flag);
    k_sent<<<256, 64, 0, stream>>>(se, sp_w1, sp_b1, sp_w2, sp_b2, sp_w3, sp_b3, semb, flag);
    k_xp  <<<256, 64, 0, stream>>>(p49, xp_w1, xp_b1, xp_w2, xp_b2, xp_w3, xp_b3, xemb, flag);
    k_puA <<<256, 256, 0, stream>>>(xemb, semb, pu_w1, pu_b1, pu_w2, pu_b2, h2buf, flag);
    k_puB <<<1280, 256, 0, stream>>>(h2buf, pu_w3, pu_b3, emb, flag);
    k_final<<<512, 256, 0, stream>>>(hA, emb, fc1_w, fc1_b, fc2_w, fc2_b, d_out, flag);
}

// Round 8
// 1593.005 us; speedup vs baseline: 2.7330x; 1.0700x over previous
//
#include <hip/hip_runtime.h>
#include <hip/hip_bf16.h>
#include <math.h>

typedef __hip_bfloat16 bf16;
typedef __bf16 bfv8 __attribute__((ext_vector_type(8)));
typedef float fv4 __attribute__((ext_vector_type(4)));

__device__ __forceinline__ float bff(const bf16 x){ return __bfloat162float(x); }
__device__ __forceinline__ float gelu_f(float v){
    return 0.5f * v * (1.f + erff(v * 0.70710678118654752f));
}
__device__ __forceinline__ float silu_f(float v){
    return v / (1.f + expf(-v));
}
// dtype-agnostic input read: f32 ? fp32 : bf16
__device__ __forceinline__ float rdf(const void* p, size_t i, bool f32){
    return f32 ? ((const float*)p)[i] : __bfloat162float(((const bf16*)p)[i]);
}
__device__ __forceinline__ unsigned int packbf2(float a, float b){
    __hip_bfloat162 v;
    v.x = __float2bfloat16(a);
    v.y = __float2bfloat16(b);
    return *reinterpret_cast<unsigned int*>(&v);
}
__device__ __forceinline__ float2 unpackbf2(unsigned int u){
    __hip_bfloat162 v = *reinterpret_cast<__hip_bfloat162*>(&u);
    return make_float2(__bfloat162float(v.x), __bfloat162float(v.y));
}
__device__ __forceinline__ float us2f(unsigned short u){
    unsigned int x = ((unsigned int)u) << 16;
    return __uint_as_float(x);
}
__device__ __forceinline__ unsigned short f2us(float f){
    bf16 v = __float2bfloat16(f);
    return *reinterpret_cast<unsigned short*>(&v);
}

// Geometry
// B=256, C=64, H=W=34 (padded), modes: ky in {0..11, 22..33} (24), kx in 0..11 (12)
// h layout (ws, bf16): [b][c][y][x], stride c = 1156, stride b = 73984
// hftA layout: [m][b][k] bf16, k in [0,128): k<64 = Re(F)[c=k], k>=64 = Im(F)[c=k-64]
// mixed layout: [(b*64+o)*288 + m] packed bf16x2 dwords (r,i)
// tabs: [0,1632) Wfy f32 | [1632,2448) Wfx f32 |
//       [2448,3536) invBT bf16 image (68x16 dw) | [3536,4624) invW2 bf16 image (34x32 dw)

// ---------------- dtype probe ----------------
__global__ __launch_bounds__(256) void k_probe(const void* x, float* flag){
    __shared__ int wild;
    int t = threadIdx.x;
    if (t == 0) wild = 0;
    __syncthreads();
    const bf16* xb = (const bf16*)x;
    for (int i = t; i < 1024; i += 256){
        float v = bff(xb[i]);
        if (!(fabsf(v) < 1e10f)) wild = 1;
    }
    __syncthreads();
    if (t == 0) flag[0] = wild ? 1.f : 0.f;
}

// ---------------- tables ----------------
__global__ __launch_bounds__(256) void k_tables(float* tabs){
    int t = threadIdx.x;
    float* Wfy = tabs;          // 24*34*2
    float* Wfx = tabs + 1632;   // 12*34*2
    unsigned int* gBT = (unsigned int*)(tabs + 2448);   // [n<68][kd<16] bf16x2
    unsigned int* gW2 = (unsigned int*)(tabs + 3536);   // [y<34][kd<32] bf16x2
    const float TWO_PI = 6.283185307179586f;
    for (int e = t; e < 24*34; e += 256){
        int kyi = e / 34, y = e % 34;
        int ky = (kyi < 12) ? kyi : kyi + 10;
        int ph = (ky * y) % 34;
        float ang = TWO_PI * (float)ph / 34.0f;
        float s, c;
        sincosf(ang, &s, &c);
        Wfy[e*2]   = c;   Wfy[e*2+1] = -s;           // e^{-i ang}
    }
    for (int e = t; e < 12*34; e += 256){
        int kx = e / 34, x = e % 34;
        int ph = (kx * x) % 34;
        float ang = TWO_PI * (float)ph / 34.0f;
        float s, c;
        sincosf(ang, &s, &c);
        Wfx[e*2] = c; Wfx[e*2+1] = -s;               // e^{-i ang}
    }
    // invBT image: n=2x+ri (x<34), k=2kx+ri2; v = ri==0 ? (ri2==0? C : -S) : (ri2==0? S : C)
    // where C = ck*cos(ang), S = ck*sin(ang), ang = +2pi*(kx*x mod 34)/34, ck = (kx==0?1:2)
    for (int i = t; i < 1088; i += 256){
        int n = i >> 4, kd = i & 15;
        int x = n >> 1, ri = n & 1;
        int kx = kd;
        float v0 = 0.f, v1 = 0.f;
        if (kx < 12){
            int ph = (kx * x) % 34;
            float ang = TWO_PI * (float)ph / 34.0f;
            float s, c;
            sincosf(ang, &s, &c);
            float ck = (kx == 0) ? 1.0f : 2.0f;
            float C = ck * c, S = ck * s;
            v0 = (ri == 0) ? C : S;       // ri2 = 0
            v1 = (ri == 0) ? -S : C;      // ri2 = 1
        }
        gBT[i] = packbf2(v0, v1);
    }
    // invW2 image: y<34, k=2kyi+ri; v = (1/1156)*(ri==0? cos : -sin), ang=+2pi*(ky*y mod 34)/34
    for (int i = t; i < 1088; i += 256){
        int y = i >> 5, kd = i & 31;
        int kyi = kd;
        float v0 = 0.f, v1 = 0.f;
        if (kyi < 24){
            int ky = (kyi < 12) ? kyi : kyi + 10;
            int ph = (ky * y) % 34;
            float ang = TWO_PI * (float)ph / 34.0f;
            float s, c;
            sincosf(ang, &s, &c);
            v0 = c * (1.0f/1156.0f);
            v1 = -s * (1.0f/1156.0f);
        }
        gW2[i] = packbf2(v0, v1);
    }
}

// ---------------- fc0: concat(x,grid) @ fc0_w + b, NCHW, zero-pad to 34x34 ----
__global__ __launch_bounds__(256) void k_fc0(const void* __restrict__ xin,
                                             const void* __restrict__ grd,
                                             const void* __restrict__ w,
                                             const void* __restrict__ bias,
                                             bf16* __restrict__ h,
                                             const float* __restrict__ flg){
    __shared__ float sin_[32*42];
    __shared__ float sw[42*64];
    __shared__ float sb[64];
    const bool f32 = (flg[0] > 0.5f);
    int bid = blockIdx.x;          // b*34 + y
    int b = bid / 34, y = bid - b*34;
    int t = threadIdx.x;
    bf16* hb = h + (size_t)b*73984 + y*34;
    if (y >= 32){
        for (int e = t; e < 2176; e += 256){
            int c = e / 34, x = e - c*34;
            hb[(size_t)c*1156 + x] = __float2bfloat16(0.f);
        }
        return;
    }
    for (int idx = t; idx < 2688; idx += 256) sw[idx] = rdf(w, idx, f32);
    if (t < 64) sb[t] = rdf(bias, t, f32);
    size_t xbase = (size_t)(b*32 + y)*32*40;
    for (int idx = t; idx < 1280; idx += 256){
        int x = idx / 40, k = idx - x*40;
        sin_[x*42 + k] = rdf(xin, xbase + idx, f32);
    }
    size_t gbase = (size_t)(b*32 + y)*32*2;
    if (t < 64){
        int x = t >> 1, k2 = t & 1;
        sin_[x*42 + 40 + k2] = rdf(grd, gbase + x*2 + k2, f32);
    }
    __syncthreads();
    {
        int xt = t & 7, ct = t >> 3;    // 8 x-tiles x 32 c-tiles
        int x0 = xt*4, c0 = ct*2;
        float acc[2][4];
        #pragma unroll
        for (int cc=0;cc<2;++cc)
            #pragma unroll
            for (int j=0;j<4;++j) acc[cc][j] = sb[c0+cc];
        for (int k = 0; k < 42; ++k){
            float sv[4], wv[2];
            #pragma unroll
            for (int j=0;j<4;++j) sv[j] = sin_[(x0+j)*42 + k];
            #pragma unroll
            for (int cc=0;cc<2;++cc) wv[cc] = sw[k*64 + c0 + cc];
            #pragma unroll
            for (int cc=0;cc<2;++cc)
                #pragma unroll
                for (int j=0;j<4;++j) acc[cc][j] += sv[j]*wv[cc];
        }
        #pragma unroll
        for (int cc=0;cc<2;++cc)
            #pragma unroll
            for (int j=0;j<4;++j)
                hb[(size_t)(c0+cc)*1156 + x0 + j] = __float2bfloat16(acc[cc][j]);
    }
    for (int e = t; e < 128; e += 256){
        int c = e >> 1, x = 32 + (e & 1);
        hb[(size_t)c*1156 + x] = __float2bfloat16(0.f);
    }
}

// ---------------- forward truncated DFT, 4 channels per block ----------------
// grid 4096 = 256 b x 16 ch-groups; writes hftA [m][b][k] (A-panel layout)
__global__ __launch_bounds__(256) void k_fwd(const bf16* __restrict__ h,
                                             unsigned int* __restrict__ hftA,
                                             const float* __restrict__ tabs){
    __shared__ unsigned int shp[2312];  // 4 x 578 packed pairs (x even, x+1)
    __shared__ float sWfy[1632];
    __shared__ float sWfx[816];
    __shared__ unsigned int st[3264];   // 4 x 816 packed bf16x2 (G intermediates)
    int blk = blockIdx.x;
    int b = blk >> 4, c0 = (blk & 15) * 4;
    int t = threadIdx.x;
    for (int i = t; i < 1632; i += 256) sWfy[i] = tabs[i];
    for (int i = t; i < 816; i += 256) sWfx[i] = tabs[1632 + i];
    const unsigned int* srcp = (const unsigned int*)(h + (size_t)b*73984 + (size_t)c0*1156);
    for (int i = t; i < 2312; i += 256) shp[i] = srcp[i];
    __syncthreads();
    // step 1: G[ch][kyi][x] = sum_y Wfy[kyi][y] * h[ch][y][x]
    if (t < 204){
        int kyit = t / 17, xt = t - kyit*17;
        int kyi0 = kyit*2, x0 = xt*2;
        float a[4][2][2][2];
        #pragma unroll
        for (int c=0;c<4;++c)
            #pragma unroll
            for (int q=0;q<2;++q){ a[c][q][0][0]=0.f; a[c][q][0][1]=0.f; a[c][q][1][0]=0.f; a[c][q][1][1]=0.f; }
        for (int y = 0; y < 34; ++y){
            int w0 = (kyi0*34 + y)*2, w1 = ((kyi0+1)*34 + y)*2;
            float w0r = sWfy[w0], w0i = sWfy[w0+1];
            float w1r = sWfy[w1], w1i = sWfy[w1+1];
            #pragma unroll
            for (int c = 0; c < 4; ++c){
                float2 hp = unpackbf2(shp[c*578 + y*17 + xt]);
                float h0 = hp.x, h1 = hp.y;
                a[c][0][0][0] += h0*w0r; a[c][0][0][1] += h0*w0i;
                a[c][0][1][0] += h1*w0r; a[c][0][1][1] += h1*w0i;
                a[c][1][0][0] += h0*w1r; a[c][1][0][1] += h0*w1i;
                a[c][1][1][0] += h1*w1r; a[c][1][1][1] += h1*w1i;
            }
        }
        #pragma unroll
        for (int c = 0; c < 4; ++c)
            #pragma unroll
            for (int q = 0; q < 2; ++q){
                int base = c*816 + (kyi0+q)*34 + x0;
                st[base]   = packbf2(a[c][q][0][0], a[c][q][0][1]);
                st[base+1] = packbf2(a[c][q][1][0], a[c][q][1][1]);
            }
    }
    __syncthreads();
    // step 2: F[ch][kyi][kx] = sum_x G[ch][kyi][x] * Wfx[kx][x]
    if (t < 144){
        int kyit = t / 12, kx = t - kyit*12;
        int kyi0 = kyit*2;
        float a[4][2][2];
        #pragma unroll
        for (int c=0;c<4;++c){ a[c][0][0]=0.f; a[c][0][1]=0.f; a[c][1][0]=0.f; a[c][1][1]=0.f; }
        for (int x = 0; x < 34; ++x){
            float cr = sWfx[(kx*34+x)*2], ci = sWfx[(kx*34+x)*2+1];
            #pragma unroll
            for (int c = 0; c < 4; ++c){
                float2 g0 = unpackbf2(st[c*816 + kyi0*34 + x]);
                float2 g1 = unpackbf2(st[c*816 + (kyi0+1)*34 + x]);
                a[c][0][0] += g0.x*cr - g0.y*ci;
                a[c][0][1] += g0.x*ci + g0.y*cr;
                a[c][1][0] += g1.x*cr - g1.y*ci;
                a[c][1][1] += g1.x*ci + g1.y*cr;
            }
        }
        // hftA[m][b][k]: real at k=c0..c0+3, imag at k=64+c0..64+c0+3 (dword-packed)
        #pragma unroll
        for (int q = 0; q < 2; ++q){
            int m = (kyi0+q)*12 + kx;
            size_t base = (size_t)m*16384 + (size_t)b*64 + (c0 >> 1);
            hftA[base]      = packbf2(a[0][q][0], a[1][q][0]);
            hftA[base + 1]  = packbf2(a[2][q][0], a[3][q][0]);
            hftA[base + 32] = packbf2(a[0][q][1], a[1][q][1]);
            hftA[base + 33] = packbf2(a[2][q][1], a[3][q][1]);
        }
    }
}

// ---------------- per-mode channel mix as bf16 MFMA GEMM ---------------------
// grid 576 = 288 modes x 2 M-halves of 128; C[128,128] = A[128,128] x B[128,128]
// A = [Hr | Hi] (direct from hftA), B = [[Wr, Wi], [-Wi, Wr]] staged as BT in LDS
__global__ __launch_bounds__(256) void k_mixm(const unsigned short* __restrict__ hftA,
                                              const void* __restrict__ sc_w1,
                                              const void* __restrict__ sc_w2,
                                              unsigned int* __restrict__ mixed, int layer,
                                              const float* __restrict__ flg){
    __shared__ unsigned short sB[128*136];   // BT[n][k], row stride 136 (conflict-free frags)
    const bool f32 = (flg[0] > 0.5f);
    int m  = blockIdx.x >> 1;
    int mh = blockIdx.x & 1;
    int b0 = mh * 128;
    int t = threadIdx.x;
    int kyi = m / 12, kx = m - kyi*12;
    const void* w = (kyi < 12) ? sc_w1 : sc_w2;
    int r = (kyi < 12) ? kyi : kyi - 12;
    size_t wbase = (size_t)layer * 64*64*144*2;
    for (int idx = t; idx < 4096; idx += 256){     // idx = i*64+o
        int i = idx >> 6, o = idx & 63;
        size_t off = wbase + (((size_t)idx*12 + r)*12 + kx)*2;
        float wr = rdf(w, off, f32);
        float wi = rdf(w, off+1, f32);
        sB[o*136 + i]           = f2us(wr);
        sB[(o+64)*136 + i]      = f2us(wi);
        sB[o*136 + i + 64]      = f2us(-wi);
        sB[(o+64)*136 + i + 64] = f2us(wr);
    }
    __syncthreads();
    int ln = t & 15, qd = (t & 63) >> 4, wv = t >> 6;
    // A fragments: A[row=b0+wv*32+tm*16+ln][k=ks*32+qd*8+j], contiguous 16B loads
    bfv8 af[2][4];
    const unsigned short* abase = hftA + (size_t)m*32768 + (size_t)(b0 + wv*32 + ln)*128 + qd*8;
    #pragma unroll
    for (int tm = 0; tm < 2; ++tm)
        #pragma unroll
        for (int ks = 0; ks < 4; ++ks)
            af[tm][ks] = *reinterpret_cast<const bfv8*>(abase + tm*2048 + ks*32);
    fv4 acc[2][8];
    #pragma unroll
    for (int tm=0;tm<2;++tm)
        #pragma unroll
        for (int tn=0;tn<8;++tn) acc[tm][tn] = (fv4){0.f,0.f,0.f,0.f};
    #pragma unroll
    for (int ks = 0; ks < 4; ++ks){
        bfv8 bfr[8];
        #pragma unroll
        for (int tn = 0; tn < 8; ++tn)
            bfr[tn] = *reinterpret_cast<const bfv8*>(&sB[(tn*16 + ln)*136 + ks*32 + qd*8]);
        #pragma unroll
        for (int tm = 0; tm < 2; ++tm)
            #pragma unroll
            for (int tn = 0; tn < 8; ++tn)
                acc[tm][tn] = __builtin_amdgcn_mfma_f32_16x16x32_bf16(af[tm][ks], bfr[tn], acc[tm][tn], 0, 0, 0);
    }
    __syncthreads();
    // C -> LDS (reuse sB): C[row][col], row stride 136; C/D map row=qd*4+r, col=ln
    #pragma unroll
    for (int tm = 0; tm < 2; ++tm)
        #pragma unroll
        for (int tn = 0; tn < 8; ++tn)
            #pragma unroll
            for (int rr = 0; rr < 4; ++rr){
                int row = wv*32 + tm*16 + qd*4 + rr;
                int col = tn*16 + ln;
                sB[row*136 + col] = f2us(acc[tm][tn][rr]);
            }
    __syncthreads();
    // pack (r,i) and write mixed[(b*64+o)*288+m]
    for (int idx = t; idx < 8192; idx += 256){
        int row = idx >> 6, o = idx & 63;
        unsigned int pr = ((unsigned int)sB[row*136 + o]) |
                          (((unsigned int)sB[row*136 + o + 64]) << 16);
        mixed[((size_t)(b0 + row)*64 + o)*288 + m] = pr;
    }
}

// ---------------- pointwise 64x64 channel GEMM (wc path), IN PLACE -----------
// grid 2304 = 256 b x 9 row-groups of 4; bf16-packed LDS
__global__ __launch_bounds__(256) void k_wc(bf16* __restrict__ h,
                                            const void* __restrict__ wc_w,
                                            const void* __restrict__ wc_b,
                                            int layer,
                                            const float* __restrict__ flg){
    __shared__ unsigned int shhp[4352];   // [c][68 dwords] = [c][136 u16 px]
    __shared__ unsigned int swp[2048];    // [c][oh] pairs (o even, o+1)
    __shared__ float sb[64];
    const bool f32 = (flg[0] > 0.5f);
    unsigned short* sh16 = (unsigned short*)shhp;
    int blk = blockIdx.x;
    int b = blk / 9, g = blk - b*9;
    int y0 = g*4;
    int nrow = 34 - y0; if (nrow > 4) nrow = 4;
    int t = threadIdx.x;
    size_t wbase = (size_t)layer*4096;
    for (int idx = t; idx < 2048; idx += 256){
        int oh = idx >> 6, c = idx & 63;
        swp[c*32 + oh] = packbf2(rdf(wc_w, wbase + (size_t)(2*oh)*64 + c, f32),
                                 rdf(wc_w, wbase + (size_t)(2*oh+1)*64 + c, f32));
    }
    if (t < 64) sb[t] = rdf(wc_b, layer*64 + t, f32);
    bf16* hb = h + (size_t)b*73984 + y0*34;
    for (int e = t; e < 4352; e += 256){
        int c = e / 68, d = e - c*68;
        shhp[e] = ((const unsigned int*)(hb + (size_t)c*1156))[d];  // trailing garbage unused
    }
    __syncthreads();
    for (int tau = t; tau < 272; tau += 256){
        int ot = tau / 34, pxt = tau - ot*34;
        int o0 = ot*8;
        float acc[4][8];
        #pragma unroll
        for (int j=0;j<4;++j)
            #pragma unroll
            for (int k=0;k<8;++k) acc[j][k] = sb[o0+k];
        for (int c = 0; c < 64; ++c){
            float hv[4], wv[8];
            #pragma unroll
            for (int j=0;j<4;++j) hv[j] = us2f(sh16[c*136 + pxt + j*34]);
            #pragma unroll
            for (int d=0;d<4;++d){
                float2 wp = unpackbf2(swp[c*32 + (o0>>1) + d]);
                wv[2*d] = wp.x; wv[2*d+1] = wp.y;
            }
            #pragma unroll
            for (int j=0;j<4;++j)
                #pragma unroll
                for (int k=0;k<8;++k) acc[j][k] += hv[j]*wv[k];
        }
        #pragma unroll
        for (int j=0;j<4;++j){
            if (j < nrow){
                #pragma unroll
                for (int k=0;k<8;++k)
                    hb[(size_t)(o0+k)*1156 + pxt + j*34] = __float2bfloat16(acc[j][k]);
            }
        }
    }
}

// ---------------- inverse truncated DFT as MFMA GEMMs; in-place add + gelu ---
// grid 4096 = 256 b x 16 o-groups of 4. Tables precomputed in k_tables (dword copies).
// Epilogue: 4 contiguous ch-planes staged to LDS (coalesced), add+gelu in LDS, dword writeback.
__global__ __launch_bounds__(256) void k_invm(const unsigned int* __restrict__ mixed,
                                              const float* __restrict__ tabs,
                                              bf16* __restrict__ hio, int layer){
    __shared__ unsigned short lds[24320];   // 48640 B total
    unsigned short* sA  = lds;              // 96*40 (step A only; later = htile)
    unsigned short* sBT = lds + 3840;       // 80*40 (step A only; later = htile)
    unsigned short* sW2 = lds + 7040;       // 48*72
    unsigned short* sG  = lds + 10496;      // 4*48*72
    unsigned int* ldsw  = (unsigned int*)lds;
    int blk = blockIdx.x;
    int b = blk >> 4, o0 = (blk & 15) * 4;
    int t = threadIdx.x;
    const unsigned int* gBT = (const unsigned int*)(tabs + 2448);
    const unsigned int* gW2 = (const unsigned int*)(tabs + 3536);
    // sA from mixed: one aligned dword per mode
    const unsigned int* msrc = mixed + ((size_t)b*64 + o0)*288;
    for (int i = t; i < 1152; i += 256){
        int ch = i / 288, m = i - ch*288;
        int kyi = m / 12, kx = m - kyi*12;
        ((unsigned int*)sA)[(ch*24 + kyi)*20 + kx] = msrc[i];
    }
    for (int i = t; i < 384; i += 256)       // zero k 24..31 (dw 12..15)
        ((unsigned int*)sA)[(i >> 2)*20 + 12 + (i & 3)] = 0;
    // sBT copy (rows n<68), zero rows 68..79
    for (int i = t; i < 1088; i += 256)
        ((unsigned int*)sBT)[(i >> 4)*20 + (i & 15)] = gBT[i];
    for (int i = t; i < 192; i += 256)
        ((unsigned int*)sBT)[(68 + (i >> 4))*20 + (i & 15)] = 0;
    // sW2 copy (rows y<34), zero rows 34..47
    for (int i = t; i < 1088; i += 256)
        ((unsigned int*)sW2)[(i >> 5)*36 + (i & 31)] = gW2[i];
    for (int i = t; i < 448; i += 256)
        ((unsigned int*)sW2)[(34 + (i >> 5))*36 + (i & 31)] = 0;
    // sG: zero only read pads — rows x in [34,48): dw 0..31; rows x<34: dw 24..31
    for (int i = t; i < 1792; i += 256){
        int r = i >> 5;
        int ch = r / 14, x = 34 + (r - (r/14)*14);
        ((unsigned int*)sG)[(ch*48 + x)*36 + (i & 31)] = 0;
    }
    for (int i = t; i < 1088; i += 256){
        int r = i >> 3;
        int ch = r / 34, x = r - (r/34)*34;
        ((unsigned int*)sG)[(ch*48 + x)*36 + 24 + (i & 7)] = 0;
    }
    __syncthreads();
    int ln = t & 15, qd = (t & 63) >> 4, wv = t >> 6;
    // ---- step A: 30 tiles (6 M x 5 N), K=32, round-robin over waves ----
    for (int tau = wv; tau < 30; tau += 4){
        int mt = tau / 5, nt = tau - mt*5;
        bfv8 a = *reinterpret_cast<const bfv8*>(&sA[(mt*16 + ln)*40 + qd*8]);
        bfv8 bb = *reinterpret_cast<const bfv8*>(&sBT[(nt*16 + ln)*40 + qd*8]);
        fv4 acc = (fv4){0.f,0.f,0.f,0.f};
        acc = __builtin_amdgcn_mfma_f32_16x16x32_bf16(a, bb, acc, 0, 0, 0);
        int col = nt*16 + ln;
        if (col < 68){
            int x = col >> 1, ri = col & 1;
            #pragma unroll
            for (int rr = 0; rr < 4; ++rr){
                int row = mt*16 + qd*4 + rr;
                int ch = row / 24, kyi = row - ch*24;
                sG[(ch*48 + x)*72 + 2*kyi + ri] = f2us(acc[rr]);
            }
        }
    }
    __syncthreads();
    // ---- stage htile (4 contiguous ch-planes) into dead sA/sBT region ----
    const unsigned int* hsrc = (const unsigned int*)(hio + (size_t)b*73984 + (size_t)o0*1156);
    for (int i = t; i < 2312; i += 256) ldsw[i] = hsrc[i];
    __syncthreads();
    // ---- step B: wave = ch; 3x3 tiles, K=64 (2 MFMAs); add+gelu into LDS htile ----
    int ch = wv;
    #pragma unroll
    for (int mt = 0; mt < 3; ++mt){
        bfv8 a0 = *reinterpret_cast<const bfv8*>(&sW2[(mt*16 + ln)*72 + qd*8]);
        bfv8 a1 = *reinterpret_cast<const bfv8*>(&sW2[(mt*16 + ln)*72 + 32 + qd*8]);
        #pragma unroll
        for (int nt = 0; nt < 3; ++nt){
            bfv8 b0 = *reinterpret_cast<const bfv8*>(&sG[(ch*48 + nt*16 + ln)*72 + qd*8]);
            bfv8 b1 = *reinterpret_cast<const bfv8*>(&sG[(ch*48 + nt*16 + ln)*72 + 32 + qd*8]);
            fv4 acc = (fv4){0.f,0.f,0.f,0.f};
            acc = __builtin_amdgcn_mfma_f32_16x16x32_bf16(a0, b0, acc, 0, 0, 0);
            acc = __builtin_amdgcn_mfma_f32_16x16x32_bf16(a1, b1, acc, 0, 0, 0);
            int x = nt*16 + ln;
            if (x < 34){
                #pragma unroll
                for (int rr = 0; rr < 4; ++rr){
                    int y = mt*16 + qd*4 + rr;
                    if (y < 34){
                        int off = ch*1156 + y*34 + x;
                        float v = acc[rr] + us2f(lds[off]);
                        if (layer < 3) v = gelu_f(v);
                        lds[off] = f2us(v);
                    }
                }
            }
        }
    }
    __syncthreads();
    // ---- coalesced dword writeback ----
    unsigned int* hdst = (unsigned int*)(hio + (size_t)b*73984 + (size_t)o0*1156);
    for (int i = t; i < 2312; i += 256) hdst[i] = ldsw[i];
}

// ---------------- 8x8/stride4 VALID conv -> gelu -> pe2 scale ----------------
__global__ __launch_bounds__(256) void k_pe(const bf16* __restrict__ h,
                                            const void* __restrict__ pw,
                                            const void* __restrict__ pb,
                                            const void* __restrict__ p2w,
                                            const void* __restrict__ p2b,
                                            float* __restrict__ p49,
                                            const float* __restrict__ flg){
    __shared__ float red[256];
    const bool f32 = (flg[0] > 0.5f);
    int bid = blockIdx.x;          // b*49 + py*7 + px
    int b = bid / 49, r = bid - b*49;
    int py = r / 7, px = r - py*7;
    int t = threadIdx.x;
    const bf16* hb = h + (size_t)b*73984 + (py*4)*34 + px*4;
    float partial = 0.f;
    for (int tt = t; tt < 4096; tt += 256){
        int c = tt >> 6, k = tt & 63, ky = k >> 3, kx = k & 7;
        partial += bff(hb[(size_t)c*1156 + ky*34 + kx]) * rdf(pw, tt, f32);
    }
    red[t] = partial;
    __syncthreads();
    for (int s = 128; s > 0; s >>= 1){
        if (t < s) red[t] += red[t + s];
        __syncthreads();
    }
    if (t == 0){
        float v = red[0] + rdf(pb, 0, f32);
        v = gelu_f(v);
        p49[bid] = v * rdf(p2w, 0, f32) + rdf(p2b, 0, f32);
    }
}

// ---------------- sentence MLP 384->32->32->16 (relu,relu,lin) ---------------
__global__ __launch_bounds__(64) void k_sent(const void* __restrict__ se,
                                             const void* __restrict__ w1, const void* __restrict__ b1,
                                             const void* __restrict__ w2, const void* __restrict__ b2,
                                             const void* __restrict__ w3, const void* __restrict__ b3,
                                             float* __restrict__ outv,
                                             const float* __restrict__ flg){
    __shared__ float s1[32], s2[32];
    const bool f32 = (flg[0] > 0.5f);
    int b = blockIdx.x, t = threadIdx.x;
    if (t < 32){
        float acc = rdf(b1, t, f32);
        size_t rbase = (size_t)b*384;
        for (int k = 0; k < 384; ++k) acc += rdf(se, rbase + k, f32) * rdf(w1, k*32 + t, f32);
        s1[t] = fmaxf(acc, 0.f);
    }
    __syncthreads();
    if (t < 32){
        float acc = rdf(b2, t, f32);
        for (int k = 0; k < 32; ++k) acc += s1[k] * rdf(w2, k*32 + t, f32);
        s2[t] = fmaxf(acc, 0.f);
    }
    __syncthreads();
    if (t < 16){
        float acc = rdf(b3, t, f32);
        for (int k = 0; k < 32; ++k) acc += s2[k] * rdf(w3, k*16 + t, f32);
        outv[b*16 + t] = acc;
    }
}

// ---------------- xp MLP 49->32->32->16 (silu,silu,lin) ----------------------
__global__ __launch_bounds__(64) void k_xp(const float* __restrict__ p49,
                                           const void* __restrict__ w1, const void* __restrict__ b1,
                                           const void* __restrict__ w2, const void* __restrict__ b2,
                                           const void* __restrict__ w3, const void* __restrict__ b3,
                                           float* __restrict__ outv,
                                           const float* __restrict__ flg){
    __shared__ float s1[32], s2[32];
    const bool f32 = (flg[0] > 0.5f);
    int b = blockIdx.x, t = threadIdx.x;
    if (t < 32){
        float acc = rdf(b1, t, f32);
        const float* row = p49 + b*49;
        for (int k = 0; k < 49; ++k) acc += row[k] * rdf(w1, k*32 + t, f32);
        s1[t] = silu_f(acc);
    }
    __syncthreads();
    if (t < 32){
        float acc = rdf(b2, t, f32);
        for (int k = 0; k < 32; ++k) acc += s1[k] * rdf(w2, k*32 + t, f32);
        s2[t] = silu_f(acc);
    }
    __syncthreads();
    if (t < 16){
        float acc = rdf(b3, t, f32);
        for (int k = 0; k < 32; ++k) acc += s2[k] * rdf(w3, k*16 + t, f32);
        outv[b*16 + t] = acc;
    }
}

// ---------------- pu MLP part A: 32->128->256 (silu,silu) --------------------
__global__ __launch_bounds__(256) void k_puA(const float* __restrict__ xemb,
                                             const float* __restrict__ semb,
                                             const void* __restrict__ w1, const void* __restrict__ b1,
                                             const void* __restrict__ w2, const void* __restrict__ b2,
                                             float* __restrict__ h2buf,
                                             const float* __restrict__ flg){
    __shared__ float ein[32];
    __shared__ float h1[128];
    const bool f32 = (flg[0] > 0.5f);
    int b = blockIdx.x, t = threadIdx.x;
    if (t < 16) ein[t] = xemb[b*16 + t];
    else if (t < 32) ein[t] = semb[b*16 + (t - 16)];
    __syncthreads();
    if (t < 128){
        float acc = rdf(b1, t, f32);
        for (int k = 0; k < 32; ++k) acc += ein[k] * rdf(w1, k*128 + t, f32);
        h1[t] = silu_f(acc);
    }
    __syncthreads();
    {
        float acc = rdf(b2, t, f32);
        for (int k = 0; k < 128; ++k) acc += h1[k] * rdf(w2, k*256 + t, f32);
        h2buf[(size_t)b*256 + t] = silu_f(acc);
    }
}

// ---------------- pu MLP part B: 256->1156 GEMM ------------------------------
// grid 1280 = 256 b (fast) x 5 n-chunks of 232
__global__ __launch_bounds__(256) void k_puB(const float* __restrict__ h2buf,
                                             const void* __restrict__ w3, const void* __restrict__ b3,
                                             float* __restrict__ emb,
                                             const float* __restrict__ flg){
    __shared__ float sh2[256];
    const bool f32 = (flg[0] > 0.5f);
    int blk = blockIdx.x;
    int b = blk & 255, nc = blk >> 8;
    int t = threadIdx.x;
    sh2[t] = h2buf[(size_t)b*256 + t];
    __syncthreads();
    int e = nc*232 + t;
    if (t < 232 && e < 1156){
        float acc = rdf(b3, e, f32);
        if (f32){
            const float* wp = (const float*)w3 + e;
            #pragma unroll 4
            for (int k = 0; k < 256; ++k) acc += sh2[k] * wp[(size_t)k*1156];
        } else {
            const bf16* wp = (const bf16*)w3 + e;
            #pragma unroll 4
            for (int k = 0; k < 256; ++k) acc += sh2[k] * bff(wp[(size_t)k*1156]);
        }
        emb[(size_t)b*1156 + e] = acc;
    }
}

// ---------------- final: crop, concat emb, fc1(MFMA)+gelu, fc2(MFMA) ---------
// grid 512 = 256 b x 2 halves; 8 iters of 2 rows (64 px).
// fc1: C[64px,128j] = A[px,c<64] x w1 (K=64) + rank-1 emb add; fc2: K=128, N=16(4)
__global__ __launch_bounds__(256, 3) void k_final(const bf16* __restrict__ h,
                                                  const float* __restrict__ emb,
                                                  const void* __restrict__ w1, const void* __restrict__ b1,
                                                  const void* __restrict__ w2, const void* __restrict__ b2,
                                                  void* __restrict__ out,
                                                  const float* __restrict__ flg){
    __shared__ unsigned short sw1t[128*72];   // w1T[j][c], stride 72 (16B-aligned rows)
    __shared__ unsigned short sw2t[16*136];   // w2T[n][j], rows 4..15 zero
    __shared__ float sw1e[128];               // w1[64][j] (emb channel)
    __shared__ float sb1[128];
    __shared__ float sb2[4];
    __shared__ unsigned short spx[64*66];     // input[c][px], stride 66 (odd dwords)
    __shared__ float sembp[64];               // emb[px]
    __shared__ unsigned short sh2[128*66];    // hid[j][px], stride 66
    const bool f32 = (flg[0] > 0.5f);
    int blk = blockIdx.x;
    int b = blk >> 1, half = blk & 1;
    int t = threadIdx.x;
    for (int i = t; i < 8320; i += 256){       // w1 [c=65][j=128]
        int c = i >> 7, j = i & 127;
        float v = rdf(w1, i, f32);
        if (c < 64) sw1t[j*72 + c] = f2us(v);
        else sw1e[j] = v;
    }
    if (t < 128) sb1[t] = rdf(b1, t, f32);
    for (int i = t; i < 2176; i += 256){       // w2 [j=128][k=4] -> w2T[n][j]
        int n = i / 136, j = i - n*136;
        float v = (n < 4 && j < 128) ? rdf(w2, j*4 + n, f32) : 0.f;
        sw2t[i] = f2us(v);
    }
    if (t < 4) sb2[t] = rdf(b2, t, f32);
    __syncthreads();
    int ln = t & 15, qd = (t & 63) >> 4, wv = t >> 6;
    // hoist B fragments (weights) into registers
    bfv8 bw1[8][2];
    #pragma unroll
    for (int tn = 0; tn < 8; ++tn)
        #pragma unroll
        for (int ks = 0; ks < 2; ++ks)
            bw1[tn][ks] = *reinterpret_cast<const bfv8*>(&sw1t[(tn*16 + ln)*72 + ks*32 + qd*8]);
    bfv8 bw2[4];
    #pragma unroll
    for (int ks = 0; ks < 4; ++ks)
        bw2[ks] = *reinterpret_cast<const bfv8*>(&sw2t[ln*136 + ks*32 + qd*8]);
    const bf16* hb = h + (size_t)b*73984;
    const float* eb = emb + (size_t)b*1156;
    for (int it = 0; it < 8; ++it){
        int y0 = half*16 + it*2;               // 2 rows = 64 px
        __syncthreads();
        for (int e = t; e < 2048; e += 256){   // stage spx[c][px] c-major
            int c = e >> 5, d = e & 31;
            int px = d*2;
            int y = y0 + (px >> 5), x = px & 31;
            float v0 = bff(hb[(size_t)c*1156 + y*34 + x]);
            int px1 = px + 1;
            int y1 = y0 + (px1 >> 5), x1 = px1 & 31;
            float v1 = bff(hb[(size_t)c*1156 + y1*34 + x1]);
            ((unsigned int*)spx)[c*33 + d] = packbf2(v0, v1);
        }
        if (t < 64){
            int y = y0 + (t >> 5), x = t & 31;
            sembp[t] = eb[y*34 + x];
        }
        __syncthreads();
        // fc1 MFMA: wave wv owns mtile wv (px = wv*16 + ...)
        fv4 acc[8];
        #pragma unroll
        for (int tn = 0; tn < 8; ++tn) acc[tn] = (fv4){0.f,0.f,0.f,0.f};
        #pragma unroll
        for (int ks = 0; ks < 2; ++ks){
            union { bfv8 v; unsigned short s[8]; } af;
            #pragma unroll
            for (int j = 0; j < 8; ++j)
                af.s[j] = spx[(ks*32 + qd*8 + j)*66 + wv*16 + ln];
            #pragma unroll
            for (int tn = 0; tn < 8; ++tn)
                acc[tn] = __builtin_amdgcn_mfma_f32_16x16x32_bf16(af.v, bw1[tn][ks], acc[tn], 0, 0, 0);
        }
        float ev[4];
        #pragma unroll
        for (int rr = 0; rr < 4; ++rr) ev[rr] = sembp[wv*16 + qd*4 + rr];
        #pragma unroll
        for (int tn = 0; tn < 8; ++tn){
            int col = tn*16 + ln;
            float we = sw1e[col];
            float bb1 = sb1[col];
            #pragma unroll
            for (int rr = 0; rr < 4; ++rr){
                float v = acc[tn][rr] + ev[rr]*we + bb1;
                sh2[col*66 + wv*16 + qd*4 + rr] = f2us(gelu_f(v));
            }
        }
        __syncthreads();
        // fc2 MFMA: K=128, N=16 (4 valid)
        fv4 a2 = (fv4){0.f,0.f,0.f,0.f};
        #pragma unroll
        for (int ks = 0; ks < 4; ++ks){
            union { bfv8 v; unsigned short s[8]; } af;
            #pragma unroll
            for (int j = 0; j < 8; ++j)
                af.s[j] = sh2[(ks*32 + qd*8 + j)*66 + wv*16 + ln];
            a2 = __builtin_amdgcn_mfma_f32_16x16x32_bf16(af.v, bw2[ks], a2, 0, 0, 0);
        }
        if (ln < 4){
            float bb2 = sb2[ln];
            #pragma unroll
            for (int rr = 0; rr < 4; ++rr){
                int pxl = wv*16 + qd*4 + rr;
                int y = y0 + (pxl >> 5), x = pxl & 31;
                size_t o = ((size_t)(b*32 + y)*32 + x)*4 + ln;
                float v = a2[rr] + bb2;
                if (f32) ((float*)out)[o] = v;
                else     ((bf16*)out)[o] = __float2bfloat16(v);
            }
        }
    }
}

extern "C" void kernel_launch(void* const* d_in, const int* in_sizes, int n_in,
                              void* d_out, int out_size, void* d_ws, size_t ws_size,
                              hipStream_t stream) {
    (void)in_sizes; (void)n_in; (void)out_size; (void)ws_size;
    const void* x     = d_in[0];
    const void* grd   = d_in[1];
    const void* se    = d_in[2];
    const void* fc0_w = d_in[3];
    const void* fc0_b = d_in[4];
    const void* sc_w1 = d_in[5];
    const void* sc_w2 = d_in[6];
    const void* wc_w  = d_in[7];
    const void* wc_b  = d_in[8];
    const void* pe1_w = d_in[9];
    const void* pe1_b = d_in[10];
    const void* pe2_w = d_in[11];
    const void* pe2_b = d_in[12];
    const void* sp_w1 = d_in[13];
    const void* sp_b1 = d_in[14];
    const void* sp_w2 = d_in[15];
    const void* sp_b2 = d_in[16];
    const void* sp_w3 = d_in[17];
    const void* sp_b3 = d_in[18];
    const void* xp_w1 = d_in[19];
    const void* xp_b1 = d_in[20];
    const void* xp_w2 = d_in[21];
    const void* xp_b2 = d_in[22];
    const void* xp_w3 = d_in[23];
    const void* xp_b3 = d_in[24];
    const void* pu_w1 = d_in[25];
    const void* pu_b1 = d_in[26];
    const void* pu_w2 = d_in[27];
    const void* pu_b2 = d_in[28];
    const void* pu_w3 = d_in[29];
    const void* pu_b3 = d_in[30];
    const void* fc1_w = d_in[31];
    const void* fc1_b = d_in[32];
    const void* fc2_w = d_in[33];
    const void* fc2_b = d_in[34];

    // workspace layout (float-unit offsets); total ~77 MB
    float* ws    = (float*)d_ws;
    bf16*  hA    = (bf16*)ws;                              // 18,939,904 bf16
    unsigned int* hft   = (unsigned int*)(ws + 9469952);   // 4,718,592 dwords (hftA panels)
    unsigned int* mixed = (unsigned int*)(ws + 14188544);  // 4,718,592 dwords
    float* tabs  = ws + 18907136;                          // 4,896 (DFT tables + inv images)
    float* p49   = ws + 18912032;                          // 12,544
    float* semb  = ws + 18924576;                          // 4,096
    float* xemb  = ws + 18928672;                          // 4,096
    float* emb   = ws + 18932768;                          // 295,936
    float* flag  = ws + 19228704;                          // 1
    float* h2buf = (float*)hft;                            // reuse: hft dead after layer loop

    k_probe<<<1, 256, 0, stream>>>(x, flag);
    k_tables<<<1, 256, 0, stream>>>(tabs);
    k_fc0<<<256*34, 256, 0, stream>>>(x, grd, fc0_w, fc0_b, hA, flag);

    for (int l = 0; l < 4; ++l){
        k_fwd<<<4096, 256, 0, stream>>>(hA, hft, tabs);
        k_mixm<<<576, 256, 0, stream>>>((const unsigned short*)hft, sc_w1, sc_w2, mixed, l, flag);
        k_wc <<<2304, 256, 0, stream>>>(hA, wc_w, wc_b, l, flag);
        k_invm<<<4096, 256, 0, stream>>>(mixed, tabs, hA, l);
    }

    k_pe  <<<256*49, 256, 0, stream>>>(hA, pe1_w, pe1_b, pe2_w, pe2_b, p49, flag);
    k_sent<<<256, 64, 0, stream>>>(se, sp_w1, sp_b1, sp_w2, sp_b2, sp_w3, sp_b3, semb, flag);
    k_xp  <<<256, 64, 0, stream>>>(p49, xp_w1, xp_b1, xp_w2, xp_b2, xp_w3, xp_b3, xemb, flag);
    k_puA <<<256, 256, 0, stream>>>(xemb, semb, pu_w1, pu_b1, pu_w2, pu_b2, h2buf, flag);
    k_puB <<<1280, 256, 0, stream>>>(h2buf, pu_w3, pu_b3, emb, flag);
    k_final<<<512, 256, 0, stream>>>(hA, emb, fc1_w, fc1_b, fc2_w, fc2_b, d_out, flag);
}